// Round 6
// baseline (501.793 us; speedup 1.0000x reference)
//
#include <hip/hip_runtime.h>
#include <math.h>

// ---------------------------------------------------------------------------
// VQ-VAE forward.
// Encoder: 256-ch convs as implicit-GEMM MFMA with 2-term bf16 split inputs
// (3 passes: w1x1 + w1x2 + w2x1). Big convs split-K=2 with PLAIN-STORE
// per-kz partial buffers. VQ: chunk-parallel partial argmin + reduce.
// Decoder: t1 + t2.
// R6: A-operand direct-from-global (contiguous 1KB/wave, L1-hot; deletes sA
//     LDS staging+reads, -55% LDS traffic) with 2-chunk-unrolled dual A regs.
//     3x3 conv: per-cg 6x34 halo tile staged ONCE for all 9 taps (B staging
//     /5.5, barriers /9; kz splits by cg). B staging stays global_load_lds.
// ---------------------------------------------------------------------------

typedef unsigned int uint;
typedef unsigned short ushort_t;
using short8 = __attribute__((ext_vector_type(8))) short;
using f32x4  = __attribute__((ext_vector_type(4))) float;

// zero-initialized pad: invalid halo rows DMA from here (always zero)
__device__ __attribute__((aligned(16))) ushort_t g_zpad[512];

static __device__ __forceinline__ int rfl(int x) { return __builtin_amdgcn_readfirstlane(x); }
static __device__ __forceinline__ ushort_t f2bf(float f) {
  uint u = __float_as_uint(f);
  return (ushort_t)((u + 0x7fffu + ((u >> 16) & 1u)) >> 16);  // RNE; finite inputs
}
static __device__ __forceinline__ float bf2f(ushort_t b) {
  return __uint_as_float(((uint)b) << 16);
}
// direct global->LDS DMA, 16B per lane; lds dest = wave-uniform base + lane*16
static __device__ __forceinline__ void gload16(const ushort_t* g, void* l) {
  __builtin_amdgcn_global_load_lds(
      (const __attribute__((address_space(1))) void*)g,
      (__attribute__((address_space(3))) void*)l, 16, 0, 0);
}

// ---------- weight prep ----------
__global__ void k_transpose_w(const float* __restrict__ w, float* __restrict__ wT, int CO, int CIKK) {
  int idx = blockIdx.x * 256 + threadIdx.x;
  if (idx >= CO * CIKK) return;
  int co = idx % CO, i = idx / CO;
  wT[idx] = w[co * CIKK + i];
}

// encoder MFMA weight pack: w[co][ci(256)][KH][KW] fp32 ->
// wp[chunk][coT(4)][pl(2)][row(64)][k(32)] bf16 split, chunk = tap*8 + cg
template<int KIND>  // 0: 4x4 (16 taps), 1: 3x3 (9 taps), 2: 1x1 (1 tap)
__global__ void k_prep_enc(const float* __restrict__ w, ushort_t* __restrict__ wp, int total) {
  int idx = blockIdx.x * 256 + threadIdx.x;
  if (idx >= total) return;
  int k = idx & 31, row = (idx >> 5) & 63, pl = (idx >> 11) & 1, coT = (idx >> 12) & 3, chunk = idx >> 14;
  int tap = chunk >> 3, cg = chunk & 7;
  int co = coT * 64 + row, ci = cg * 32 + k;
  int ky, kx, KK, KW;
  if (KIND == 0)      { ky = tap >> 2; kx = tap & 3;       KK = 16; KW = 4; }
  else if (KIND == 1) { ky = tap / 3;  kx = tap - ky * 3;  KK = 9;  KW = 3; }
  else                { ky = 0;        kx = 0;             KK = 1;  KW = 1; }
  float v = w[(co * 256 + ci) * KK + ky * KW + kx];
  ushort_t b0 = f2bf(v);
  wp[idx] = pl ? f2bf(v - bf2f(b0)) : b0;
}

// t1_w [ci][co][ky][kx] -> bf16 [par][tap][c8][co][kk32]
__global__ void k_prep_t1w(const float* __restrict__ w, ushort_t* __restrict__ wb) {
  int idx = blockIdx.x * 256 + threadIdx.x;  // 1048576
  int kk  = idx & 31;
  int co  = (idx >> 5) & 255;
  int c8  = (idx >> 13) & 7;
  int tap = (idx >> 16) & 3;
  int par = idx >> 18;
  int ry = par & 1, rx = (par >> 1) & 1;
  int a = tap >> 1, b = tap & 1;
  int ky = ((ry + 1) & 1) + 2 * a;
  int kx = ((rx + 1) & 1) + 2 * b;
  int ci = c8 * 32 + kk;
  wb[idx] = f2bf(w[((ci * 256 + co) << 4) + ky * 4 + kx]);
}

// t2_w [ci(256)][co(3)][4][4] -> bf16 [par(4)][chunk(32)][co16][k32]
__global__ void k_prep_t2w(const float* __restrict__ w, ushort_t* __restrict__ wb) {
  int idx = blockIdx.x * 256 + threadIdx.x;  // 65536
  int k = idx & 31, co = (idx >> 5) & 15, chunk = (idx >> 9) & 31, par = idx >> 14;
  int tap = chunk >> 3, cg = chunk & 7;
  int a = tap >> 1, b = tap & 1;
  int ry = par & 1, rx = (par >> 1) & 1;
  int ky = ((ry + 1) & 1) + 2 * a;
  int kx = ((rx + 1) & 1) + 2 * b;
  int ci = cg * 32 + k;
  float v = (co < 3) ? w[((ci * 3 + co) << 4) + ky * 4 + kx] : 0.f;
  wb[idx] = f2bf(v);
}

// cnorm[j] = sum_c cb[j][c]^2
__global__ void k_prep_cb(const float* __restrict__ cb, float* __restrict__ cnorm) {
  int idx = blockIdx.x * 256 + threadIdx.x;
  if (idx < 512) {
    float s = 0.f;
    for (int c = 0; c < 64; ++c) { float v = cb[idx * 64 + c]; s = fmaf(v, v, s); }
    cnorm[idx] = s;
  }
}

// ---------- conv1: 3->256, 4x4 s2 p1, relu, output split-bf16 NHWC ----------
__global__ __launch_bounds__(256) void k_conv1_split(
    const float* __restrict__ in, ushort_t* __restrict__ o0, ushort_t* __restrict__ o1,
    const float* __restrict__ wT, const float* __restrict__ bias)
{
  __shared__ float s_in[3 * 360];  // parity-split cols, pitch 20 (2-way free)
  const int tid = threadIdx.x;
  const int lane = tid & 63;
  const int wv = rfl(tid >> 6);
  const int px = lane & 7, py = lane >> 3;
  const int tx = blockIdx.x & 7, ty = blockIdx.x >> 3;
  const int X = tx * 8, Y = ty * 8;
  const int cob = blockIdx.y * 64 + wv * 16;
  const int n = blockIdx.z;
  float acc[16];
#pragma unroll
  for (int i = 0; i < 16; ++i) acc[i] = bias[cob + i];
  const float* inN = in + (size_t)n * 3 * 16384;
  for (int e = tid; e < 3 * 360; e += 256) {
    int col2 = e % 20; int t = e / 20; int row = t % 18; int ci = t / 18;
    int pr = col2 / 10, hc = col2 % 10, ixl = 2 * hc + pr;
    int iy = 2 * Y - 1 + row, ix = 2 * X - 1 + ixl;
    float v = 0.f;
    if (ixl < 18 && (unsigned)iy < 128u && (unsigned)ix < 128u)
      v = inN[ci * 16384 + iy * 128 + ix];
    s_in[e] = v;
  }
  __syncthreads();
  const float* wc = wT + cob;
#pragma unroll
  for (int c = 0; c < 3; ++c) {
    const float* base = s_in + c * 360 + py * 40 + px;
#pragma unroll
    for (int ky = 0; ky < 4; ++ky) {
#pragma unroll
      for (int kx = 0; kx < 4; ++kx) {
        float iv = base[ky * 20 + (kx & 1) * 10 + (kx >> 1)];
        const float* w = wc + (size_t)(c * 16 + ky * 4 + kx) * 256;  // uniform
#pragma unroll
        for (int i = 0; i < 16; ++i) acc[i] = fmaf(iv, w[i], acc[i]);
      }
    }
  }
  const int pxg = n * 4096 + (Y + py) * 64 + (X + px);
  uint p0[8], p1[8];
#pragma unroll
  for (int i = 0; i < 8; ++i) {
    float va = fmaxf(acc[2 * i], 0.f), vb = fmaxf(acc[2 * i + 1], 0.f);
    ushort_t a0 = f2bf(va), b0 = f2bf(vb);
    ushort_t a1 = f2bf(va - bf2f(a0)), b1 = f2bf(vb - bf2f(b0));
    p0[i] = (uint)a0 | ((uint)b0 << 16);
    p1[i] = (uint)a1 | ((uint)b1 << 16);
  }
  ushort_t* d0 = o0 + (size_t)pxg * 256 + cob;
  ushort_t* d1 = o1 + (size_t)pxg * 256 + cob;
  uint4 v0a; v0a.x = p0[0]; v0a.y = p0[1]; v0a.z = p0[2]; v0a.w = p0[3];
  uint4 v0b; v0b.x = p0[4]; v0b.y = p0[5]; v0b.z = p0[6]; v0b.w = p0[7];
  uint4 v1a; v1a.x = p1[0]; v1a.y = p1[1]; v1a.z = p1[2]; v1a.w = p1[3];
  uint4 v1b; v1b.x = p1[4]; v1b.y = p1[5]; v1b.z = p1[6]; v1b.w = p1[7];
  *(uint4*)d0 = v0a; *(uint4*)(d0 + 8) = v0b;
  *(uint4*)d1 = v1a; *(uint4*)(d1 + 8) = v1b;
}

// ---------- conv2 implicit-GEMM MFMA, split-K=2, plain-store partial --------
// Block: 64co x 128px, 4 waves. A direct-from-global (dual reg set, 2-chunk
// unroll); B via global_load_lds dbuf. grid (pxT 64, coT 4, kz 2).
__global__ __launch_bounds__(256) void k_enc_mfma_split(
    const ushort_t* __restrict__ x0, const ushort_t* __restrict__ x1,
    const ushort_t* __restrict__ wp, float* __restrict__ part)
{
  __shared__ ushort_t smem[2][8192];   // B only: [pl][128row][32k] per buf (16KB)
  const int tid = threadIdx.x, lane = tid & 63, wv = tid >> 6;
  const int l15 = lane & 15, q = lane >> 4;
  const int pxT = blockIdx.x, coT = blockIdx.y;
  const int CH0 = blockIdx.z * 64, CH1 = CH0 + 64;
  f32x4 acc[4][2];
#pragma unroll
  for (int m = 0; m < 4; ++m)
#pragma unroll
    for (int n = 0; n < 2; ++n) acc[m][n] = (f32x4){0.f, 0.f, 0.f, 0.f};

  // B staging: thread handles rows r0 and r0+64, 16B quarter kq
  const int r0 = tid >> 2, kq = tid & 3;
  int bimg[2], bu[2], bvc[2];
#pragma unroll
  for (int r = 0; r < 2; ++r) {
    int bpx = pxT * 128 + r0 + r * 64;
    bimg[r] = bpx >> 10; int bp = bpx & 1023; bu[r] = bp >> 5; bvc[r] = bp & 31;
  }
  const ushort_t* srcB[2][2];  // [row r][plane p], excludes cg offset
  int ptap = -1;
  auto retap = [&](int tap) {
    ptap = tap;
    int ky = tap >> 2, kx = tap & 3;
#pragma unroll
    for (int r = 0; r < 2; ++r) {
      int iy = 2 * bu[r] - 1 + ky, ix = 2 * bvc[r] - 1 + kx;
      bool v = ((unsigned)iy < 64u) && ((unsigned)ix < 64u);
      size_t rowb = ((size_t)(bimg[r] * 4096 + iy * 64 + ix)) << 8;
      srcB[r][0] = (v ? (x0 + rowb) : g_zpad) + kq * 8;
      srcB[r][1] = (v ? (x1 + rowb) : g_zpad) + kq * 8;
    }
  };

  const int wvb = wv * 1024;  // wave-uniform byte base (lane*16 auto)
  auto stage = [&](int chunk, int bi) {
    const int tap = chunk >> 3, cg = chunk & 7;
    if (tap != ptap) retap(tap);
    char* bufb = (char*)smem[bi];
    const int ko = cg * 32;
    gload16(srcB[0][0] + ko, bufb + wvb);            // pl0 rows 0-63
    gload16(srcB[1][0] + ko, bufb + 4096 + wvb);     // pl0 rows 64-127
    gload16(srcB[0][1] + ko, bufb + 8192 + wvb);     // pl1 rows 0-63
    gload16(srcB[1][1] + ko, bufb + 12288 + wvb);    // pl1 rows 64-127
  };
  const ushort_t* wpl = wp + l15 * 32 + q * 8 + ((size_t)coT << 12);
  auto loadA = [&](int chunk, short8 (&af)[4][2]) {
    const ushort_t* ap = wpl + ((size_t)chunk << 14);
#pragma unroll
    for (int m = 0; m < 4; ++m) {
      af[m][0] = *(const short8*)(ap + m * 512);
      af[m][1] = *(const short8*)(ap + 2048 + m * 512);
    }
  };
  auto compute = [&](short8 (&af)[4][2], const ushort_t* buf) {
    short8 bf[2][2];
#pragma unroll
    for (int n = 0; n < 2; ++n)
#pragma unroll
      for (int pl = 0; pl < 2; ++pl)
        bf[n][pl] = *(const short8*)(buf + pl * 4096 + (wv * 32 + n * 16 + l15) * 32 + q * 8);
#pragma unroll
    for (int m = 0; m < 4; ++m)
#pragma unroll
      for (int n = 0; n < 2; ++n) {
        acc[m][n] = __builtin_amdgcn_mfma_f32_16x16x32_bf16(af[m][0], bf[n][0], acc[m][n], 0, 0, 0);
        acc[m][n] = __builtin_amdgcn_mfma_f32_16x16x32_bf16(af[m][0], bf[n][1], acc[m][n], 0, 0, 0);
        acc[m][n] = __builtin_amdgcn_mfma_f32_16x16x32_bf16(af[m][1], bf[n][0], acc[m][n], 0, 0, 0);
      }
  };

  short8 afC[4][2], afN[4][2];
  stage(CH0, 0);
  loadA(CH0, afC);
  __syncthreads();
  int cur = 0;
  for (int c = CH0; c < CH1; c += 2) {
    // even chunk: compute c with afC; prefetch chunk c+1 (A regs + B LDS)
    stage(c + 1, cur ^ 1);
    loadA(c + 1, afN);
    compute(afC, smem[cur]);
    __syncthreads();
    cur ^= 1;
    // odd chunk
    if (c + 2 < CH1) { stage(c + 2, cur ^ 1); loadA(c + 2, afC); }
    compute(afN, smem[cur]);
    __syncthreads();
    cur ^= 1;
  }

  // plain stores to this kz's private partial slice (deterministic)
  float* pz = part + ((size_t)blockIdx.z << 21);
#pragma unroll
  for (int m = 0; m < 4; ++m) {
#pragma unroll
    for (int n = 0; n < 2; ++n) {
#pragma unroll
      for (int r = 0; r < 4; ++r) {
        const int co_l = m * 16 + q * 4 + r;
        const int px_l = wv * 32 + n * 16 + l15;
        const int px = pxT * 128 + px_l;
        const int img = px >> 10, pp = px & 1023;
        const size_t ha = ((size_t)(img * 256 + coT * 64 + co_l)) * 1024 + pp;
        pz[ha] = acc[m][n][r];
      }
    }
  }
}

// ---------- 3x3 implicit-GEMM MFMA, split-K=2 (by cg), halo-staged B --------
// Per cg: stage [2pl][6row][34col][32k] halo ONCE (26KB), consume by all 9
// taps via computed ds_read offsets. 1 barrier per cg. A direct-from-global.
// grid (pxT 64, coT 4, kz 2); kz z covers cg z*4..z*4+3.
__global__ __launch_bounds__(256) void k_enc_mfma_3x3(
    const ushort_t* __restrict__ x0, const ushort_t* __restrict__ x1,
    const ushort_t* __restrict__ wp, float* __restrict__ part)
{
  __shared__ ushort_t smem[2][14336];  // halo buf padded to 7*4096B
  const int tid = threadIdx.x, lane = tid & 63, wv = tid >> 6;
  const int l15 = lane & 15, q = lane >> 4;
  const int pxT = blockIdx.x, coT = blockIdx.y;
  const int CG0 = blockIdx.z * 4, CG1 = CG0 + 4;
  const int img = pxT >> 3;          // 8 blocks per 32x32 image
  const int U0 = (pxT & 7) * 4;      // base output row of this 128px strip
  f32x4 acc[4][2];
#pragma unroll
  for (int m = 0; m < 4; ++m)
#pragma unroll
    for (int n = 0; n < 2; ++n) acc[m][n] = (f32x4){0.f, 0.f, 0.f, 0.f};

  // precompute 7 DMA source pointers (halo slot -> global addr, sans cg)
  // slot = pl*816 + r*136 + c*4 + kq ; halo (pl,r,c) = plane, row U0-1+r, col c-1
  const ushort_t* srcp[7];
#pragma unroll
  for (int i = 0; i < 7; ++i) {
    int slot = i * 256 + tid;
    int pl = slot >= 816 ? 1 : 0;
    int rem = slot - pl * 816;
    int rr = rem / 136;
    int c4 = rem - rr * 136;
    int cc = c4 >> 2, kq2 = c4 & 3;
    int iy = U0 - 1 + rr, ix = cc - 1;
    bool valid = (slot < 1632) && ((unsigned)iy < 32u) && ((unsigned)ix < 32u);
    const ushort_t* base = valid
        ? ((pl ? x1 : x0) + (((size_t)(img * 1024 + iy * 32 + ix)) << 8))
        : g_zpad;
    srcp[i] = base + kq2 * 8;
  }
  const int wvb = wv * 1024;
  auto stageH = [&](int cg, int bi) {
    char* bufb = (char*)smem[bi];
    const int ko = cg * 32;
#pragma unroll
    for (int i = 0; i < 7; ++i) gload16(srcp[i] + ko, bufb + i * 4096 + wvb);
  };
  const ushort_t* wpl = wp + l15 * 32 + q * 8 + ((size_t)coT << 12);

  stageH(CG0, 0);
  __syncthreads();
  int cur = 0;
  for (int cg = CG0; cg < CG1; ++cg) {
    if (cg + 1 < CG1) stageH(cg + 1, cur ^ 1);
    const ushort_t* buf = smem[cur];
#pragma unroll 3
    for (int tap = 0; tap < 9; ++tap) {
      const int ky = tap / 3, kx = tap - ky * 3;
      const int chunk = tap * 8 + cg;
      const ushort_t* ap = wpl + ((size_t)chunk << 14);
      short8 af[4][2], bf[2][2];
#pragma unroll
      for (int m = 0; m < 4; ++m) {
        af[m][0] = *(const short8*)(ap + m * 512);
        af[m][1] = *(const short8*)(ap + 2048 + m * 512);
      }
      const int r = wv + ky;
#pragma unroll
      for (int n = 0; n < 2; ++n)
#pragma unroll
        for (int pl = 0; pl < 2; ++pl)
          bf[n][pl] = *(const short8*)(buf + pl * 6528 + r * 1088 + (n * 16 + l15 + kx) * 32 + q * 8);
#pragma unroll
      for (int m = 0; m < 4; ++m)
#pragma unroll
        for (int n = 0; n < 2; ++n) {
          acc[m][n] = __builtin_amdgcn_mfma_f32_16x16x32_bf16(af[m][0], bf[n][0], acc[m][n], 0, 0, 0);
          acc[m][n] = __builtin_amdgcn_mfma_f32_16x16x32_bf16(af[m][0], bf[n][1], acc[m][n], 0, 0, 0);
          acc[m][n] = __builtin_amdgcn_mfma_f32_16x16x32_bf16(af[m][1], bf[n][0], acc[m][n], 0, 0, 0);
        }
    }
    __syncthreads();
    cur ^= 1;
  }

  float* pz = part + ((size_t)blockIdx.z << 21);
#pragma unroll
  for (int m = 0; m < 4; ++m) {
#pragma unroll
    for (int n = 0; n < 2; ++n) {
#pragma unroll
      for (int r = 0; r < 4; ++r) {
        const int co_l = m * 16 + q * 4 + r;
        const int px_l = wv * 32 + n * 16 + l15;
        const int px = pxT * 128 + px_l;
        const int imgp = px >> 10, pp = px & 1023;
        const size_t ha = ((size_t)(imgp * 256 + coT * 64 + co_l)) * 1024 + pp;
        pz[ha] = acc[m][n][r];
      }
    }
  }
}

// ---------- epilogue for split convs ----------
// v = p0 + p1 + bias (fixed order -> deterministic).
// WH (conv2): v=relu(v); h32=v; split v.   !WH (3x3): split relu(v).
template<bool WH>
__global__ __launch_bounds__(256) void k_enc_epi(
    const float* __restrict__ part, float* __restrict__ h32,
    ushort_t* __restrict__ s0, ushort_t* __restrict__ s1,
    const float* __restrict__ bias)
{
  const int px = blockIdx.x * 256 + threadIdx.x;  // 8192
  const int co0 = blockIdx.y * 16;
  const int img = px >> 10, pp = px & 1023;
  const float* part1 = part + (1u << 21);
  uint p0[8], p1[8];
#pragma unroll
  for (int i = 0; i < 8; ++i) {
    size_t ha = ((size_t)(img * 256 + co0 + 2 * i)) * 1024 + pp;
    size_t hb = ha + 1024;
    float va = part[ha] + part1[ha] + bias[co0 + 2 * i];
    float vb = part[hb] + part1[hb] + bias[co0 + 2 * i + 1];
    float sa, sb;
    if (WH) {
      va = fmaxf(va, 0.f); vb = fmaxf(vb, 0.f);
      h32[ha] = va; h32[hb] = vb; sa = va; sb = vb;
    } else { sa = fmaxf(va, 0.f); sb = fmaxf(vb, 0.f); }
    ushort_t a0 = f2bf(sa), b0 = f2bf(sb);
    p0[i] = (uint)a0 | ((uint)b0 << 16);
    p1[i] = (uint)f2bf(sa - bf2f(a0)) | ((uint)f2bf(sb - bf2f(b0)) << 16);
  }
  ushort_t* d0 = s0 + (size_t)px * 256 + co0;
  ushort_t* d1 = s1 + (size_t)px * 256 + co0;
  uint4 v0a; v0a.x = p0[0]; v0a.y = p0[1]; v0a.z = p0[2]; v0a.w = p0[3];
  uint4 v0b; v0b.x = p0[4]; v0b.y = p0[5]; v0b.z = p0[6]; v0b.w = p0[7];
  uint4 v1a; v1a.x = p1[0]; v1a.y = p1[1]; v1a.z = p1[2]; v1a.w = p1[3];
  uint4 v1b; v1b.x = p1[4]; v1b.y = p1[5]; v1b.z = p1[6]; v1b.w = p1[7];
  *(uint4*)d0 = v0a; *(uint4*)(d0 + 8) = v0b;
  *(uint4*)d1 = v1a; *(uint4*)(d1 + 8) = v1b;
}

// ---------- residual 1x1 MFMA (fused epilogue) ----------
// h += conv1x1(x) + bias; write h32; if WS also split(relu(h)) via LDS shuffle.
// R6: A direct-from-global; B via global_load_lds dbuf (8 chunks).
template<bool WS>
__global__ __launch_bounds__(256) void k_enc_mfma(
    const ushort_t* __restrict__ x0, const ushort_t* __restrict__ x1,
    const ushort_t* __restrict__ wp, const float* __restrict__ bias,
    float* __restrict__ h32, ushort_t* __restrict__ sp0, ushort_t* __restrict__ sp1)
{
  __shared__ ushort_t smem[18432];   // B dbuf 2x8192; WS epilogue reuses [0,18432)
  const int tid = threadIdx.x, lane = tid & 63, wv = tid >> 6;
  const int l15 = lane & 15, q = lane >> 4;
  const int pxT = blockIdx.x, coT = blockIdx.y;
  f32x4 acc[4][2];
#pragma unroll
  for (int m = 0; m < 4; ++m)
#pragma unroll
    for (int n = 0; n < 2; ++n) acc[m][n] = (f32x4){0.f, 0.f, 0.f, 0.f};

  const int r0 = tid >> 2, kq = tid & 3;
  const ushort_t* srcB[2][2];
#pragma unroll
  for (int r = 0; r < 2; ++r) {
    size_t rowb = ((size_t)(pxT * 128 + r0 + r * 64)) << 8;
    srcB[r][0] = x0 + rowb + kq * 8;
    srcB[r][1] = x1 + rowb + kq * 8;
  }
  const int wvb = wv * 1024;
  auto stage = [&](int c, int bi) {
    char* bufb = (char*)(smem + bi * 8192);
    const int ko = c * 32;
    gload16(srcB[0][0] + ko, bufb + wvb);
    gload16(srcB[1][0] + ko, bufb + 4096 + wvb);
    gload16(srcB[0][1] + ko, bufb + 8192 + wvb);
    gload16(srcB[1][1] + ko, bufb + 12288 + wvb);
  };
  const ushort_t* wpl = wp + l15 * 32 + q * 8 + ((size_t)coT << 12);
  auto loadA = [&](int c, short8 (&af)[4][2]) {
    const ushort_t* ap = wpl + ((size_t)c << 14);
#pragma unroll
    for (int m = 0; m < 4; ++m) {
      af[m][0] = *(const short8*)(ap + m * 512);
      af[m][1] = *(const short8*)(ap + 2048 + m * 512);
    }
  };
  auto compute = [&](short8 (&af)[4][2], const ushort_t* buf) {
    short8 bf[2][2];
#pragma unroll
    for (int n = 0; n < 2; ++n)
#pragma unroll
      for (int pl = 0; pl < 2; ++pl)
        bf[n][pl] = *(const short8*)(buf + pl * 4096 + (wv * 32 + n * 16 + l15) * 32 + q * 8);
#pragma unroll
    for (int m = 0; m < 4; ++m)
#pragma unroll
      for (int n = 0; n < 2; ++n) {
        acc[m][n] = __builtin_amdgcn_mfma_f32_16x16x32_bf16(af[m][0], bf[n][0], acc[m][n], 0, 0, 0);
        acc[m][n] = __builtin_amdgcn_mfma_f32_16x16x32_bf16(af[m][0], bf[n][1], acc[m][n], 0, 0, 0);
        acc[m][n] = __builtin_amdgcn_mfma_f32_16x16x32_bf16(af[m][1], bf[n][0], acc[m][n], 0, 0, 0);
      }
  };

  short8 afC[4][2], afN[4][2];
  stage(0, 0);
  loadA(0, afC);
  __syncthreads();
  int cur = 0;
  for (int c = 0; c < 8; c += 2) {
    stage(c + 1, cur ^ 1);
    loadA(c + 1, afN);
    compute(afC, smem + cur * 8192);
    __syncthreads();
    cur ^= 1;
    if (c + 2 < 8) { stage(c + 2, cur ^ 1); loadA(c + 2, afC); }
    compute(afN, smem + cur * 8192);
    __syncthreads();
    cur ^= 1;
  }

#pragma unroll
  for (int m = 0; m < 4; ++m) {
#pragma unroll
    for (int n = 0; n < 2; ++n) {
#pragma unroll
      for (int r = 0; r < 4; ++r) {
        const int co_l = m * 16 + q * 4 + r;
        const int px_l = wv * 32 + n * 16 + l15;
        float v = acc[m][n][r] + bias[coT * 64 + co_l];
        const int px = pxT * 128 + px_l;
        const int img = px >> 10, pp = px & 1023;
        const size_t ha = ((size_t)(img * 256 + coT * 64 + co_l)) * 1024 + pp;
        v += h32[ha];
        h32[ha] = v;
        if (WS) {
          float sv = fmaxf(v, 0.f);
          ushort_t b0 = f2bf(sv);
          smem[px_l * 72 + co_l] = b0;
          smem[9216 + px_l * 72 + co_l] = f2bf(sv - bf2f(b0));
        }
      }
    }
  }
  if (WS) {
    __syncthreads();
#pragma unroll
    for (int i = 0; i < 8; ++i) {
      int idx = tid + 256 * i;
      int pl = idx >> 10, w2 = idx & 1023, pxl = w2 >> 3, g = w2 & 7;
      uint4 vv = *(const uint4*)(smem + pl * 9216 + pxl * 72 + g * 8);
      ushort_t* dst = (pl ? sp1 : sp0) + ((size_t)(pxT * 128 + pxl)) * 256 + coT * 64 + g * 8;
      *(uint4*)dst = vv;
    }
  }
}

// ---------- 1x1 conv fp32 (to_z only) ----------
__global__ __launch_bounds__(256) void k_conv1x1(
    const float* __restrict__ in, float* __restrict__ out,
    const float* __restrict__ wT, const float* __restrict__ bias,
    int CI, int CO, int P)
{
  const int p = blockIdx.x * 256 + threadIdx.x;
  const int cob = blockIdx.y * 16;
  const int n = blockIdx.z;
  const float* inN = in + (size_t)n * CI * P + p;
  float acc[16];
#pragma unroll
  for (int i = 0; i < 16; ++i) acc[i] = bias[cob + i];
  const float* wr = wT + cob;
#pragma unroll 4
  for (int ci = 0; ci < CI; ++ci) {
    float iv = inN[(size_t)ci * P];
    const float* w = wr + (size_t)ci * CO;  // uniform
#pragma unroll
    for (int i = 0; i < 16; ++i) acc[i] = fmaf(iv, w[i], acc[i]);
  }
  float* outN = out + (size_t)n * CO * P + p;
#pragma unroll
  for (int i = 0; i < 16; ++i) outN[(size_t)(cob + i) * P] = acc[i];
}

// ---------- VQ partial: 16 chunks of 32 codes; per-j math identical ----------
__global__ __launch_bounds__(256) void k_vq_part(
    const float* __restrict__ z_e, const float* __restrict__ cb,
    const float* __restrict__ cnorm, float* __restrict__ pbest, int* __restrict__ pbid)
{
  int g = blockIdx.x * 256 + threadIdx.x;  // 8192 points
  int chunk = blockIdx.y;                  // 16 chunks
  int img = g >> 10, p = g & 1023;
  const float* zp = z_e + (size_t)img * 64 * 1024 + p;
  float z[64];
#pragma unroll
  for (int c = 0; c < 64; ++c) z[c] = zp[(size_t)c * 1024];
  float best = 3.4e38f; int bid = chunk << 5;
  const int j0 = chunk << 5;
  for (int j = j0; j < j0 + 32; ++j) {
    const float* cj = cb + j * 64;  // uniform -> scalar loads
    float m = 0.f;
#pragma unroll
    for (int c = 0; c < 64; ++c) m = fmaf(z[c], cj[c], m);
    float d = fmaf(-2.f, m, cnorm[j]);
    if (d < best) { best = d; bid = j; }  // strict <: first-min within chunk
  }
  pbest[chunk * 8192 + g] = best;
  pbid[chunk * 8192 + g] = bid;
}

// ---------- VQ reduce: argmin across chunks (ascending -> np.argmin) + e_k ----------
__global__ __launch_bounds__(256) void k_vq_reduce(
    const float* __restrict__ pbest, const int* __restrict__ pbid,
    const float* __restrict__ cb, float* __restrict__ ids_f, float* __restrict__ ek)
{
  int g = blockIdx.x * 256 + threadIdx.x;  // 8192
  float best = 3.4e38f; int bid = 0;
#pragma unroll
  for (int ch = 0; ch < 16; ++ch) {
    float d = pbest[ch * 8192 + g];
    int b = pbid[ch * 8192 + g];
    if (d < best) { best = d; bid = b; }
  }
  ids_f[g] = (float)bid;
  int img = g >> 10, p = g & 1023;
  const float* cbid = cb + bid * 64;
  float* ekp = ek + (size_t)img * 64 * 1024 + p;
#pragma unroll
  for (int c = 0; c < 64; ++c) ekp[(size_t)c * 1024] = cbid[c];
}

// ---------- from_z 1x1 (64->256) + relu -> NHWC bf16 ----------
__global__ __launch_bounds__(256) void k_from_z(
    const float* __restrict__ ek, ushort_t* __restrict__ nhwc,
    const float* __restrict__ wT, const float* __restrict__ bias)
{
  const int p = blockIdx.x * 256 + threadIdx.x;  // 0..1023
  const int co0 = blockIdx.y * 16;
  const int n = blockIdx.z;
  const float* inN = ek + (size_t)n * 64 * 1024 + p;
  float acc[16];
#pragma unroll
  for (int i = 0; i < 16; ++i) acc[i] = bias[co0 + i];
#pragma unroll 4
  for (int ci = 0; ci < 64; ++ci) {
    float iv = inN[(size_t)ci * 1024];
    const float* w = wT + (size_t)ci * 256 + co0;  // uniform
#pragma unroll
    for (int i = 0; i < 16; ++i) acc[i] = fmaf(iv, w[i], acc[i]);
  }
  uint pk[8];
#pragma unroll
  for (int i = 0; i < 8; ++i) {
    ushort_t lo = f2bf(fmaxf(acc[2 * i], 0.f));
    ushort_t hi = f2bf(fmaxf(acc[2 * i + 1], 0.f));
    pk[i] = (uint)lo | ((uint)hi << 16);
  }
  ushort_t* op = nhwc + (((size_t)n * 1024 + p) * 256 + co0);
  uint4 v0; v0.x = pk[0]; v0.y = pk[1]; v0.z = pk[2]; v0.w = pk[3];
  uint4 v1; v1.x = pk[4]; v1.y = pk[5]; v1.z = pk[6]; v1.w = pk[7];
  *(uint4*)(op) = v0;
  *(uint4*)(op + 8) = v1;
}

// ---------- t1 convtranspose 4x4 s2 p1, 256->256, bf16 MFMA, relu -> bf16 NHWC
// R6: A direct-from-global (dual reg set); B via global_load_lds dbuf.
__global__ __launch_bounds__(256) void k_mfma_t1(
    const ushort_t* __restrict__ nhwc, const ushort_t* __restrict__ wb,
    const float* __restrict__ bias, ushort_t* __restrict__ t1o)
{
  __shared__ ushort_t smem[2][4096];   // B only: [128row][32k] per buf (8KB)
  const int tid = threadIdx.x;
  const int lane = tid & 63;
  const int wv = tid >> 6;
  const int wm = wv & 1, wn = wv >> 1;
  const int l15 = lane & 15, q = lane >> 4;
  const int pxT = blockIdx.x, coT = blockIdx.y, par = blockIdx.z;
  const int ry = par & 1, rx = (par >> 1) & 1;
  const int pxbase = pxT * 128;
  const int img = pxbase >> 10;
  f32x4 acc[4][4];
#pragma unroll
  for (int i = 0; i < 4; ++i)
#pragma unroll
    for (int j = 0; j < 4; ++j) acc[i][j] = (f32x4){0.f, 0.f, 0.f, 0.f};

  const int srow = tid >> 2, kg = tid & 3;
  int bu2[2], bv2[2];
#pragma unroll
  for (int r = 0; r < 2; ++r) {
    int px = pxbase + srow + r * 64;
    bu2[r] = (px >> 5) & 31; bv2[r] = px & 31;
  }
  const ushort_t* nb[2];
  int ptap = -1;
  auto retap = [&](int tap) {
    ptap = tap;
    int ta = tap >> 1, tb = tap & 1;
#pragma unroll
    for (int r = 0; r < 2; ++r) {
      int iy = bu2[r] + ry - ta, ix = bv2[r] + rx - tb;
      bool v = ((unsigned)iy < 32u) && ((unsigned)ix < 32u);
      nb[r] = (v ? (nhwc + (((size_t)(img * 1024 + iy * 32 + ix)) << 8)) : g_zpad) + kg * 8;
    }
  };
  const int wvb = wv * 1024;
  auto stage = [&](int c, int bi) {
    const int tap = c >> 3, c8 = c & 7;
    if (tap != ptap) retap(tap);
    char* bufb = (char*)smem[bi];
    const int ko = c8 * 32;
    gload16(nb[0] + ko, bufb + wvb);
    gload16(nb[1] + ko, bufb + 4096 + wvb);
  };
  const ushort_t* wA = wb + coT * 4096 + (wm * 64 + l15) * 32 + q * 8;
  auto loadA = [&](int c, short8 (&af)[4]) {
    const int tap = c >> 3, c8 = c & 7;
    const ushort_t* ap = wA + ((size_t)((par * 4 + tap) * 8 + c8) << 13);
#pragma unroll
    for (int i = 0; i < 4; ++i) af[i] = *(const short8*)(ap + i * 512);
  };
  auto compute = [&](short8 (&af)[4], const ushort_t* buf) {
    short8 bfr[4];
#pragma unroll
    for (int j = 0; j < 4; ++j)
      bfr[j] = *(const short8*)(buf + (wn * 64 + j * 16 + l15) * 32 + q * 8);
#pragma unroll
    for (int i = 0; i < 4; ++i)
#pragma unroll
      for (int j = 0; j < 4; ++j)
        acc[i][j] = __builtin_amdgcn_mfma_f32_16x16x32_bf16(af[i], bfr[j], acc[i][j], 0, 0, 0);
  };

  short8 afC[4], afN[4];
  stage(0, 0);
  loadA(0, afC);
  __syncthreads();
  int cur = 0;
  for (int c = 0; c < 32; c += 2) {
    stage(c + 1, cur ^ 1);
    loadA(c + 1, afN);
    compute(afC, smem[cur]);
    __syncthreads();
    cur ^= 1;
    if (c + 2 < 32) { stage(c + 2, cur ^ 1); loadA(c + 2, afC); }
    compute(afN, smem[cur]);
    __syncthreads();
    cur ^= 1;
  }

#pragma unroll
  for (int i = 0; i < 4; ++i) {
    int co = coT * 128 + wm * 64 + i * 16 + q * 4;
#pragma unroll
    for (int j = 0; j < 4; ++j) {
      int px = pxbase + wn * 64 + j * 16 + l15;
      int u = (px >> 5) & 31, vv = px & 31;
      int oy = 2 * u + ry, ox = 2 * vv + rx;
      ushort_t e0 = f2bf(fmaxf(acc[i][j][0] + bias[co + 0], 0.f));
      ushort_t e1 = f2bf(fmaxf(acc[i][j][1] + bias[co + 1], 0.f));
      ushort_t e2 = f2bf(fmaxf(acc[i][j][2] + bias[co + 2], 0.f));
      ushort_t e3 = f2bf(fmaxf(acc[i][j][3] + bias[co + 3], 0.f));
      uint2 pk; pk.x = (uint)e0 | ((uint)e1 << 16); pk.y = (uint)e2 | ((uint)e3 << 16);
      *(uint2*)(t1o + ((size_t)(img * 4096 + oy * 64 + ox) * 256 + co)) = pk;
    }
  }
}

// ---------- t2 convtranspose 4x4 s2 p1, 256->3, bf16 MFMA, sigmoid ----------
__global__ __launch_bounds__(256) void k_mfma_t2(
    const ushort_t* __restrict__ t1o, const ushort_t* __restrict__ wb,
    const float* __restrict__ bias, float* __restrict__ out)
{
  __shared__ ushort_t sA2[256 * 32];
  __shared__ ushort_t sB2[16 * 32];
  const int tid = threadIdx.x, lane = tid & 63, wv = tid >> 6;
  const int l15 = lane & 15, q = lane >> 4;
  const int pxb = blockIdx.x * 256;
  const int par = blockIdx.y;
  const int ry = par & 1, rx = (par >> 1) & 1;
  f32x4 acc[4];
#pragma unroll
  for (int m = 0; m < 4; ++m) acc[m] = (f32x4){0.f, 0.f, 0.f, 0.f};
  const int kg = tid & 3;
  const int ssw = ((tid >> 2) & 7) << 3;
  size_t rb[4]; bool rv[4];
  for (int chunk = 0; chunk < 32; ++chunk) {
    const int tap = chunk >> 3, cg = chunk & 7;
    const int a = tap >> 1, b = tap & 1;
    if ((chunk & 7) == 0) {
#pragma unroll
      for (int i = 0; i < 4; ++i) {
        int row = (tid >> 2) + 64 * i;
        int px = pxb + row;
        int img = px >> 12, p = px & 4095, u = p >> 6, v = p & 63;
        int iy = u + ry - a, ix = v + rx - b;
        rv[i] = ((unsigned)iy < 64u) && ((unsigned)ix < 64u);
        rb[i] = ((size_t)(img * 4096 + iy * 64 + ix)) << 8;
      }
    }
    uint4 av[4];
#pragma unroll
    for (int i = 0; i < 4; ++i) {
      if (rv[i]) av[i] = *(const uint4*)(t1o + rb[i] + cg * 32 + kg * 8);
      else { av[i].x = 0; av[i].y = 0; av[i].z = 0; av[i].w = 0; }
    }
    uint4 bv;
    if (tid < 64) bv = *(const uint4*)(wb + ((size_t)(par * 32 + chunk)) * 512 + tid * 8);
    __syncthreads();
#pragma unroll
    for (int i = 0; i < 4; ++i)
      *(uint4*)(sA2 + (((((tid >> 2) + 64 * i) * 32) + kg * 8) ^ ssw)) = av[i];
    if (tid < 64) *(uint4*)(sB2 + ((tid * 8) ^ ssw)) = bv;
    __syncthreads();
    short8 bf = *(const short8*)(sB2 + ((l15 * 32 + q * 8) ^ ((l15 & 7) << 3)));
#pragma unroll
    for (int m = 0; m < 4; ++m) {
      const int row = wv * 64 + m * 16 + l15;
      short8 af = *(const short8*)(sA2 + ((row * 32 + q * 8) ^ ((row & 7) << 3)));
      acc[m] = __builtin_amdgcn_mfma_f32_16x16x32_bf16(af, bf, acc[m], 0, 0, 0);
    }
    __syncthreads();
  }
  const int co = l15;
  if (co < 3) {
    float bco = bias[co];
#pragma unroll
    for (int m = 0; m < 4; ++m) {
#pragma unroll
      for (int r = 0; r < 4; ++r) {
        int px = pxb + wv * 64 + m * 16 + q * 4 + r;
        int img = px >> 12, p = px & 4095, u = p >> 6, v = p & 63;
        size_t addr = ((size_t)(img * 3 + co)) * 16384 + (2 * u + ry) * 128 + (2 * v + rx);
        out[addr] = 1.f / (1.f + expf(-(acc[m][r] + bco)));
      }
    }
  }
}

// ---------------------------------------------------------------------------
extern "C" void kernel_launch(void* const* d_in, const int* in_sizes, int n_in,
                              void* d_out, int out_size, void* d_ws, size_t ws_size,
                              hipStream_t stream) {
  (void)in_sizes; (void)n_in; (void)out_size; (void)ws_size;
  const float* x      = (const float*)d_in[0];
  const float* c1_w   = (const float*)d_in[1];
  const float* c1_b   = (const float*)d_in[2];
  const float* c2_w   = (const float*)d_in[3];
  const float* c2_b   = (const float*)d_in[4];
  const float* r0_w3  = (const float*)d_in[5];
  const float* r0_b3  = (const float*)d_in[6];
  const float* r0_w1  = (const float*)d_in[7];
  const float* r0_b1  = (const float*)d_in[8];
  const float* r1_w3  = (const float*)d_in[9];
  const float* r1_b3  = (const float*)d_in[10];
  const float* r1_w1  = (const float*)d_in[11];
  const float* r1_b1  = (const float*)d_in[12];
  const float* to_z_w = (const float*)d_in[13];
  const float* to_z_b = (const float*)d_in[14];
  const float* cb     = (const float*)d_in[15];
  const float* from_z_w = (const float*)d_in[16];
  const float* from_z_b = (const float*)d_in[17];
  const float* t1_w   = (const float*)d_in[18];
  const float* t1_b   = (const float*)d_in[19];
  const float* t2_w   = (const float*)d_in[20];
  const float* t2_b   = (const float*)d_in[21];

  float* wsf = (float*)d_ws;
  // Era-choreographed regions (float offsets) — see R3 comments; unchanged.
  ushort_t* xs1p0 = (ushort_t*)(wsf + 0);
  ushort_t* xs1p1 = (ushort_t*)(wsf + 4194304);
  float*    cp0   = wsf + 8388608;               // conv2 partial kz0 (= h32 slot)
  float*    h32   = wsf + 8388608;
  float*    qp0   = wsf + 4194304;               // 3x3 partials (xs1p1 slot, dead)
  ushort_t* sE0   = (ushort_t*)(wsf + 0);        // split ping [0,1.05M)
  ushort_t* sE1   = (ushort_t*)(wsf + 1048576);  // split ping [1.05,2.1M)
  ushort_t* sF0   = (ushort_t*)(wsf + 2097152);  // split pong [2.1,3.15M)
  ushort_t* sF1   = (ushort_t*)(wsf + 3145728);  // split pong [3.15,4.19M)
  float*    pbest = wsf + 0;                     // vq-era
  int*      pbid  = (int*)(wsf + 131072);        // vq-era
  ushort_t* t1out = (ushort_t*)(wsf + 2097152);  // dec-era [2.1M, 6.29M)
  ushort_t* decn  = (ushort_t*)(wsf + 6291456);  // dec-era [6.29M, 7.34M)
  ushort_t* wp_c2   = (ushort_t*)(wsf + 12582912);
  ushort_t* wp_r0w3 = (ushort_t*)(wsf + 13631488);
  ushort_t* wp_r1w3 = (ushort_t*)(wsf + 14221312);
  ushort_t* wp_r0w1 = (ushort_t*)(wsf + 14811136);
  ushort_t* wp_r1w1 = (ushort_t*)(wsf + 14876672);
  float*    wt_c1   = wsf + 14942208;
  float*    wt_toz  = wsf + 14954496;
  float*    wt_fromz= wsf + 14970880;
  ushort_t* t1wb    = (ushort_t*)(wsf + 14987264);
  ushort_t* w2pk    = (ushort_t*)(wsf + 15511552);
  float*    cnorm   = wsf + 15544320;

  float* out_img = (float*)d_out;        // 393216
  float* z_e_out = out_img + 393216;     // 524288
  float* e_k_out = z_e_out + 524288;     // 524288
  float* ids_out = e_k_out + 524288;     // 8192 (stored as float)

  // ---- weight prep ----
  k_transpose_w<<<48, 256, 0, stream>>>(c1_w, wt_c1, 256, 48);
  k_transpose_w<<<64, 256, 0, stream>>>(to_z_w, wt_toz, 64, 256);
  k_transpose_w<<<64, 256, 0, stream>>>(from_z_w, wt_fromz, 256, 64);
  k_prep_enc<0><<<8192, 256, 0, stream>>>(c2_w,  wp_c2,   128 << 14);
  k_prep_enc<1><<<4608, 256, 0, stream>>>(r0_w3, wp_r0w3, 72 << 14);
  k_prep_enc<1><<<4608, 256, 0, stream>>>(r1_w3, wp_r1w3, 72 << 14);
  k_prep_enc<2><<<512,  256, 0, stream>>>(r0_w1, wp_r0w1, 8 << 14);
  k_prep_enc<2><<<512,  256, 0, stream>>>(r1_w1, wp_r1w1, 8 << 14);
  k_prep_t1w<<<4096, 256, 0, stream>>>(t1_w, t1wb);
  k_prep_t2w<<<256, 256, 0, stream>>>(t2_w, w2pk);
  k_prep_cb<<<2, 256, 0, stream>>>(cb, cnorm);

  // ---- encoder ----
  k_conv1_split<<<dim3(64, 4, 8), 256, 0, stream>>>(x, xs1p0, xs1p1, wt_c1, c1_b);
  // conv2: plain-store partials cp0/cp1, epilogue: sum+relu -> h32 + splits
  k_enc_mfma_split<<<dim3(64, 4, 2), 256, 0, stream>>>(xs1p0, xs1p1, wp_c2, cp0);
  k_enc_epi<true><<<dim3(32, 16), 256, 0, stream>>>(cp0, h32, sE0, sE1, c2_b);
  // r0 w3
  k_enc_mfma_3x3<<<dim3(64, 4, 2), 256, 0, stream>>>(sE0, sE1, wp_r0w3, qp0);
  k_enc_epi<false><<<dim3(32, 16), 256, 0, stream>>>(qp0, nullptr, sE0, sE1, r0_b3);
  // r0 w1: h += conv; write h32 + split(relu(h))
  k_enc_mfma<true ><<<dim3(64, 4), 256, 0, stream>>>(
      sE0, sE1, wp_r0w1, r0_b1, h32, sF0, sF1);
  // r1 w3
  k_enc_mfma_3x3<<<dim3(64, 4, 2), 256, 0, stream>>>(sF0, sF1, wp_r1w3, qp0);
  k_enc_epi<false><<<dim3(32, 16), 256, 0, stream>>>(qp0, nullptr, sE0, sE1, r1_b3);
  // r1 w1: h += conv; write h32 only
  k_enc_mfma<false><<<dim3(64, 4), 256, 0, stream>>>(
      sE0, sE1, wp_r1w1, r1_b1, h32, nullptr, nullptr);
  // to_z (fp32)
  k_conv1x1<<<dim3(4, 4, 8), 256, 0, stream>>>(h32, z_e_out, wt_toz, to_z_b, 256, 64, 1024);

  // ---- VQ (chunk-parallel; bit-identical argmin) ----
  k_vq_part<<<dim3(32, 16), 256, 0, stream>>>(z_e_out, cb, cnorm, pbest, pbid);
  k_vq_reduce<<<32, 256, 0, stream>>>(pbest, pbid, cb, ids_out, e_k_out);

  // ---- decoder (bf16) ----
  k_from_z<<<dim3(4, 16, 8), 256, 0, stream>>>(e_k_out, decn, wt_fromz, from_z_b);
  k_mfma_t1<<<dim3(64, 2, 4), 256, 0, stream>>>(decn, t1wb, t1_b, t1out);
  k_mfma_t2<<<dim3(128, 4), 256, 0, stream>>>(t1out, w2pk, t2_b, out_img);
}

// Round 7
// 426.316 us; speedup vs baseline: 1.1770x; 1.1770x over previous
//
#include <hip/hip_runtime.h>
#include <math.h>

// ---------------------------------------------------------------------------
// VQ-VAE forward.
// Encoder: 256-ch convs as implicit-GEMM MFMA with 2-term bf16 split inputs
// (3 passes: w1x1 + w1x2 + w2x1). Big convs split-K=2 with PLAIN-STORE
// per-kz partial buffers (no atomics, no memset). VQ: chunk-parallel partial
// argmin + reduce. Decoder: t1 + t2.
// R7: exact revert to R5's verified kernels (global_load_lds staging, linear
//     LDS, 1-barrier-per-chunk dbuf; R6's A-direct regressed via compiler
//     load-sinking). NEW: coalesced k_prep_enc — one wave per (co, ci-64);
//     lane reads contiguous KK floats (16x less fetch), writes 64B bursts.
//     Bit-identical wp layout.
// ---------------------------------------------------------------------------

typedef unsigned int uint;
typedef unsigned short ushort_t;
using short8 = __attribute__((ext_vector_type(8))) short;
using f32x4  = __attribute__((ext_vector_type(4))) float;

// zero-initialized pad: invalid halo rows DMA from here (always zero)
__device__ __attribute__((aligned(16))) ushort_t g_zpad[512];

static __device__ __forceinline__ int rfl(int x) { return __builtin_amdgcn_readfirstlane(x); }
static __device__ __forceinline__ ushort_t f2bf(float f) {
  uint u = __float_as_uint(f);
  return (ushort_t)((u + 0x7fffu + ((u >> 16) & 1u)) >> 16);  // RNE; finite inputs
}
static __device__ __forceinline__ float bf2f(ushort_t b) {
  return __uint_as_float(((uint)b) << 16);
}
// direct global->LDS DMA, 16B per lane; lds dest = wave-uniform base + lane*16
static __device__ __forceinline__ void gload16(const ushort_t* g, void* l) {
  __builtin_amdgcn_global_load_lds(
      (const __attribute__((address_space(1))) void*)g,
      (__attribute__((address_space(3))) void*)l, 16, 0, 0);
}

// ---------- weight prep ----------
__global__ void k_transpose_w(const float* __restrict__ w, float* __restrict__ wT, int CO, int CIKK) {
  int idx = blockIdx.x * 256 + threadIdx.x;
  if (idx >= CO * CIKK) return;
  int co = idx % CO, i = idx / CO;
  wT[idx] = w[co * CIKK + i];
}

// encoder MFMA weight pack: w[co][ci(256)][KH][KW] fp32 ->
// wp[chunk][coT(4)][pl(2)][row(64)][k(32)] bf16 split, chunk = tap*8 + cg
// R7: one wave per (co, ci-block-of-64); lane reads its ci's CONTIGUOUS KK
// floats (coalesced), writes each (tap,pl) as lane-consecutive k (64B bursts).
template<int KIND>  // 0: 4x4 (16 taps), 1: 3x3 (9 taps), 2: 1x1 (1 tap)
__global__ __launch_bounds__(256) void k_prep_enc(
    const float* __restrict__ w, ushort_t* __restrict__ wp)
{
  constexpr int KK = (KIND == 0) ? 16 : (KIND == 1 ? 9 : 1);
  constexpr int KW = (KIND == 0) ? 4  : (KIND == 1 ? 3 : 1);
  constexpr int NT = KK;  // taps
  const int tid = threadIdx.x;
  const int wvg = blockIdx.x * 4 + (tid >> 6);   // 0..1023
  const int lane = tid & 63;
  const int co = wvg >> 2;
  const int ci = (wvg & 3) * 64 + lane;
  const float* src = w + (size_t)(co * 256 + ci) * KK;
  const int coT = co >> 6, row = co & 63, cg = ci >> 5, k = ci & 31;
  float v[KK];
#pragma unroll
  for (int j = 0; j < KK; ++j) v[j] = src[j];
#pragma unroll
  for (int tap = 0; tap < NT; ++tap) {
    int ky, kx;
    if (KIND == 0)      { ky = tap >> 2; kx = tap & 3; }
    else if (KIND == 1) { ky = tap / 3;  kx = tap - ky * 3; }
    else                { ky = 0; kx = 0; }
    float val = v[ky * KW + kx];
    ushort_t b0 = f2bf(val);
    ushort_t b1 = f2bf(val - bf2f(b0));
    const int chunk = tap * 8 + cg;
    size_t base = ((size_t)(chunk * 4 + coT) << 12) + row * 32 + k;
    wp[base] = b0;          // pl=0
    wp[base + 2048] = b1;   // pl=1
  }
}

// t1_w [ci][co][ky][kx] -> bf16 [par][tap][c8][co][kk32]
__global__ void k_prep_t1w(const float* __restrict__ w, ushort_t* __restrict__ wb) {
  int idx = blockIdx.x * 256 + threadIdx.x;  // 1048576
  int kk  = idx & 31;
  int co  = (idx >> 5) & 255;
  int c8  = (idx >> 13) & 7;
  int tap = (idx >> 16) & 3;
  int par = idx >> 18;
  int ry = par & 1, rx = (par >> 1) & 1;
  int a = tap >> 1, b = tap & 1;
  int ky = ((ry + 1) & 1) + 2 * a;
  int kx = ((rx + 1) & 1) + 2 * b;
  int ci = c8 * 32 + kk;
  wb[idx] = f2bf(w[((ci * 256 + co) << 4) + ky * 4 + kx]);
}

// t2_w [ci(256)][co(3)][4][4] -> bf16 [par(4)][chunk(32)][co16][k32]
__global__ void k_prep_t2w(const float* __restrict__ w, ushort_t* __restrict__ wb) {
  int idx = blockIdx.x * 256 + threadIdx.x;  // 65536
  int k = idx & 31, co = (idx >> 5) & 15, chunk = (idx >> 9) & 31, par = idx >> 14;
  int tap = chunk >> 3, cg = chunk & 7;
  int a = tap >> 1, b = tap & 1;
  int ry = par & 1, rx = (par >> 1) & 1;
  int ky = ((ry + 1) & 1) + 2 * a;
  int kx = ((rx + 1) & 1) + 2 * b;
  int ci = cg * 32 + k;
  float v = (co < 3) ? w[((ci * 3 + co) << 4) + ky * 4 + kx] : 0.f;
  wb[idx] = f2bf(v);
}

// cnorm[j] = sum_c cb[j][c]^2
__global__ void k_prep_cb(const float* __restrict__ cb, float* __restrict__ cnorm) {
  int idx = blockIdx.x * 256 + threadIdx.x;
  if (idx < 512) {
    float s = 0.f;
    for (int c = 0; c < 64; ++c) { float v = cb[idx * 64 + c]; s = fmaf(v, v, s); }
    cnorm[idx] = s;
  }
}

// ---------- conv1: 3->256, 4x4 s2 p1, relu, output split-bf16 NHWC ----------
__global__ __launch_bounds__(256) void k_conv1_split(
    const float* __restrict__ in, ushort_t* __restrict__ o0, ushort_t* __restrict__ o1,
    const float* __restrict__ wT, const float* __restrict__ bias)
{
  __shared__ float s_in[3 * 360];  // parity-split cols, pitch 20 (2-way free)
  const int tid = threadIdx.x;
  const int lane = tid & 63;
  const int wv = rfl(tid >> 6);
  const int px = lane & 7, py = lane >> 3;
  const int tx = blockIdx.x & 7, ty = blockIdx.x >> 3;
  const int X = tx * 8, Y = ty * 8;
  const int cob = blockIdx.y * 64 + wv * 16;
  const int n = blockIdx.z;
  float acc[16];
#pragma unroll
  for (int i = 0; i < 16; ++i) acc[i] = bias[cob + i];
  const float* inN = in + (size_t)n * 3 * 16384;
  for (int e = tid; e < 3 * 360; e += 256) {
    int col2 = e % 20; int t = e / 20; int row = t % 18; int ci = t / 18;
    int pr = col2 / 10, hc = col2 % 10, ixl = 2 * hc + pr;
    int iy = 2 * Y - 1 + row, ix = 2 * X - 1 + ixl;
    float v = 0.f;
    if (ixl < 18 && (unsigned)iy < 128u && (unsigned)ix < 128u)
      v = inN[ci * 16384 + iy * 128 + ix];
    s_in[e] = v;
  }
  __syncthreads();
  const float* wc = wT + cob;
#pragma unroll
  for (int c = 0; c < 3; ++c) {
    const float* base = s_in + c * 360 + py * 40 + px;
#pragma unroll
    for (int ky = 0; ky < 4; ++ky) {
#pragma unroll
      for (int kx = 0; kx < 4; ++kx) {
        float iv = base[ky * 20 + (kx & 1) * 10 + (kx >> 1)];
        const float* w = wc + (size_t)(c * 16 + ky * 4 + kx) * 256;  // uniform
#pragma unroll
        for (int i = 0; i < 16; ++i) acc[i] = fmaf(iv, w[i], acc[i]);
      }
    }
  }
  const int pxg = n * 4096 + (Y + py) * 64 + (X + px);
  uint p0[8], p1[8];
#pragma unroll
  for (int i = 0; i < 8; ++i) {
    float va = fmaxf(acc[2 * i], 0.f), vb = fmaxf(acc[2 * i + 1], 0.f);
    ushort_t a0 = f2bf(va), b0 = f2bf(vb);
    ushort_t a1 = f2bf(va - bf2f(a0)), b1 = f2bf(vb - bf2f(b0));
    p0[i] = (uint)a0 | ((uint)b0 << 16);
    p1[i] = (uint)a1 | ((uint)b1 << 16);
  }
  ushort_t* d0 = o0 + (size_t)pxg * 256 + cob;
  ushort_t* d1 = o1 + (size_t)pxg * 256 + cob;
  uint4 v0a; v0a.x = p0[0]; v0a.y = p0[1]; v0a.z = p0[2]; v0a.w = p0[3];
  uint4 v0b; v0b.x = p0[4]; v0b.y = p0[5]; v0b.z = p0[6]; v0b.w = p0[7];
  uint4 v1a; v1a.x = p1[0]; v1a.y = p1[1]; v1a.z = p1[2]; v1a.w = p1[3];
  uint4 v1b; v1b.x = p1[4]; v1b.y = p1[5]; v1b.z = p1[6]; v1b.w = p1[7];
  *(uint4*)d0 = v0a; *(uint4*)(d0 + 8) = v0b;
  *(uint4*)d1 = v1a; *(uint4*)(d1 + 8) = v1b;
}

// ---------- encoder implicit-GEMM MFMA, split-K=2, plain-store partial ------
// Block: 64co x 128px, 4 waves; wave: 64co x 32px = 4x2 of 16x16x32; 3 passes.
// grid (pxT 64, coT 4, kz 2); kz block z stores its partial at part + z*2^21.
// global_load_lds staging, linear LDS [sA: pl|row64|k32][sB: pl|row128|k32].
template<int KIND>  // 0: conv2 (128 chunks), 1: 3x3 (72 chunks)
__global__ __launch_bounds__(256) void k_enc_mfma_split(
    const ushort_t* __restrict__ x0, const ushort_t* __restrict__ x1,
    const ushort_t* __restrict__ wp, float* __restrict__ part)
{
  __shared__ ushort_t smem[2][12288];   // per buf: sA 4096 us (8KB) | sB 8192 us (16KB)
  const int tid = threadIdx.x, lane = tid & 63, wv = tid >> 6;
  const int l15 = lane & 15, q = lane >> 4;
  const int pxT = blockIdx.x, coT = blockIdx.y;
  constexpr int NCH = (KIND == 0) ? 128 : 72;
  const int CH0 = blockIdx.z * (NCH / 2), CH1 = CH0 + NCH / 2;
  f32x4 acc[4][2];
#pragma unroll
  for (int m = 0; m < 4; ++m)
#pragma unroll
    for (int n = 0; n < 2; ++n) acc[m][n] = (f32x4){0.f, 0.f, 0.f, 0.f};

  // B staging: thread handles rows r0 and r0+64, 16B quarter kq
  const int r0 = tid >> 2, kq = tid & 3;
  int bimg[2], bu[2], bvc[2];
#pragma unroll
  for (int r = 0; r < 2; ++r) {
    int bpx = pxT * 128 + r0 + r * 64;
    bimg[r] = bpx >> 10; int bp = bpx & 1023; bu[r] = bp >> 5; bvc[r] = bp & 31;
  }
  const ushort_t* srcB[2][2];  // [row r][plane p], excludes cg offset
  int ptap = -1;
  auto retap = [&](int tap) {
    ptap = tap;
    int ky, kx;
    if (KIND == 0) { ky = tap >> 2; kx = tap & 3; }
    else           { ky = tap / 3;  kx = tap - ky * 3; }
#pragma unroll
    for (int r = 0; r < 2; ++r) {
      bool v; size_t rowb;
      if (KIND == 0) {
        int iy = 2 * bu[r] - 1 + ky, ix = 2 * bvc[r] - 1 + kx;
        v = ((unsigned)iy < 64u) && ((unsigned)ix < 64u);
        rowb = ((size_t)(bimg[r] * 4096 + iy * 64 + ix)) << 8;
      } else {
        int iy = bu[r] - 1 + ky, ix = bvc[r] - 1 + kx;
        v = ((unsigned)iy < 32u) && ((unsigned)ix < 32u);
        rowb = ((size_t)(bimg[r] * 1024 + iy * 32 + ix)) << 8;
      }
      srcB[r][0] = (v ? (x0 + rowb) : g_zpad) + kq * 8;
      srcB[r][1] = (v ? (x1 + rowb) : g_zpad) + kq * 8;
    }
  };

  const int wvb = wv * 1024;  // wave-uniform byte base (lane*16 auto)
  auto stage = [&](int chunk, int bi) {
    const int tap = chunk >> 3, cg = chunk & 7;
    if (tap != ptap) retap(tap);
    char* bufb = (char*)smem[bi];
    const ushort_t* ap = wp + ((size_t)(chunk * 4 + coT) << 12) + tid * 8;
    gload16(ap,        bufb + wvb);                        // sA pl0
    gload16(ap + 2048, bufb + 4096 + wvb);                 // sA pl1
    const int ko = cg * 32;
    gload16(srcB[0][0] + ko, bufb + 8192 + wvb);           // sB pl0 rows 0-63
    gload16(srcB[1][0] + ko, bufb + 8192 + 4096 + wvb);    // sB pl0 rows 64-127
    gload16(srcB[0][1] + ko, bufb + 16384 + wvb);          // sB pl1 rows 0-63
    gload16(srcB[1][1] + ko, bufb + 16384 + 4096 + wvb);   // sB pl1 rows 64-127
  };
  auto compute = [&](const ushort_t* buf) {
    const ushort_t* sA = buf;
    const ushort_t* sB = buf + 4096;
    short8 af[4][2], bf[2][2];
#pragma unroll
    for (int m = 0; m < 4; ++m)
#pragma unroll
      for (int pl = 0; pl < 2; ++pl)
        af[m][pl] = *(const short8*)(sA + pl * 2048 + (m * 16 + l15) * 32 + q * 8);
#pragma unroll
    for (int n = 0; n < 2; ++n)
#pragma unroll
      for (int pl = 0; pl < 2; ++pl)
        bf[n][pl] = *(const short8*)(sB + pl * 4096 + (wv * 32 + n * 16 + l15) * 32 + q * 8);
#pragma unroll
    for (int m = 0; m < 4; ++m)
#pragma unroll
      for (int n = 0; n < 2; ++n) {
        acc[m][n] = __builtin_amdgcn_mfma_f32_16x16x32_bf16(af[m][0], bf[n][0], acc[m][n], 0, 0, 0);
        acc[m][n] = __builtin_amdgcn_mfma_f32_16x16x32_bf16(af[m][0], bf[n][1], acc[m][n], 0, 0, 0);
        acc[m][n] = __builtin_amdgcn_mfma_f32_16x16x32_bf16(af[m][1], bf[n][0], acc[m][n], 0, 0, 0);
      }
  };

  stage(CH0, 0);
  __syncthreads();
  int cur = 0;
  for (int c = CH0; c < CH1; ++c) {
    if (c + 1 < CH1) stage(c + 1, cur ^ 1);   // DMA in flight under compute
    compute(smem[cur]);
    __syncthreads();                           // drains DMA; 1 barrier/chunk
    cur ^= 1;
  }

  // plain stores to this kz's private partial slice (deterministic)
  float* pz = part + ((size_t)blockIdx.z << 21);
#pragma unroll
  for (int m = 0; m < 4; ++m) {
#pragma unroll
    for (int n = 0; n < 2; ++n) {
#pragma unroll
      for (int r = 0; r < 4; ++r) {
        const int co_l = m * 16 + q * 4 + r;
        const int px_l = wv * 32 + n * 16 + l15;
        const int px = pxT * 128 + px_l;
        const int img = px >> 10, pp = px & 1023;
        const size_t ha = ((size_t)(img * 256 + coT * 64 + co_l)) * 1024 + pp;
        pz[ha] = acc[m][n][r];
      }
    }
  }
}

// ---------- epilogue for split convs ----------
// v = p0 + p1 + bias (fixed order -> deterministic).
// WH (conv2): v=relu(v); h32=v; split v.   !WH (3x3): split relu(v).
template<bool WH>
__global__ __launch_bounds__(256) void k_enc_epi(
    const float* __restrict__ part, float* __restrict__ h32,
    ushort_t* __restrict__ s0, ushort_t* __restrict__ s1,
    const float* __restrict__ bias)
{
  const int px = blockIdx.x * 256 + threadIdx.x;  // 8192
  const int co0 = blockIdx.y * 16;
  const int img = px >> 10, pp = px & 1023;
  const float* part1 = part + (1u << 21);
  uint p0[8], p1[8];
#pragma unroll
  for (int i = 0; i < 8; ++i) {
    size_t ha = ((size_t)(img * 256 + co0 + 2 * i)) * 1024 + pp;
    size_t hb = ha + 1024;
    float va = part[ha] + part1[ha] + bias[co0 + 2 * i];
    float vb = part[hb] + part1[hb] + bias[co0 + 2 * i + 1];
    float sa, sb;
    if (WH) {
      va = fmaxf(va, 0.f); vb = fmaxf(vb, 0.f);
      h32[ha] = va; h32[hb] = vb; sa = va; sb = vb;
    } else { sa = fmaxf(va, 0.f); sb = fmaxf(vb, 0.f); }
    ushort_t a0 = f2bf(sa), b0 = f2bf(sb);
    p0[i] = (uint)a0 | ((uint)b0 << 16);
    p1[i] = (uint)f2bf(sa - bf2f(a0)) | ((uint)f2bf(sb - bf2f(b0)) << 16);
  }
  ushort_t* d0 = s0 + (size_t)px * 256 + co0;
  ushort_t* d1 = s1 + (size_t)px * 256 + co0;
  uint4 v0a; v0a.x = p0[0]; v0a.y = p0[1]; v0a.z = p0[2]; v0a.w = p0[3];
  uint4 v0b; v0b.x = p0[4]; v0b.y = p0[5]; v0b.z = p0[6]; v0b.w = p0[7];
  uint4 v1a; v1a.x = p1[0]; v1a.y = p1[1]; v1a.z = p1[2]; v1a.w = p1[3];
  uint4 v1b; v1b.x = p1[4]; v1b.y = p1[5]; v1b.z = p1[6]; v1b.w = p1[7];
  *(uint4*)d0 = v0a; *(uint4*)(d0 + 8) = v0b;
  *(uint4*)d1 = v1a; *(uint4*)(d1 + 8) = v1b;
}

// ---------- residual 1x1 MFMA (fused epilogue) ----------
// h += conv1x1(x) + bias; write h32; if WS also split(relu(h)) via LDS shuffle.
// global_load_lds staging (8 chunks), linear LDS.
template<bool WS>
__global__ __launch_bounds__(256) void k_enc_mfma(
    const ushort_t* __restrict__ x0, const ushort_t* __restrict__ x1,
    const ushort_t* __restrict__ wp, const float* __restrict__ bias,
    float* __restrict__ h32, ushort_t* __restrict__ sp0, ushort_t* __restrict__ sp1)
{
  __shared__ ushort_t smem[24576];   // dbuf 2x12288; WS epilogue reuses [0,18432)
  const int tid = threadIdx.x, lane = tid & 63, wv = tid >> 6;
  const int l15 = lane & 15, q = lane >> 4;
  const int pxT = blockIdx.x, coT = blockIdx.y;
  f32x4 acc[4][2];
#pragma unroll
  for (int m = 0; m < 4; ++m)
#pragma unroll
    for (int n = 0; n < 2; ++n) acc[m][n] = (f32x4){0.f, 0.f, 0.f, 0.f};

  const int r0 = tid >> 2, kq = tid & 3;
  const ushort_t* srcB[2][2];
#pragma unroll
  for (int r = 0; r < 2; ++r) {
    size_t rowb = ((size_t)(pxT * 128 + r0 + r * 64)) << 8;
    srcB[r][0] = x0 + rowb + kq * 8;
    srcB[r][1] = x1 + rowb + kq * 8;
  }
  const int wvb = wv * 1024;
  auto stage = [&](int c, int bi) {
    char* bufb = (char*)(smem + bi * 12288);
    const ushort_t* ap = wp + ((size_t)(c * 4 + coT) << 12) + tid * 8;
    gload16(ap,        bufb + wvb);
    gload16(ap + 2048, bufb + 4096 + wvb);
    const int ko = c * 32;
    gload16(srcB[0][0] + ko, bufb + 8192 + wvb);
    gload16(srcB[1][0] + ko, bufb + 8192 + 4096 + wvb);
    gload16(srcB[0][1] + ko, bufb + 16384 + wvb);
    gload16(srcB[1][1] + ko, bufb + 16384 + 4096 + wvb);
  };
  auto compute = [&](const ushort_t* buf) {
    const ushort_t* sA = buf;
    const ushort_t* sB = buf + 4096;
    short8 af[4][2], bf[2][2];
#pragma unroll
    for (int m = 0; m < 4; ++m)
#pragma unroll
      for (int pl = 0; pl < 2; ++pl)
        af[m][pl] = *(const short8*)(sA + pl * 2048 + (m * 16 + l15) * 32 + q * 8);
#pragma unroll
    for (int n = 0; n < 2; ++n)
#pragma unroll
      for (int pl = 0; pl < 2; ++pl)
        bf[n][pl] = *(const short8*)(sB + pl * 4096 + (wv * 32 + n * 16 + l15) * 32 + q * 8);
#pragma unroll
    for (int m = 0; m < 4; ++m)
#pragma unroll
      for (int n = 0; n < 2; ++n) {
        acc[m][n] = __builtin_amdgcn_mfma_f32_16x16x32_bf16(af[m][0], bf[n][0], acc[m][n], 0, 0, 0);
        acc[m][n] = __builtin_amdgcn_mfma_f32_16x16x32_bf16(af[m][0], bf[n][1], acc[m][n], 0, 0, 0);
        acc[m][n] = __builtin_amdgcn_mfma_f32_16x16x32_bf16(af[m][1], bf[n][0], acc[m][n], 0, 0, 0);
      }
  };

  stage(0, 0);
  __syncthreads();
  int cur = 0;
  for (int c = 0; c < 8; ++c) {
    if (c + 1 < 8) stage(c + 1, cur ^ 1);
    compute(smem + cur * 12288);
    __syncthreads();
    cur ^= 1;
  }

#pragma unroll
  for (int m = 0; m < 4; ++m) {
#pragma unroll
    for (int n = 0; n < 2; ++n) {
#pragma unroll
      for (int r = 0; r < 4; ++r) {
        const int co_l = m * 16 + q * 4 + r;
        const int px_l = wv * 32 + n * 16 + l15;
        float v = acc[m][n][r] + bias[coT * 64 + co_l];
        const int px = pxT * 128 + px_l;
        const int img = px >> 10, pp = px & 1023;
        const size_t ha = ((size_t)(img * 256 + coT * 64 + co_l)) * 1024 + pp;
        v += h32[ha];
        h32[ha] = v;
        if (WS) {
          float sv = fmaxf(v, 0.f);
          ushort_t b0 = f2bf(sv);
          smem[px_l * 72 + co_l] = b0;
          smem[9216 + px_l * 72 + co_l] = f2bf(sv - bf2f(b0));
        }
      }
    }
  }
  if (WS) {
    __syncthreads();
#pragma unroll
    for (int i = 0; i < 8; ++i) {
      int idx = tid + 256 * i;
      int pl = idx >> 10, w2 = idx & 1023, pxl = w2 >> 3, g = w2 & 7;
      uint4 vv = *(const uint4*)(smem + pl * 9216 + pxl * 72 + g * 8);
      ushort_t* dst = (pl ? sp1 : sp0) + ((size_t)(pxT * 128 + pxl)) * 256 + coT * 64 + g * 8;
      *(uint4*)dst = vv;
    }
  }
}

// ---------- 1x1 conv fp32 (to_z only) ----------
__global__ __launch_bounds__(256) void k_conv1x1(
    const float* __restrict__ in, float* __restrict__ out,
    const float* __restrict__ wT, const float* __restrict__ bias,
    int CI, int CO, int P)
{
  const int p = blockIdx.x * 256 + threadIdx.x;
  const int cob = blockIdx.y * 16;
  const int n = blockIdx.z;
  const float* inN = in + (size_t)n * CI * P + p;
  float acc[16];
#pragma unroll
  for (int i = 0; i < 16; ++i) acc[i] = bias[cob + i];
  const float* wr = wT + cob;
#pragma unroll 4
  for (int ci = 0; ci < CI; ++ci) {
    float iv = inN[(size_t)ci * P];
    const float* w = wr + (size_t)ci * CO;  // uniform
#pragma unroll
    for (int i = 0; i < 16; ++i) acc[i] = fmaf(iv, w[i], acc[i]);
  }
  float* outN = out + (size_t)n * CO * P + p;
#pragma unroll
  for (int i = 0; i < 16; ++i) outN[(size_t)(cob + i) * P] = acc[i];
}

// ---------- VQ partial: 16 chunks of 32 codes; per-j math identical ----------
__global__ __launch_bounds__(256) void k_vq_part(
    const float* __restrict__ z_e, const float* __restrict__ cb,
    const float* __restrict__ cnorm, float* __restrict__ pbest, int* __restrict__ pbid)
{
  int g = blockIdx.x * 256 + threadIdx.x;  // 8192 points
  int chunk = blockIdx.y;                  // 16 chunks
  int img = g >> 10, p = g & 1023;
  const float* zp = z_e + (size_t)img * 64 * 1024 + p;
  float z[64];
#pragma unroll
  for (int c = 0; c < 64; ++c) z[c] = zp[(size_t)c * 1024];
  float best = 3.4e38f; int bid = chunk << 5;
  const int j0 = chunk << 5;
  for (int j = j0; j < j0 + 32; ++j) {
    const float* cj = cb + j * 64;  // uniform -> scalar loads
    float m = 0.f;
#pragma unroll
    for (int c = 0; c < 64; ++c) m = fmaf(z[c], cj[c], m);
    float d = fmaf(-2.f, m, cnorm[j]);
    if (d < best) { best = d; bid = j; }  // strict <: first-min within chunk
  }
  pbest[chunk * 8192 + g] = best;
  pbid[chunk * 8192 + g] = bid;
}

// ---------- VQ reduce: argmin across chunks (ascending -> np.argmin) + e_k ----------
__global__ __launch_bounds__(256) void k_vq_reduce(
    const float* __restrict__ pbest, const int* __restrict__ pbid,
    const float* __restrict__ cb, float* __restrict__ ids_f, float* __restrict__ ek)
{
  int g = blockIdx.x * 256 + threadIdx.x;  // 8192
  float best = 3.4e38f; int bid = 0;
#pragma unroll
  for (int ch = 0; ch < 16; ++ch) {
    float d = pbest[ch * 8192 + g];
    int b = pbid[ch * 8192 + g];
    if (d < best) { best = d; bid = b; }
  }
  ids_f[g] = (float)bid;
  int img = g >> 10, p = g & 1023;
  const float* cbid = cb + bid * 64;
  float* ekp = ek + (size_t)img * 64 * 1024 + p;
#pragma unroll
  for (int c = 0; c < 64; ++c) ekp[(size_t)c * 1024] = cbid[c];
}

// ---------- from_z 1x1 (64->256) + relu -> NHWC bf16 ----------
__global__ __launch_bounds__(256) void k_from_z(
    const float* __restrict__ ek, ushort_t* __restrict__ nhwc,
    const float* __restrict__ wT, const float* __restrict__ bias)
{
  const int p = blockIdx.x * 256 + threadIdx.x;  // 0..1023
  const int co0 = blockIdx.y * 16;
  const int n = blockIdx.z;
  const float* inN = ek + (size_t)n * 64 * 1024 + p;
  float acc[16];
#pragma unroll
  for (int i = 0; i < 16; ++i) acc[i] = bias[co0 + i];
#pragma unroll 4
  for (int ci = 0; ci < 64; ++ci) {
    float iv = inN[(size_t)ci * 1024];
    const float* w = wT + (size_t)ci * 256 + co0;  // uniform
#pragma unroll
    for (int i = 0; i < 16; ++i) acc[i] = fmaf(iv, w[i], acc[i]);
  }
  uint pk[8];
#pragma unroll
  for (int i = 0; i < 8; ++i) {
    ushort_t lo = f2bf(fmaxf(acc[2 * i], 0.f));
    ushort_t hi = f2bf(fmaxf(acc[2 * i + 1], 0.f));
    pk[i] = (uint)lo | ((uint)hi << 16);
  }
  ushort_t* op = nhwc + (((size_t)n * 1024 + p) * 256 + co0);
  uint4 v0; v0.x = pk[0]; v0.y = pk[1]; v0.z = pk[2]; v0.w = pk[3];
  uint4 v1; v1.x = pk[4]; v1.y = pk[5]; v1.z = pk[6]; v1.w = pk[7];
  *(uint4*)(op) = v0;
  *(uint4*)(op + 8) = v1;
}

// ---------- t1 convtranspose 4x4 s2 p1, 256->256, bf16 MFMA, relu -> bf16 NHWC
// global_load_lds staging, linear LDS; 1-barrier-per-chunk dbuf.
__global__ __launch_bounds__(256) void k_mfma_t1(
    const ushort_t* __restrict__ nhwc, const ushort_t* __restrict__ wb,
    const float* __restrict__ bias, ushort_t* __restrict__ t1o)
{
  __shared__ ushort_t smem[2][8192];   // per buf: sA 4096 us | sB 4096 us
  const int tid = threadIdx.x;
  const int lane = tid & 63;
  const int wv = tid >> 6;
  const int wm = wv & 1, wn = wv >> 1;
  const int l15 = lane & 15, q = lane >> 4;
  const int pxT = blockIdx.x, coT = blockIdx.y, par = blockIdx.z;
  const int ry = par & 1, rx = (par >> 1) & 1;
  const int pxbase = pxT * 128;
  const int img = pxbase >> 10;
  f32x4 acc[4][4];
#pragma unroll
  for (int i = 0; i < 4; ++i)
#pragma unroll
    for (int j = 0; j < 4; ++j) acc[i][j] = (f32x4){0.f, 0.f, 0.f, 0.f};

  const int srow = tid >> 2, kg = tid & 3;
  int bu2[2], bv2[2];
#pragma unroll
  for (int r = 0; r < 2; ++r) {
    int px = pxbase + srow + r * 64;
    bu2[r] = (px >> 5) & 31; bv2[r] = px & 31;
  }
  const ushort_t* nb[2];
  int ptap = -1;
  auto retap = [&](int tap) {
    ptap = tap;
    int ta = tap >> 1, tb = tap & 1;
#pragma unroll
    for (int r = 0; r < 2; ++r) {
      int iy = bu2[r] + ry - ta, ix = bv2[r] + rx - tb;
      bool v = ((unsigned)iy < 32u) && ((unsigned)ix < 32u);
      nb[r] = (v ? (nhwc + (((size_t)(img * 1024 + iy * 32 + ix)) << 8)) : g_zpad) + kg * 8;
    }
  };
  const int wvb = wv * 1024;
  auto stage = [&](int c, int bi) {
    const int tap = c >> 3, c8 = c & 7;
    if (tap != ptap) retap(tap);
    char* bufb = (char*)smem[bi];
    const ushort_t* Abase = wb + ((size_t)((par * 4 + tap) * 8 + c8) << 13) + coT * 4096 + tid * 8;
    gload16(Abase,        bufb + wvb);
    gload16(Abase + 2048, bufb + 4096 + wvb);
    const int ko = c8 * 32;
    gload16(nb[0] + ko, bufb + 8192 + wvb);
    gload16(nb[1] + ko, bufb + 8192 + 4096 + wvb);
  };
  auto compute = [&](const ushort_t* buf) {
    const ushort_t* sA = buf;
    const ushort_t* sB = buf + 4096;
    short8 af[4], bfr[4];
#pragma unroll
    for (int i = 0; i < 4; ++i)
      af[i] = *(const short8*)(sA + (wm * 64 + i * 16 + l15) * 32 + q * 8);
#pragma unroll
    for (int j = 0; j < 4; ++j)
      bfr[j] = *(const short8*)(sB + (wn * 64 + j * 16 + l15) * 32 + q * 8);
#pragma unroll
    for (int i = 0; i < 4; ++i)
#pragma unroll
      for (int j = 0; j < 4; ++j)
        acc[i][j] = __builtin_amdgcn_mfma_f32_16x16x32_bf16(af[i], bfr[j], acc[i][j], 0, 0, 0);
  };

  stage(0, 0);
  __syncthreads();
  int cur = 0;
  for (int c = 0; c < 32; ++c) {
    if (c + 1 < 32) stage(c + 1, cur ^ 1);
    compute(smem[cur]);
    __syncthreads();
    cur ^= 1;
  }

#pragma unroll
  for (int i = 0; i < 4; ++i) {
    int co = coT * 128 + wm * 64 + i * 16 + q * 4;
#pragma unroll
    for (int j = 0; j < 4; ++j) {
      int px = pxbase + wn * 64 + j * 16 + l15;
      int u = (px >> 5) & 31, vv = px & 31;
      int oy = 2 * u + ry, ox = 2 * vv + rx;
      ushort_t e0 = f2bf(fmaxf(acc[i][j][0] + bias[co + 0], 0.f));
      ushort_t e1 = f2bf(fmaxf(acc[i][j][1] + bias[co + 1], 0.f));
      ushort_t e2 = f2bf(fmaxf(acc[i][j][2] + bias[co + 2], 0.f));
      ushort_t e3 = f2bf(fmaxf(acc[i][j][3] + bias[co + 3], 0.f));
      uint2 pk; pk.x = (uint)e0 | ((uint)e1 << 16); pk.y = (uint)e2 | ((uint)e3 << 16);
      *(uint2*)(t1o + ((size_t)(img * 4096 + oy * 64 + ox) * 256 + co)) = pk;
    }
  }
}

// ---------- t2 convtranspose 4x4 s2 p1, 256->3, bf16 MFMA, sigmoid ----------
__global__ __launch_bounds__(256) void k_mfma_t2(
    const ushort_t* __restrict__ t1o, const ushort_t* __restrict__ wb,
    const float* __restrict__ bias, float* __restrict__ out)
{
  __shared__ ushort_t sA2[256 * 32];
  __shared__ ushort_t sB2[16 * 32];
  const int tid = threadIdx.x, lane = tid & 63, wv = tid >> 6;
  const int l15 = lane & 15, q = lane >> 4;
  const int pxb = blockIdx.x * 256;
  const int par = blockIdx.y;
  const int ry = par & 1, rx = (par >> 1) & 1;
  f32x4 acc[4];
#pragma unroll
  for (int m = 0; m < 4; ++m) acc[m] = (f32x4){0.f, 0.f, 0.f, 0.f};
  const int kg = tid & 3;
  const int ssw = ((tid >> 2) & 7) << 3;
  size_t rb[4]; bool rv[4];
  for (int chunk = 0; chunk < 32; ++chunk) {
    const int tap = chunk >> 3, cg = chunk & 7;
    const int a = tap >> 1, b = tap & 1;
    if ((chunk & 7) == 0) {
#pragma unroll
      for (int i = 0; i < 4; ++i) {
        int row = (tid >> 2) + 64 * i;
        int px = pxb + row;
        int img = px >> 12, p = px & 4095, u = p >> 6, v = p & 63;
        int iy = u + ry - a, ix = v + rx - b;
        rv[i] = ((unsigned)iy < 64u) && ((unsigned)ix < 64u);
        rb[i] = ((size_t)(img * 4096 + iy * 64 + ix)) << 8;
      }
    }
    uint4 av[4];
#pragma unroll
    for (int i = 0; i < 4; ++i) {
      if (rv[i]) av[i] = *(const uint4*)(t1o + rb[i] + cg * 32 + kg * 8);
      else { av[i].x = 0; av[i].y = 0; av[i].z = 0; av[i].w = 0; }
    }
    uint4 bv;
    if (tid < 64) bv = *(const uint4*)(wb + ((size_t)(par * 32 + chunk)) * 512 + tid * 8);
    __syncthreads();
#pragma unroll
    for (int i = 0; i < 4; ++i)
      *(uint4*)(sA2 + (((((tid >> 2) + 64 * i) * 32) + kg * 8) ^ ssw)) = av[i];
    if (tid < 64) *(uint4*)(sB2 + ((tid * 8) ^ ssw)) = bv;
    __syncthreads();
    short8 bf = *(const short8*)(sB2 + ((l15 * 32 + q * 8) ^ ((l15 & 7) << 3)));
#pragma unroll
    for (int m = 0; m < 4; ++m) {
      const int row = wv * 64 + m * 16 + l15;
      short8 af = *(const short8*)(sA2 + ((row * 32 + q * 8) ^ ((row & 7) << 3)));
      acc[m] = __builtin_amdgcn_mfma_f32_16x16x32_bf16(af, bf, acc[m], 0, 0, 0);
    }
    __syncthreads();
  }
  const int co = l15;
  if (co < 3) {
    float bco = bias[co];
#pragma unroll
    for (int m = 0; m < 4; ++m) {
#pragma unroll
      for (int r = 0; r < 4; ++r) {
        int px = pxb + wv * 64 + m * 16 + q * 4 + r;
        int img = px >> 12, p = px & 4095, u = p >> 6, v = p & 63;
        size_t addr = ((size_t)(img * 3 + co)) * 16384 + (2 * u + ry) * 128 + (2 * v + rx);
        out[addr] = 1.f / (1.f + expf(-(acc[m][r] + bco)));
      }
    }
  }
}

// ---------------------------------------------------------------------------
extern "C" void kernel_launch(void* const* d_in, const int* in_sizes, int n_in,
                              void* d_out, int out_size, void* d_ws, size_t ws_size,
                              hipStream_t stream) {
  (void)in_sizes; (void)n_in; (void)out_size; (void)ws_size;
  const float* x      = (const float*)d_in[0];
  const float* c1_w   = (const float*)d_in[1];
  const float* c1_b   = (const float*)d_in[2];
  const float* c2_w   = (const float*)d_in[3];
  const float* c2_b   = (const float*)d_in[4];
  const float* r0_w3  = (const float*)d_in[5];
  const float* r0_b3  = (const float*)d_in[6];
  const float* r0_w1  = (const float*)d_in[7];
  const float* r0_b1  = (const float*)d_in[8];
  const float* r1_w3  = (const float*)d_in[9];
  const float* r1_b3  = (const float*)d_in[10];
  const float* r1_w1  = (const float*)d_in[11];
  const float* r1_b1  = (const float*)d_in[12];
  const float* to_z_w = (const float*)d_in[13];
  const float* to_z_b = (const float*)d_in[14];
  const float* cb     = (const float*)d_in[15];
  const float* from_z_w = (const float*)d_in[16];
  const float* from_z_b = (const float*)d_in[17];
  const float* t1_w   = (const float*)d_in[18];
  const float* t1_b   = (const float*)d_in[19];
  const float* t2_w   = (const float*)d_in[20];
  const float* t2_b   = (const float*)d_in[21];

  float* wsf = (float*)d_ws;
  // Era-choreographed regions (float offsets) — see R3 comments; unchanged.
  ushort_t* xs1p0 = (ushort_t*)(wsf + 0);
  ushort_t* xs1p1 = (ushort_t*)(wsf + 4194304);
  float*    cp0   = wsf + 8388608;               // conv2 partial kz0 (= h32 slot)
  float*    h32   = wsf + 8388608;
  float*    qp0   = wsf + 4194304;               // 3x3 partials (xs1p1 slot, dead)
  ushort_t* sE0   = (ushort_t*)(wsf + 0);        // split ping [0,1.05M)
  ushort_t* sE1   = (ushort_t*)(wsf + 1048576);  // split ping [1.05,2.1M)
  ushort_t* sF0   = (ushort_t*)(wsf + 2097152);  // split pong [2.1,3.15M)
  ushort_t* sF1   = (ushort_t*)(wsf + 3145728);  // split pong [3.15,4.19M)
  float*    pbest = wsf + 0;                     // vq-era
  int*      pbid  = (int*)(wsf + 131072);        // vq-era
  ushort_t* t1out = (ushort_t*)(wsf + 2097152);  // dec-era [2.1M, 6.29M)
  ushort_t* decn  = (ushort_t*)(wsf + 6291456);  // dec-era [6.29M, 7.34M)
  ushort_t* wp_c2   = (ushort_t*)(wsf + 12582912);
  ushort_t* wp_r0w3 = (ushort_t*)(wsf + 13631488);
  ushort_t* wp_r1w3 = (ushort_t*)(wsf + 14221312);
  ushort_t* wp_r0w1 = (ushort_t*)(wsf + 14811136);
  ushort_t* wp_r1w1 = (ushort_t*)(wsf + 14876672);
  float*    wt_c1   = wsf + 14942208;
  float*    wt_toz  = wsf + 14954496;
  float*    wt_fromz= wsf + 14970880;
  ushort_t* t1wb    = (ushort_t*)(wsf + 14987264);
  ushort_t* w2pk    = (ushort_t*)(wsf + 15511552);
  float*    cnorm   = wsf + 15544320;

  float* out_img = (float*)d_out;        // 393216
  float* z_e_out = out_img + 393216;     // 524288
  float* e_k_out = z_e_out + 524288;     // 524288
  float* ids_out = e_k_out + 524288;     // 8192 (stored as float)

  // ---- weight prep ----
  k_transpose_w<<<48, 256, 0, stream>>>(c1_w, wt_c1, 256, 48);
  k_transpose_w<<<64, 256, 0, stream>>>(to_z_w, wt_toz, 64, 256);
  k_transpose_w<<<64, 256, 0, stream>>>(from_z_w, wt_fromz, 256, 64);
  k_prep_enc<0><<<256, 256, 0, stream>>>(c2_w,  wp_c2);
  k_prep_enc<1><<<256, 256, 0, stream>>>(r0_w3, wp_r0w3);
  k_prep_enc<1><<<256, 256, 0, stream>>>(r1_w3, wp_r1w3);
  k_prep_enc<2><<<256, 256, 0, stream>>>(r0_w1, wp_r0w1);
  k_prep_enc<2><<<256, 256, 0, stream>>>(r1_w1, wp_r1w1);
  k_prep_t1w<<<4096, 256, 0, stream>>>(t1_w, t1wb);
  k_prep_t2w<<<256, 256, 0, stream>>>(t2_w, w2pk);
  k_prep_cb<<<2, 256, 0, stream>>>(cb, cnorm);

  // ---- encoder ----
  k_conv1_split<<<dim3(64, 4, 8), 256, 0, stream>>>(x, xs1p0, xs1p1, wt_c1, c1_b);
  // conv2: plain-store partials cp0/cp1, epilogue: sum+relu -> h32 + splits
  k_enc_mfma_split<0><<<dim3(64, 4, 2), 256, 0, stream>>>(xs1p0, xs1p1, wp_c2, cp0);
  k_enc_epi<true><<<dim3(32, 16), 256, 0, stream>>>(cp0, h32, sE0, sE1, c2_b);
  // r0 w3
  k_enc_mfma_split<1><<<dim3(64, 4, 2), 256, 0, stream>>>(sE0, sE1, wp_r0w3, qp0);
  k_enc_epi<false><<<dim3(32, 16), 256, 0, stream>>>(qp0, nullptr, sE0, sE1, r0_b3);
  // r0 w1: h += conv; write h32 + split(relu(h))
  k_enc_mfma<true ><<<dim3(64, 4), 256, 0, stream>>>(
      sE0, sE1, wp_r0w1, r0_b1, h32, sF0, sF1);
  // r1 w3
  k_enc_mfma_split<1><<<dim3(64, 4, 2), 256, 0, stream>>>(sF0, sF1, wp_r1w3, qp0);
  k_enc_epi<false><<<dim3(32, 16), 256, 0, stream>>>(qp0, nullptr, sE0, sE1, r1_b3);
  // r1 w1: h += conv; write h32 only
  k_enc_mfma<false><<<dim3(64, 4), 256, 0, stream>>>(
      sE0, sE1, wp_r1w1, r1_b1, h32, nullptr, nullptr);
  // to_z (fp32)
  k_conv1x1<<<dim3(4, 4, 8), 256, 0, stream>>>(h32, z_e_out, wt_toz, to_z_b, 256, 64, 1024);

  // ---- VQ (chunk-parallel; bit-identical argmin) ----
  k_vq_part<<<dim3(32, 16), 256, 0, stream>>>(z_e_out, cb, cnorm, pbest, pbid);
  k_vq_reduce<<<32, 256, 0, stream>>>(pbest, pbid, cb, ids_out, e_k_out);

  // ---- decoder (bf16) ----
  k_from_z<<<dim3(4, 16, 8), 256, 0, stream>>>(e_k_out, decn, wt_fromz, from_z_b);
  k_mfma_t1<<<dim3(64, 2, 4), 256, 0, stream>>>(decn, t1wb, t1_b, t1out);
  k_mfma_t2<<<dim3(128, 4), 256, 0, stream>>>(t1out, w2pk, t2_b, out_img);
}

// Round 8
// 409.412 us; speedup vs baseline: 1.2256x; 1.0413x over previous
//
#include <hip/hip_runtime.h>
#include <math.h>

// ---------------------------------------------------------------------------
// VQ-VAE forward.
// Encoder: 256-ch convs as implicit-GEMM MFMA with 2-term bf16 split inputs
// (3 passes: w1x1 + w1x2 + w2x1). Big convs split-K=2 with PLAIN-STORE
// per-kz partial buffers. VQ: chunk-parallel partial argmin + reduce.
// Decoder: t1 + t2.
// R8: 3x3 convs -> per-cg halo staging (R6's verified halo mapping, isolated
//     from the A-direct change that caused R6's regression): stage all 9 taps'
//     A (36KB) + 6x34 input halo (28KB) per cg via global_load_lds, then 108
//     MFMA with NO barriers between taps (2 barriers/cg vs 18/block before).
//     Block 32co x 128px, grid (64,8,2). conv2/t1 unchanged (at structure
//     ceiling). Prep kernels merged 11 -> 5 dispatches.
// ---------------------------------------------------------------------------

typedef unsigned int uint;
typedef unsigned short ushort_t;
using short8 = __attribute__((ext_vector_type(8))) short;
using f32x4  = __attribute__((ext_vector_type(4))) float;

// zero-initialized pad: invalid halo rows DMA from here (always zero)
__device__ __attribute__((aligned(16))) ushort_t g_zpad[512];

static __device__ __forceinline__ int rfl(int x) { return __builtin_amdgcn_readfirstlane(x); }
static __device__ __forceinline__ ushort_t f2bf(float f) {
  uint u = __float_as_uint(f);
  return (ushort_t)((u + 0x7fffu + ((u >> 16) & 1u)) >> 16);  // RNE; finite inputs
}
static __device__ __forceinline__ float bf2f(ushort_t b) {
  return __uint_as_float(((uint)b) << 16);
}
// direct global->LDS DMA, 16B per lane; lds dest = wave-uniform base + lane*16
static __device__ __forceinline__ void gload16(const ushort_t* g, void* l) {
  __builtin_amdgcn_global_load_lds(
      (const __attribute__((address_space(1))) void*)g,
      (__attribute__((address_space(3))) void*)l, 16, 0, 0);
}

// ---------- weight prep ----------
// merged small preps: 3 transposes + cnorm + t2w pack in one launch (434 blocks)
__global__ __launch_bounds__(256) void k_prep_misc(
    const float* __restrict__ c1w, float* __restrict__ wt_c1,
    const float* __restrict__ tozw, float* __restrict__ wt_toz,
    const float* __restrict__ fromzw, float* __restrict__ wt_fromz,
    const float* __restrict__ cb, float* __restrict__ cnorm,
    const float* __restrict__ t2w, ushort_t* __restrict__ w2pk)
{
  const int b = blockIdx.x, tid = threadIdx.x;
  if (b < 48) {            // c1 transpose: CO=256, CIKK=48 (12288 elems)
    int idx = b * 256 + tid;
    int co = idx % 256, i = idx / 256;
    wt_c1[idx] = c1w[co * 48 + i];
  } else if (b < 112) {    // to_z transpose: CO=64, CIKK=256 (16384)
    int idx = (b - 48) * 256 + tid;
    int co = idx % 64, i = idx / 64;
    wt_toz[idx] = tozw[co * 256 + i];
  } else if (b < 176) {    // from_z transpose: CO=256, CIKK=64 (16384)
    int idx = (b - 112) * 256 + tid;
    int co = idx % 256, i = idx / 256;
    wt_fromz[idx] = fromzw[co * 64 + i];
  } else if (b < 178) {    // cnorm[j] = sum_c cb[j][c]^2
    int idx = (b - 176) * 256 + tid;
    if (idx < 512) {
      float s = 0.f;
      for (int c = 0; c < 64; ++c) { float v = cb[idx * 64 + c]; s = fmaf(v, v, s); }
      cnorm[idx] = s;
    }
  } else {                 // t2_w pack: 65536 elems (256 blocks)
    int idx = (b - 178) * 256 + tid;
    int k = idx & 31, co = (idx >> 5) & 15, chunk = (idx >> 9) & 31, par = idx >> 14;
    int tap = chunk >> 3, cg = chunk & 7;
    int a = tap >> 1, bb = tap & 1;
    int ry = par & 1, rx = (par >> 1) & 1;
    int ky = ((ry + 1) & 1) + 2 * a;
    int kx = ((rx + 1) & 1) + 2 * bb;
    int ci = cg * 32 + k;
    float v = (co < 3) ? t2w[((ci * 3 + co) << 4) + ky * 4 + kx] : 0.f;
    w2pk[idx] = f2bf(v);
  }
}

// encoder MFMA weight pack: w[co][ci(256)][KH][KW] fp32 ->
// wp[chunk][coT(4)][pl(2)][row(64)][k(32)] bf16 split, chunk = tap*8 + cg
// one wave per (co, ci-block-of-64); lane reads its ci's CONTIGUOUS KK floats.
template<int KIND>  // 0: 4x4 (16 taps), 1: 3x3 (9 taps), 2: 1x1 (1 tap)
__global__ __launch_bounds__(256) void k_prep_enc(
    const float* __restrict__ w, ushort_t* __restrict__ wp)
{
  constexpr int KK = (KIND == 0) ? 16 : (KIND == 1 ? 9 : 1);
  constexpr int KW = (KIND == 0) ? 4  : (KIND == 1 ? 3 : 1);
  constexpr int NT = KK;  // taps
  const int tid = threadIdx.x;
  const int wvg = blockIdx.x * 4 + (tid >> 6);   // 0..1023
  const int lane = tid & 63;
  const int co = wvg >> 2;
  const int ci = (wvg & 3) * 64 + lane;
  const float* src = w + (size_t)(co * 256 + ci) * KK;
  const int coT = co >> 6, row = co & 63, cg = ci >> 5, k = ci & 31;
  float v[KK];
#pragma unroll
  for (int j = 0; j < KK; ++j) v[j] = src[j];
#pragma unroll
  for (int tap = 0; tap < NT; ++tap) {
    int ky, kx;
    if (KIND == 0)      { ky = tap >> 2; kx = tap & 3; }
    else if (KIND == 1) { ky = tap / 3;  kx = tap - ky * 3; }
    else                { ky = 0; kx = 0; }
    float val = v[ky * KW + kx];
    ushort_t b0 = f2bf(val);
    ushort_t b1 = f2bf(val - bf2f(b0));
    const int chunk = tap * 8 + cg;
    size_t base = ((size_t)(chunk * 4 + coT) << 12) + row * 32 + k;
    wp[base] = b0;          // pl=0
    wp[base + 2048] = b1;   // pl=1
  }
}

// paired variant: blocks 0..255 -> (wa,oa), 256..511 -> (wb2,ob)
template<int KIND>
__global__ __launch_bounds__(256) void k_prep_enc2(
    const float* __restrict__ wa, ushort_t* __restrict__ oa,
    const float* __restrict__ wb2, ushort_t* __restrict__ ob)
{
  constexpr int KK = (KIND == 0) ? 16 : (KIND == 1 ? 9 : 1);
  constexpr int KW = (KIND == 0) ? 4  : (KIND == 1 ? 3 : 1);
  constexpr int NT = KK;
  const float* w = (blockIdx.x < 256) ? wa : wb2;
  ushort_t* wp = (blockIdx.x < 256) ? oa : ob;
  const int bx = blockIdx.x & 255;
  const int tid = threadIdx.x;
  const int wvg = bx * 4 + (tid >> 6);
  const int lane = tid & 63;
  const int co = wvg >> 2;
  const int ci = (wvg & 3) * 64 + lane;
  const float* src = w + (size_t)(co * 256 + ci) * KK;
  const int coT = co >> 6, row = co & 63, cg = ci >> 5, k = ci & 31;
  float v[KK];
#pragma unroll
  for (int j = 0; j < KK; ++j) v[j] = src[j];
#pragma unroll
  for (int tap = 0; tap < NT; ++tap) {
    int ky, kx;
    if (KIND == 0)      { ky = tap >> 2; kx = tap & 3; }
    else if (KIND == 1) { ky = tap / 3;  kx = tap - ky * 3; }
    else                { ky = 0; kx = 0; }
    float val = v[ky * KW + kx];
    ushort_t b0 = f2bf(val);
    ushort_t b1 = f2bf(val - bf2f(b0));
    const int chunk = tap * 8 + cg;
    size_t base = ((size_t)(chunk * 4 + coT) << 12) + row * 32 + k;
    wp[base] = b0;
    wp[base + 2048] = b1;
  }
}

// t1_w [ci][co][ky][kx] -> bf16 [par][tap][c8][co][kk32]
__global__ void k_prep_t1w(const float* __restrict__ w, ushort_t* __restrict__ wb) {
  int idx = blockIdx.x * 256 + threadIdx.x;  // 1048576
  int kk  = idx & 31;
  int co  = (idx >> 5) & 255;
  int c8  = (idx >> 13) & 7;
  int tap = (idx >> 16) & 3;
  int par = idx >> 18;
  int ry = par & 1, rx = (par >> 1) & 1;
  int a = tap >> 1, b = tap & 1;
  int ky = ((ry + 1) & 1) + 2 * a;
  int kx = ((rx + 1) & 1) + 2 * b;
  int ci = c8 * 32 + kk;
  wb[idx] = f2bf(w[((ci * 256 + co) << 4) + ky * 4 + kx]);
}

// ---------- conv1: 3->256, 4x4 s2 p1, relu, output split-bf16 NHWC ----------
__global__ __launch_bounds__(256) void k_conv1_split(
    const float* __restrict__ in, ushort_t* __restrict__ o0, ushort_t* __restrict__ o1,
    const float* __restrict__ wT, const float* __restrict__ bias)
{
  __shared__ float s_in[3 * 360];  // parity-split cols, pitch 20 (2-way free)
  const int tid = threadIdx.x;
  const int lane = tid & 63;
  const int wv = rfl(tid >> 6);
  const int px = lane & 7, py = lane >> 3;
  const int tx = blockIdx.x & 7, ty = blockIdx.x >> 3;
  const int X = tx * 8, Y = ty * 8;
  const int cob = blockIdx.y * 64 + wv * 16;
  const int n = blockIdx.z;
  float acc[16];
#pragma unroll
  for (int i = 0; i < 16; ++i) acc[i] = bias[cob + i];
  const float* inN = in + (size_t)n * 3 * 16384;
  for (int e = tid; e < 3 * 360; e += 256) {
    int col2 = e % 20; int t = e / 20; int row = t % 18; int ci = t / 18;
    int pr = col2 / 10, hc = col2 % 10, ixl = 2 * hc + pr;
    int iy = 2 * Y - 1 + row, ix = 2 * X - 1 + ixl;
    float v = 0.f;
    if (ixl < 18 && (unsigned)iy < 128u && (unsigned)ix < 128u)
      v = inN[ci * 16384 + iy * 128 + ix];
    s_in[e] = v;
  }
  __syncthreads();
  const float* wc = wT + cob;
#pragma unroll
  for (int c = 0; c < 3; ++c) {
    const float* base = s_in + c * 360 + py * 40 + px;
#pragma unroll
    for (int ky = 0; ky < 4; ++ky) {
#pragma unroll
      for (int kx = 0; kx < 4; ++kx) {
        float iv = base[ky * 20 + (kx & 1) * 10 + (kx >> 1)];
        const float* w = wc + (size_t)(c * 16 + ky * 4 + kx) * 256;  // uniform
#pragma unroll
        for (int i = 0; i < 16; ++i) acc[i] = fmaf(iv, w[i], acc[i]);
      }
    }
  }
  const int pxg = n * 4096 + (Y + py) * 64 + (X + px);
  uint p0[8], p1[8];
#pragma unroll
  for (int i = 0; i < 8; ++i) {
    float va = fmaxf(acc[2 * i], 0.f), vb = fmaxf(acc[2 * i + 1], 0.f);
    ushort_t a0 = f2bf(va), b0 = f2bf(vb);
    ushort_t a1 = f2bf(va - bf2f(a0)), b1 = f2bf(vb - bf2f(b0));
    p0[i] = (uint)a0 | ((uint)b0 << 16);
    p1[i] = (uint)a1 | ((uint)b1 << 16);
  }
  ushort_t* d0 = o0 + (size_t)pxg * 256 + cob;
  ushort_t* d1 = o1 + (size_t)pxg * 256 + cob;
  uint4 v0a; v0a.x = p0[0]; v0a.y = p0[1]; v0a.z = p0[2]; v0a.w = p0[3];
  uint4 v0b; v0b.x = p0[4]; v0b.y = p0[5]; v0b.z = p0[6]; v0b.w = p0[7];
  uint4 v1a; v1a.x = p1[0]; v1a.y = p1[1]; v1a.z = p1[2]; v1a.w = p1[3];
  uint4 v1b; v1b.x = p1[4]; v1b.y = p1[5]; v1b.z = p1[6]; v1b.w = p1[7];
  *(uint4*)d0 = v0a; *(uint4*)(d0 + 8) = v0b;
  *(uint4*)d1 = v1a; *(uint4*)(d1 + 8) = v1b;
}

// ---------- conv2 implicit-GEMM MFMA, split-K=2, plain-store partial --------
// Block: 64co x 128px, 4 waves; wave: 64co x 32px = 4x2 of 16x16x32; 3 passes.
// grid (pxT 64, coT 4, kz 2). global_load_lds staging, linear LDS.
template<int KIND>  // 0: conv2 (128 chunks)
__global__ __launch_bounds__(256) void k_enc_mfma_split(
    const ushort_t* __restrict__ x0, const ushort_t* __restrict__ x1,
    const ushort_t* __restrict__ wp, float* __restrict__ part)
{
  __shared__ ushort_t smem[2][12288];   // per buf: sA 4096 us (8KB) | sB 8192 us (16KB)
  const int tid = threadIdx.x, lane = tid & 63, wv = tid >> 6;
  const int l15 = lane & 15, q = lane >> 4;
  const int pxT = blockIdx.x, coT = blockIdx.y;
  constexpr int NCH = (KIND == 0) ? 128 : 72;
  const int CH0 = blockIdx.z * (NCH / 2), CH1 = CH0 + NCH / 2;
  f32x4 acc[4][2];
#pragma unroll
  for (int m = 0; m < 4; ++m)
#pragma unroll
    for (int n = 0; n < 2; ++n) acc[m][n] = (f32x4){0.f, 0.f, 0.f, 0.f};

  // B staging: thread handles rows r0 and r0+64, 16B quarter kq
  const int r0 = tid >> 2, kq = tid & 3;
  int bimg[2], bu[2], bvc[2];
#pragma unroll
  for (int r = 0; r < 2; ++r) {
    int bpx = pxT * 128 + r0 + r * 64;
    bimg[r] = bpx >> 10; int bp = bpx & 1023; bu[r] = bp >> 5; bvc[r] = bp & 31;
  }
  const ushort_t* srcB[2][2];  // [row r][plane p], excludes cg offset
  int ptap = -1;
  auto retap = [&](int tap) {
    ptap = tap;
    int ky, kx;
    if (KIND == 0) { ky = tap >> 2; kx = tap & 3; }
    else           { ky = tap / 3;  kx = tap - ky * 3; }
#pragma unroll
    for (int r = 0; r < 2; ++r) {
      bool v; size_t rowb;
      if (KIND == 0) {
        int iy = 2 * bu[r] - 1 + ky, ix = 2 * bvc[r] - 1 + kx;
        v = ((unsigned)iy < 64u) && ((unsigned)ix < 64u);
        rowb = ((size_t)(bimg[r] * 4096 + iy * 64 + ix)) << 8;
      } else {
        int iy = bu[r] - 1 + ky, ix = bvc[r] - 1 + kx;
        v = ((unsigned)iy < 32u) && ((unsigned)ix < 32u);
        rowb = ((size_t)(bimg[r] * 1024 + iy * 32 + ix)) << 8;
      }
      srcB[r][0] = (v ? (x0 + rowb) : g_zpad) + kq * 8;
      srcB[r][1] = (v ? (x1 + rowb) : g_zpad) + kq * 8;
    }
  };

  const int wvb = wv * 1024;  // wave-uniform byte base (lane*16 auto)
  auto stage = [&](int chunk, int bi) {
    const int tap = chunk >> 3, cg = chunk & 7;
    if (tap != ptap) retap(tap);
    char* bufb = (char*)smem[bi];
    const ushort_t* ap = wp + ((size_t)(chunk * 4 + coT) << 12) + tid * 8;
    gload16(ap,        bufb + wvb);                        // sA pl0
    gload16(ap + 2048, bufb + 4096 + wvb);                 // sA pl1
    const int ko = cg * 32;
    gload16(srcB[0][0] + ko, bufb + 8192 + wvb);           // sB pl0 rows 0-63
    gload16(srcB[1][0] + ko, bufb + 8192 + 4096 + wvb);    // sB pl0 rows 64-127
    gload16(srcB[0][1] + ko, bufb + 16384 + wvb);          // sB pl1 rows 0-63
    gload16(srcB[1][1] + ko, bufb + 16384 + 4096 + wvb);   // sB pl1 rows 64-127
  };
  auto compute = [&](const ushort_t* buf) {
    const ushort_t* sA = buf;
    const ushort_t* sB = buf + 4096;
    short8 af[4][2], bf[2][2];
#pragma unroll
    for (int m = 0; m < 4; ++m)
#pragma unroll
      for (int pl = 0; pl < 2; ++pl)
        af[m][pl] = *(const short8*)(sA + pl * 2048 + (m * 16 + l15) * 32 + q * 8);
#pragma unroll
    for (int n = 0; n < 2; ++n)
#pragma unroll
      for (int pl = 0; pl < 2; ++pl)
        bf[n][pl] = *(const short8*)(sB + pl * 4096 + (wv * 32 + n * 16 + l15) * 32 + q * 8);
#pragma unroll
    for (int m = 0; m < 4; ++m)
#pragma unroll
      for (int n = 0; n < 2; ++n) {
        acc[m][n] = __builtin_amdgcn_mfma_f32_16x16x32_bf16(af[m][0], bf[n][0], acc[m][n], 0, 0, 0);
        acc[m][n] = __builtin_amdgcn_mfma_f32_16x16x32_bf16(af[m][0], bf[n][1], acc[m][n], 0, 0, 0);
        acc[m][n] = __builtin_amdgcn_mfma_f32_16x16x32_bf16(af[m][1], bf[n][0], acc[m][n], 0, 0, 0);
      }
  };

  stage(CH0, 0);
  __syncthreads();
  int cur = 0;
  for (int c = CH0; c < CH1; ++c) {
    if (c + 1 < CH1) stage(c + 1, cur ^ 1);   // DMA in flight under compute
    compute(smem[cur]);
    __syncthreads();                           // drains DMA; 1 barrier/chunk
    cur ^= 1;
  }

  // plain stores to this kz's private partial slice (deterministic)
  float* pz = part + ((size_t)blockIdx.z << 21);
#pragma unroll
  for (int m = 0; m < 4; ++m) {
#pragma unroll
    for (int n = 0; n < 2; ++n) {
#pragma unroll
      for (int r = 0; r < 4; ++r) {
        const int co_l = m * 16 + q * 4 + r;
        const int px_l = wv * 32 + n * 16 + l15;
        const int px = pxT * 128 + px_l;
        const int img = px >> 10, pp = px & 1023;
        const size_t ha = ((size_t)(img * 256 + coT * 64 + co_l)) * 1024 + pp;
        pz[ha] = acc[m][n][r];
      }
    }
  }
}

// ---------- 3x3 implicit-GEMM MFMA, split-K=2 (by cg), per-cg halo B --------
// Block 32co x 128px (4 waves, wave 32co x 32px, acc 2x2). Per cg: stage all
// 9 taps' A (36KB, 9 DMA) + [2pl][6r][34c][32k] halo (7 DMA, R6-verified
// mapping), 1 barrier, 108 MFMA with no tap barriers, 1 barrier.
// grid (pxT 64, coT 8, kz 2); kz z covers cg z*4..z*4+3.
__global__ __launch_bounds__(256) void k_enc_mfma_3x3h(
    const ushort_t* __restrict__ x0, const ushort_t* __restrict__ x1,
    const ushort_t* __restrict__ wp, float* __restrict__ part)
{
  __shared__ ushort_t smem[32768];  // A 18432 us | halo 14336 us (1632 used + pad)
  const int tid = threadIdx.x, lane = tid & 63, wv = tid >> 6;
  const int l15 = lane & 15, q = lane >> 4;
  const int pxT = blockIdx.x, coT = blockIdx.y;
  const int CG0 = blockIdx.z * 4;
  const int img = pxT >> 3;          // 8 blocks per 32x32 image
  const int U0 = (pxT & 7) * 4;      // base output row of this 128px strip
  f32x4 acc[2][2];
#pragma unroll
  for (int m = 0; m < 2; ++m)
#pragma unroll
    for (int n = 0; n < 2; ++n) acc[m][n] = (f32x4){0.f, 0.f, 0.f, 0.f};

  // halo DMA sources: slot = pl*816 + r*136 + c*4 + kq ; (pl, row U0-1+r, col c-1)
  const ushort_t* srcp[7];
#pragma unroll
  for (int i = 0; i < 7; ++i) {
    int slot = i * 256 + tid;
    int pl = slot >= 816 ? 1 : 0;
    int rem = slot - pl * 816;
    int rr = rem / 136;
    int c4 = rem - rr * 136;
    int cc = c4 >> 2, kq2 = c4 & 3;
    int iy = U0 - 1 + rr, ix = cc - 1;
    bool valid = (slot < 1632) && ((unsigned)iy < 32u) && ((unsigned)ix < 32u);
    const ushort_t* base = valid
        ? ((pl ? x1 : x0) + (((size_t)(img * 1024 + iy * 32 + ix)) << 8))
        : g_zpad;
    srcp[i] = base + kq2 * 8;
  }
  // A DMA source: per tap one 4KB DMA; threads 0..127 pl0, 128..255 pl1
  const int apl = tid >> 7;
  const int aus = apl * 2048 + (coT & 1) * 1024 + (tid & 127) * 8;
  const int coTq = coT >> 1;
  const int wvb = wv * 1024;
  char* bufb = (char*)smem;

  for (int cg = CG0; cg < CG0 + 4; ++cg) {
#pragma unroll
    for (int tap = 0; tap < 9; ++tap) {
      const int chunk = tap * 8 + cg;
      gload16(wp + ((size_t)(chunk * 4 + coTq) << 12) + aus, bufb + tap * 4096 + wvb);
    }
    const int ko = cg * 32;
#pragma unroll
    for (int i = 0; i < 7; ++i)
      gload16(srcp[i] + ko, bufb + 36864 + i * 4096 + wvb);
    __syncthreads();
    const ushort_t* Ab = smem;
    const ushort_t* Hb = smem + 18432;
#pragma unroll 3
    for (int tap = 0; tap < 9; ++tap) {
      const int ky = tap / 3, kx = tap - ky * 3;
      short8 af[2][2], bf[2][2];
#pragma unroll
      for (int m = 0; m < 2; ++m)
#pragma unroll
        for (int pl = 0; pl < 2; ++pl)
          af[m][pl] = *(const short8*)(Ab + tap * 2048 + pl * 1024 + (m * 16 + l15) * 32 + q * 8);
      const int r = wv + ky;
#pragma unroll
      for (int n = 0; n < 2; ++n)
#pragma unroll
        for (int pl = 0; pl < 2; ++pl)
          bf[n][pl] = *(const short8*)(Hb + pl * 6528 + r * 1088 + (n * 16 + l15 + kx) * 32 + q * 8);
#pragma unroll
      for (int m = 0; m < 2; ++m)
#pragma unroll
        for (int n = 0; n < 2; ++n) {
          acc[m][n] = __builtin_amdgcn_mfma_f32_16x16x32_bf16(af[m][0], bf[n][0], acc[m][n], 0, 0, 0);
          acc[m][n] = __builtin_amdgcn_mfma_f32_16x16x32_bf16(af[m][0], bf[n][1], acc[m][n], 0, 0, 0);
          acc[m][n] = __builtin_amdgcn_mfma_f32_16x16x32_bf16(af[m][1], bf[n][0], acc[m][n], 0, 0, 0);
        }
    }
    __syncthreads();   // before restage (single-buffered)
  }

  float* pz = part + ((size_t)blockIdx.z << 21);
#pragma unroll
  for (int m = 0; m < 2; ++m) {
#pragma unroll
    for (int n = 0; n < 2; ++n) {
#pragma unroll
      for (int r = 0; r < 4; ++r) {
        const int co_l = m * 16 + q * 4 + r;
        const int px_l = wv * 32 + n * 16 + l15;
        const int px = pxT * 128 + px_l;
        const int imgp = px >> 10, pp = px & 1023;
        const size_t ha = ((size_t)(imgp * 256 + coT * 32 + co_l)) * 1024 + pp;
        pz[ha] = acc[m][n][r];
      }
    }
  }
}

// ---------- epilogue for split convs ----------
// v = p0 + p1 + bias (fixed order -> deterministic).
// WH (conv2): v=relu(v); h32=v; split v.   !WH (3x3): split relu(v).
template<bool WH>
__global__ __launch_bounds__(256) void k_enc_epi(
    const float* __restrict__ part, float* __restrict__ h32,
    ushort_t* __restrict__ s0, ushort_t* __restrict__ s1,
    const float* __restrict__ bias)
{
  const int px = blockIdx.x * 256 + threadIdx.x;  // 8192
  const int co0 = blockIdx.y * 16;
  const int img = px >> 10, pp = px & 1023;
  const float* part1 = part + (1u << 21);
  uint p0[8], p1[8];
#pragma unroll
  for (int i = 0; i < 8; ++i) {
    size_t ha = ((size_t)(img * 256 + co0 + 2 * i)) * 1024 + pp;
    size_t hb = ha + 1024;
    float va = part[ha] + part1[ha] + bias[co0 + 2 * i];
    float vb = part[hb] + part1[hb] + bias[co0 + 2 * i + 1];
    float sa, sb;
    if (WH) {
      va = fmaxf(va, 0.f); vb = fmaxf(vb, 0.f);
      h32[ha] = va; h32[hb] = vb; sa = va; sb = vb;
    } else { sa = fmaxf(va, 0.f); sb = fmaxf(vb, 0.f); }
    ushort_t a0 = f2bf(sa), b0 = f2bf(sb);
    p0[i] = (uint)a0 | ((uint)b0 << 16);
    p1[i] = (uint)f2bf(sa - bf2f(a0)) | ((uint)f2bf(sb - bf2f(b0)) << 16);
  }
  ushort_t* d0 = s0 + (size_t)px * 256 + co0;
  ushort_t* d1 = s1 + (size_t)px * 256 + co0;
  uint4 v0a; v0a.x = p0[0]; v0a.y = p0[1]; v0a.z = p0[2]; v0a.w = p0[3];
  uint4 v0b; v0b.x = p0[4]; v0b.y = p0[5]; v0b.z = p0[6]; v0b.w = p0[7];
  uint4 v1a; v1a.x = p1[0]; v1a.y = p1[1]; v1a.z = p1[2]; v1a.w = p1[3];
  uint4 v1b; v1b.x = p1[4]; v1b.y = p1[5]; v1b.z = p1[6]; v1b.w = p1[7];
  *(uint4*)d0 = v0a; *(uint4*)(d0 + 8) = v0b;
  *(uint4*)d1 = v1a; *(uint4*)(d1 + 8) = v1b;
}

// ---------- residual 1x1 MFMA (fused epilogue) ----------
// h += conv1x1(x) + bias; write h32; if WS also split(relu(h)) via LDS shuffle.
// global_load_lds staging (8 chunks), linear LDS.
template<bool WS>
__global__ __launch_bounds__(256) void k_enc_mfma(
    const ushort_t* __restrict__ x0, const ushort_t* __restrict__ x1,
    const ushort_t* __restrict__ wp, const float* __restrict__ bias,
    float* __restrict__ h32, ushort_t* __restrict__ sp0, ushort_t* __restrict__ sp1)
{
  __shared__ ushort_t smem[24576];   // dbuf 2x12288; WS epilogue reuses [0,18432)
  const int tid = threadIdx.x, lane = tid & 63, wv = tid >> 6;
  const int l15 = lane & 15, q = lane >> 4;
  const int pxT = blockIdx.x, coT = blockIdx.y;
  f32x4 acc[4][2];
#pragma unroll
  for (int m = 0; m < 4; ++m)
#pragma unroll
    for (int n = 0; n < 2; ++n) acc[m][n] = (f32x4){0.f, 0.f, 0.f, 0.f};

  const int r0 = tid >> 2, kq = tid & 3;
  const ushort_t* srcB[2][2];
#pragma unroll
  for (int r = 0; r < 2; ++r) {
    size_t rowb = ((size_t)(pxT * 128 + r0 + r * 64)) << 8;
    srcB[r][0] = x0 + rowb + kq * 8;
    srcB[r][1] = x1 + rowb + kq * 8;
  }
  const int wvb = wv * 1024;
  auto stage = [&](int c, int bi) {
    char* bufb = (char*)(smem + bi * 12288);
    const ushort_t* ap = wp + ((size_t)(c * 4 + coT) << 12) + tid * 8;
    gload16(ap,        bufb + wvb);
    gload16(ap + 2048, bufb + 4096 + wvb);
    const int ko = c * 32;
    gload16(srcB[0][0] + ko, bufb + 8192 + wvb);
    gload16(srcB[1][0] + ko, bufb + 8192 + 4096 + wvb);
    gload16(srcB[0][1] + ko, bufb + 16384 + wvb);
    gload16(srcB[1][1] + ko, bufb + 16384 + 4096 + wvb);
  };
  auto compute = [&](const ushort_t* buf) {
    const ushort_t* sA = buf;
    const ushort_t* sB = buf + 4096;
    short8 af[4][2], bf[2][2];
#pragma unroll
    for (int m = 0; m < 4; ++m)
#pragma unroll
      for (int pl = 0; pl < 2; ++pl)
        af[m][pl] = *(const short8*)(sA + pl * 2048 + (m * 16 + l15) * 32 + q * 8);
#pragma unroll
    for (int n = 0; n < 2; ++n)
#pragma unroll
      for (int pl = 0; pl < 2; ++pl)
        bf[n][pl] = *(const short8*)(sB + pl * 4096 + (wv * 32 + n * 16 + l15) * 32 + q * 8);
#pragma unroll
    for (int m = 0; m < 4; ++m)
#pragma unroll
      for (int n = 0; n < 2; ++n) {
        acc[m][n] = __builtin_amdgcn_mfma_f32_16x16x32_bf16(af[m][0], bf[n][0], acc[m][n], 0, 0, 0);
        acc[m][n] = __builtin_amdgcn_mfma_f32_16x16x32_bf16(af[m][0], bf[n][1], acc[m][n], 0, 0, 0);
        acc[m][n] = __builtin_amdgcn_mfma_f32_16x16x32_bf16(af[m][1], bf[n][0], acc[m][n], 0, 0, 0);
      }
  };

  stage(0, 0);
  __syncthreads();
  int cur = 0;
  for (int c = 0; c < 8; ++c) {
    if (c + 1 < 8) stage(c + 1, cur ^ 1);
    compute(smem + cur * 12288);
    __syncthreads();
    cur ^= 1;
  }

#pragma unroll
  for (int m = 0; m < 4; ++m) {
#pragma unroll
    for (int n = 0; n < 2; ++n) {
#pragma unroll
      for (int r = 0; r < 4; ++r) {
        const int co_l = m * 16 + q * 4 + r;
        const int px_l = wv * 32 + n * 16 + l15;
        float v = acc[m][n][r] + bias[coT * 64 + co_l];
        const int px = pxT * 128 + px_l;
        const int img = px >> 10, pp = px & 1023;
        const size_t ha = ((size_t)(img * 256 + coT * 64 + co_l)) * 1024 + pp;
        v += h32[ha];
        h32[ha] = v;
        if (WS) {
          float sv = fmaxf(v, 0.f);
          ushort_t b0 = f2bf(sv);
          smem[px_l * 72 + co_l] = b0;
          smem[9216 + px_l * 72 + co_l] = f2bf(sv - bf2f(b0));
        }
      }
    }
  }
  if (WS) {
    __syncthreads();
#pragma unroll
    for (int i = 0; i < 8; ++i) {
      int idx = tid + 256 * i;
      int pl = idx >> 10, w2 = idx & 1023, pxl = w2 >> 3, g = w2 & 7;
      uint4 vv = *(const uint4*)(smem + pl * 9216 + pxl * 72 + g * 8);
      ushort_t* dst = (pl ? sp1 : sp0) + ((size_t)(pxT * 128 + pxl)) * 256 + coT * 64 + g * 8;
      *(uint4*)dst = vv;
    }
  }
}

// ---------- 1x1 conv fp32 (to_z only) ----------
__global__ __launch_bounds__(256) void k_conv1x1(
    const float* __restrict__ in, float* __restrict__ out,
    const float* __restrict__ wT, const float* __restrict__ bias,
    int CI, int CO, int P)
{
  const int p = blockIdx.x * 256 + threadIdx.x;
  const int cob = blockIdx.y * 16;
  const int n = blockIdx.z;
  const float* inN = in + (size_t)n * CI * P + p;
  float acc[16];
#pragma unroll
  for (int i = 0; i < 16; ++i) acc[i] = bias[cob + i];
  const float* wr = wT + cob;
#pragma unroll 4
  for (int ci = 0; ci < CI; ++ci) {
    float iv = inN[(size_t)ci * P];
    const float* w = wr + (size_t)ci * CO;  // uniform
#pragma unroll
    for (int i = 0; i < 16; ++i) acc[i] = fmaf(iv, w[i], acc[i]);
  }
  float* outN = out + (size_t)n * CO * P + p;
#pragma unroll
  for (int i = 0; i < 16; ++i) outN[(size_t)(cob + i) * P] = acc[i];
}

// ---------- VQ partial: 16 chunks of 32 codes; per-j math identical ----------
__global__ __launch_bounds__(256) void k_vq_part(
    const float* __restrict__ z_e, const float* __restrict__ cb,
    const float* __restrict__ cnorm, float* __restrict__ pbest, int* __restrict__ pbid)
{
  int g = blockIdx.x * 256 + threadIdx.x;  // 8192 points
  int chunk = blockIdx.y;                  // 16 chunks
  int img = g >> 10, p = g & 1023;
  const float* zp = z_e + (size_t)img * 64 * 1024 + p;
  float z[64];
#pragma unroll
  for (int c = 0; c < 64; ++c) z[c] = zp[(size_t)c * 1024];
  float best = 3.4e38f; int bid = chunk << 5;
  const int j0 = chunk << 5;
  for (int j = j0; j < j0 + 32; ++j) {
    const float* cj = cb + j * 64;  // uniform -> scalar loads
    float m = 0.f;
#pragma unroll
    for (int c = 0; c < 64; ++c) m = fmaf(z[c], cj[c], m);
    float d = fmaf(-2.f, m, cnorm[j]);
    if (d < best) { best = d; bid = j; }  // strict <: first-min within chunk
  }
  pbest[chunk * 8192 + g] = best;
  pbid[chunk * 8192 + g] = bid;
}

// ---------- VQ reduce: argmin across chunks (ascending -> np.argmin) + e_k ----------
__global__ __launch_bounds__(256) void k_vq_reduce(
    const float* __restrict__ pbest, const int* __restrict__ pbid,
    const float* __restrict__ cb, float* __restrict__ ids_f, float* __restrict__ ek)
{
  int g = blockIdx.x * 256 + threadIdx.x;  // 8192
  float best = 3.4e38f; int bid = 0;
#pragma unroll
  for (int ch = 0; ch < 16; ++ch) {
    float d = pbest[ch * 8192 + g];
    int b = pbid[ch * 8192 + g];
    if (d < best) { best = d; bid = b; }
  }
  ids_f[g] = (float)bid;
  int img = g >> 10, p = g & 1023;
  const float* cbid = cb + bid * 64;
  float* ekp = ek + (size_t)img * 64 * 1024 + p;
#pragma unroll
  for (int c = 0; c < 64; ++c) ekp[(size_t)c * 1024] = cbid[c];
}

// ---------- from_z 1x1 (64->256) + relu -> NHWC bf16 ----------
__global__ __launch_bounds__(256) void k_from_z(
    const float* __restrict__ ek, ushort_t* __restrict__ nhwc,
    const float* __restrict__ wT, const float* __restrict__ bias)
{
  const int p = blockIdx.x * 256 + threadIdx.x;  // 0..1023
  const int co0 = blockIdx.y * 16;
  const int n = blockIdx.z;
  const float* inN = ek + (size_t)n * 64 * 1024 + p;
  float acc[16];
#pragma unroll
  for (int i = 0; i < 16; ++i) acc[i] = bias[co0 + i];
#pragma unroll 4
  for (int ci = 0; ci < 64; ++ci) {
    float iv = inN[(size_t)ci * 1024];
    const float* w = wT + (size_t)ci * 256 + co0;  // uniform
#pragma unroll
    for (int i = 0; i < 16; ++i) acc[i] = fmaf(iv, w[i], acc[i]);
  }
  uint pk[8];
#pragma unroll
  for (int i = 0; i < 8; ++i) {
    ushort_t lo = f2bf(fmaxf(acc[2 * i], 0.f));
    ushort_t hi = f2bf(fmaxf(acc[2 * i + 1], 0.f));
    pk[i] = (uint)lo | ((uint)hi << 16);
  }
  ushort_t* op = nhwc + (((size_t)n * 1024 + p) * 256 + co0);
  uint4 v0; v0.x = pk[0]; v0.y = pk[1]; v0.z = pk[2]; v0.w = pk[3];
  uint4 v1; v1.x = pk[4]; v1.y = pk[5]; v1.z = pk[6]; v1.w = pk[7];
  *(uint4*)(op) = v0;
  *(uint4*)(op + 8) = v1;
}

// ---------- t1 convtranspose 4x4 s2 p1, 256->256, bf16 MFMA, relu -> bf16 NHWC
// global_load_lds staging, linear LDS; 1-barrier-per-chunk dbuf.
__global__ __launch_bounds__(256) void k_mfma_t1(
    const ushort_t* __restrict__ nhwc, const ushort_t* __restrict__ wb,
    const float* __restrict__ bias, ushort_t* __restrict__ t1o)
{
  __shared__ ushort_t smem[2][8192];   // per buf: sA 4096 us | sB 4096 us
  const int tid = threadIdx.x;
  const int lane = tid & 63;
  const int wv = tid >> 6;
  const int wm = wv & 1, wn = wv >> 1;
  const int l15 = lane & 15, q = lane >> 4;
  const int pxT = blockIdx.x, coT = blockIdx.y, par = blockIdx.z;
  const int ry = par & 1, rx = (par >> 1) & 1;
  const int pxbase = pxT * 128;
  const int img = pxbase >> 10;
  f32x4 acc[4][4];
#pragma unroll
  for (int i = 0; i < 4; ++i)
#pragma unroll
    for (int j = 0; j < 4; ++j) acc[i][j] = (f32x4){0.f, 0.f, 0.f, 0.f};

  const int srow = tid >> 2, kg = tid & 3;
  int bu2[2], bv2[2];
#pragma unroll
  for (int r = 0; r < 2; ++r) {
    int px = pxbase + srow + r * 64;
    bu2[r] = (px >> 5) & 31; bv2[r] = px & 31;
  }
  const ushort_t* nb[2];
  int ptap = -1;
  auto retap = [&](int tap) {
    ptap = tap;
    int ta = tap >> 1, tb = tap & 1;
#pragma unroll
    for (int r = 0; r < 2; ++r) {
      int iy = bu2[r] + ry - ta, ix = bv2[r] + rx - tb;
      bool v = ((unsigned)iy < 32u) && ((unsigned)ix < 32u);
      nb[r] = (v ? (nhwc + (((size_t)(img * 1024 + iy * 32 + ix)) << 8)) : g_zpad) + kg * 8;
    }
  };
  const int wvb = wv * 1024;
  auto stage = [&](int c, int bi) {
    const int tap = c >> 3, c8 = c & 7;
    if (tap != ptap) retap(tap);
    char* bufb = (char*)smem[bi];
    const ushort_t* Abase = wb + ((size_t)((par * 4 + tap) * 8 + c8) << 13) + coT * 4096 + tid * 8;
    gload16(Abase,        bufb + wvb);
    gload16(Abase + 2048, bufb + 4096 + wvb);
    const int ko = c8 * 32;
    gload16(nb[0] + ko, bufb + 8192 + wvb);
    gload16(nb[1] + ko, bufb + 8192 + 4096 + wvb);
  };
  auto compute = [&](const ushort_t* buf) {
    const ushort_t* sA = buf;
    const ushort_t* sB = buf + 4096;
    short8 af[4], bfr[4];
#pragma unroll
    for (int i = 0; i < 4; ++i)
      af[i] = *(const short8*)(sA + (wm * 64 + i * 16 + l15) * 32 + q * 8);
#pragma unroll
    for (int j = 0; j < 4; ++j)
      bfr[j] = *(const short8*)(sB + (wn * 64 + j * 16 + l15) * 32 + q * 8);
#pragma unroll
    for (int i = 0; i < 4; ++i)
#pragma unroll
      for (int j = 0; j < 4; ++j)
        acc[i][j] = __builtin_amdgcn_mfma_f32_16x16x32_bf16(af[i], bfr[j], acc[i][j], 0, 0, 0);
  };

  stage(0, 0);
  __syncthreads();
  int cur = 0;
  for (int c = 0; c < 32; ++c) {
    if (c + 1 < 32) stage(c + 1, cur ^ 1);
    compute(smem[cur]);
    __syncthreads();
    cur ^= 1;
  }

#pragma unroll
  for (int i = 0; i < 4; ++i) {
    int co = coT * 128 + wm * 64 + i * 16 + q * 4;
#pragma unroll
    for (int j = 0; j < 4; ++j) {
      int px = pxbase + wn * 64 + j * 16 + l15;
      int u = (px >> 5) & 31, vv = px & 31;
      int oy = 2 * u + ry, ox = 2 * vv + rx;
      ushort_t e0 = f2bf(fmaxf(acc[i][j][0] + bias[co + 0], 0.f));
      ushort_t e1 = f2bf(fmaxf(acc[i][j][1] + bias[co + 1], 0.f));
      ushort_t e2 = f2bf(fmaxf(acc[i][j][2] + bias[co + 2], 0.f));
      ushort_t e3 = f2bf(fmaxf(acc[i][j][3] + bias[co + 3], 0.f));
      uint2 pk; pk.x = (uint)e0 | ((uint)e1 << 16); pk.y = (uint)e2 | ((uint)e3 << 16);
      *(uint2*)(t1o + ((size_t)(img * 4096 + oy * 64 + ox) * 256 + co)) = pk;
    }
  }
}

// ---------- t2 convtranspose 4x4 s2 p1, 256->3, bf16 MFMA, sigmoid ----------
__global__ __launch_bounds__(256) void k_mfma_t2(
    const ushort_t* __restrict__ t1o, const ushort_t* __restrict__ wb,
    const float* __restrict__ bias, float* __restrict__ out)
{
  __shared__ ushort_t sA2[256 * 32];
  __shared__ ushort_t sB2[16 * 32];
  const int tid = threadIdx.x, lane = tid & 63, wv = tid >> 6;
  const int l15 = lane & 15, q = lane >> 4;
  const int pxb = blockIdx.x * 256;
  const int par = blockIdx.y;
  const int ry = par & 1, rx = (par >> 1) & 1;
  f32x4 acc[4];
#pragma unroll
  for (int m = 0; m < 4; ++m) acc[m] = (f32x4){0.f, 0.f, 0.f, 0.f};
  const int kg = tid & 3;
  const int ssw = ((tid >> 2) & 7) << 3;
  size_t rb[4]; bool rv[4];
  for (int chunk = 0; chunk < 32; ++chunk) {
    const int tap = chunk >> 3, cg = chunk & 7;
    const int a = tap >> 1, b = tap & 1;
    if ((chunk & 7) == 0) {
#pragma unroll
      for (int i = 0; i < 4; ++i) {
        int row = (tid >> 2) + 64 * i;
        int px = pxb + row;
        int img = px >> 12, p = px & 4095, u = p >> 6, v = p & 63;
        int iy = u + ry - a, ix = v + rx - b;
        rv[i] = ((unsigned)iy < 64u) && ((unsigned)ix < 64u);
        rb[i] = ((size_t)(img * 4096 + iy * 64 + ix)) << 8;
      }
    }
    uint4 av[4];
#pragma unroll
    for (int i = 0; i < 4; ++i) {
      if (rv[i]) av[i] = *(const uint4*)(t1o + rb[i] + cg * 32 + kg * 8);
      else { av[i].x = 0; av[i].y = 0; av[i].z = 0; av[i].w = 0; }
    }
    uint4 bv;
    if (tid < 64) bv = *(const uint4*)(wb + ((size_t)(par * 32 + chunk)) * 512 + tid * 8);
    __syncthreads();
#pragma unroll
    for (int i = 0; i < 4; ++i)
      *(uint4*)(sA2 + (((((tid >> 2) + 64 * i) * 32) + kg * 8) ^ ssw)) = av[i];
    if (tid < 64) *(uint4*)(sB2 + ((tid * 8) ^ ssw)) = bv;
    __syncthreads();
    short8 bf = *(const short8*)(sB2 + ((l15 * 32 + q * 8) ^ ((l15 & 7) << 3)));
#pragma unroll
    for (int m = 0; m < 4; ++m) {
      const int row = wv * 64 + m * 16 + l15;
      short8 af = *(const short8*)(sA2 + ((row * 32 + q * 8) ^ ((row & 7) << 3)));
      acc[m] = __builtin_amdgcn_mfma_f32_16x16x32_bf16(af, bf, acc[m], 0, 0, 0);
    }
    __syncthreads();
  }
  const int co = l15;
  if (co < 3) {
    float bco = bias[co];
#pragma unroll
    for (int m = 0; m < 4; ++m) {
#pragma unroll
      for (int r = 0; r < 4; ++r) {
        int px = pxb + wv * 64 + m * 16 + q * 4 + r;
        int img = px >> 12, p = px & 4095, u = p >> 6, v = p & 63;
        size_t addr = ((size_t)(img * 3 + co)) * 16384 + (2 * u + ry) * 128 + (2 * v + rx);
        out[addr] = 1.f / (1.f + expf(-(acc[m][r] + bco)));
      }
    }
  }
}

// ---------------------------------------------------------------------------
extern "C" void kernel_launch(void* const* d_in, const int* in_sizes, int n_in,
                              void* d_out, int out_size, void* d_ws, size_t ws_size,
                              hipStream_t stream) {
  (void)in_sizes; (void)n_in; (void)out_size; (void)ws_size;
  const float* x      = (const float*)d_in[0];
  const float* c1_w   = (const float*)d_in[1];
  const float* c1_b   = (const float*)d_in[2];
  const float* c2_w   = (const float*)d_in[3];
  const float* c2_b   = (const float*)d_in[4];
  const float* r0_w3  = (const float*)d_in[5];
  const float* r0_b3  = (const float*)d_in[6];
  const float* r0_w1  = (const float*)d_in[7];
  const float* r0_b1  = (const float*)d_in[8];
  const float* r1_w3  = (const float*)d_in[9];
  const float* r1_b3  = (const float*)d_in[10];
  const float* r1_w1  = (const float*)d_in[11];
  const float* r1_b1  = (const float*)d_in[12];
  const float* to_z_w = (const float*)d_in[13];
  const float* to_z_b = (const float*)d_in[14];
  const float* cb     = (const float*)d_in[15];
  const float* from_z_w = (const float*)d_in[16];
  const float* from_z_b = (const float*)d_in[17];
  const float* t1_w   = (const float*)d_in[18];
  const float* t1_b   = (const float*)d_in[19];
  const float* t2_w   = (const float*)d_in[20];
  const float* t2_b   = (const float*)d_in[21];

  float* wsf = (float*)d_ws;
  // Era-choreographed regions (float offsets) — see R3 comments; unchanged.
  ushort_t* xs1p0 = (ushort_t*)(wsf + 0);
  ushort_t* xs1p1 = (ushort_t*)(wsf + 4194304);
  float*    cp0   = wsf + 8388608;               // conv2 partial kz0 (= h32 slot)
  float*    h32   = wsf + 8388608;
  float*    qp0   = wsf + 4194304;               // 3x3 partials (xs1p1 slot, dead)
  ushort_t* sE0   = (ushort_t*)(wsf + 0);        // split ping [0,1.05M)
  ushort_t* sE1   = (ushort_t*)(wsf + 1048576);  // split ping [1.05,2.1M)
  ushort_t* sF0   = (ushort_t*)(wsf + 2097152);  // split pong [2.1,3.15M)
  ushort_t* sF1   = (ushort_t*)(wsf + 3145728);  // split pong [3.15,4.19M)
  float*    pbest = wsf + 0;                     // vq-era
  int*      pbid  = (int*)(wsf + 131072);        // vq-era
  ushort_t* t1out = (ushort_t*)(wsf + 2097152);  // dec-era [2.1M, 6.29M)
  ushort_t* decn  = (ushort_t*)(wsf + 6291456);  // dec-era [6.29M, 7.34M)
  ushort_t* wp_c2   = (ushort_t*)(wsf + 12582912);
  ushort_t* wp_r0w3 = (ushort_t*)(wsf + 13631488);
  ushort_t* wp_r1w3 = (ushort_t*)(wsf + 14221312);
  ushort_t* wp_r0w1 = (ushort_t*)(wsf + 14811136);
  ushort_t* wp_r1w1 = (ushort_t*)(wsf + 14876672);
  float*    wt_c1   = wsf + 14942208;
  float*    wt_toz  = wsf + 14954496;
  float*    wt_fromz= wsf + 14970880;
  ushort_t* t1wb    = (ushort_t*)(wsf + 14987264);
  ushort_t* w2pk    = (ushort_t*)(wsf + 15511552);
  float*    cnorm   = wsf + 15544320;

  float* out_img = (float*)d_out;        // 393216
  float* z_e_out = out_img + 393216;     // 524288
  float* e_k_out = z_e_out + 524288;     // 524288
  float* ids_out = e_k_out + 524288;     // 8192 (stored as float)

  // ---- weight prep (merged: 11 -> 5 dispatches) ----
  k_prep_misc<<<434, 256, 0, stream>>>(c1_w, wt_c1, to_z_w, wt_toz,
                                       from_z_w, wt_fromz, cb, cnorm, t2_w, w2pk);
  k_prep_enc<0><<<256, 256, 0, stream>>>(c2_w, wp_c2);
  k_prep_enc2<1><<<512, 256, 0, stream>>>(r0_w3, wp_r0w3, r1_w3, wp_r1w3);
  k_prep_enc2<2><<<512, 256, 0, stream>>>(r0_w1, wp_r0w1, r1_w1, wp_r1w1);
  k_prep_t1w<<<4096, 256, 0, stream>>>(t1_w, t1wb);

  // ---- encoder ----
  k_conv1_split<<<dim3(64, 4, 8), 256, 0, stream>>>(x, xs1p0, xs1p1, wt_c1, c1_b);
  // conv2: plain-store partials cp0/cp1, epilogue: sum+relu -> h32 + splits
  k_enc_mfma_split<0><<<dim3(64, 4, 2), 256, 0, stream>>>(xs1p0, xs1p1, wp_c2, cp0);
  k_enc_epi<true><<<dim3(32, 16), 256, 0, stream>>>(cp0, h32, sE0, sE1, c2_b);
  // r0 w3 (halo-staged, per-cg barriers)
  k_enc_mfma_3x3h<<<dim3(64, 8, 2), 256, 0, stream>>>(sE0, sE1, wp_r0w3, qp0);
  k_enc_epi<false><<<dim3(32, 16), 256, 0, stream>>>(qp0, nullptr, sE0, sE1, r0_b3);
  // r0 w1: h += conv; write h32 + split(relu(h))
  k_enc_mfma<true ><<<dim3(64, 4), 256, 0, stream>>>(
      sE0, sE1, wp_r0w1, r0_b1, h32, sF0, sF1);
  // r1 w3
  k_enc_mfma_3x3h<<<dim3(64, 8, 2), 256, 0, stream>>>(sF0, sF1, wp_r1w3, qp0);
  k_enc_epi<false><<<dim3(32, 16), 256, 0, stream>>>(qp0, nullptr, sE0, sE1, r1_b3);
  // r1 w1: h += conv; write h32 only
  k_enc_mfma<false><<<dim3(64, 4), 256, 0, stream>>>(
      sE0, sE1, wp_r1w1, r1_b1, h32, nullptr, nullptr);
  // to_z (fp32)
  k_conv1x1<<<dim3(4, 4, 8), 256, 0, stream>>>(h32, z_e_out, wt_toz, to_z_b, 256, 64, 1024);

  // ---- VQ (chunk-parallel; bit-identical argmin) ----
  k_vq_part<<<dim3(32, 16), 256, 0, stream>>>(z_e_out, cb, cnorm, pbest, pbid);
  k_vq_reduce<<<32, 256, 0, stream>>>(pbest, pbid, cb, ids_out, e_k_out);

  // ---- decoder (bf16) ----
  k_from_z<<<dim3(4, 16, 8), 256, 0, stream>>>(e_k_out, decn, wt_fromz, from_z_b);
  k_mfma_t1<<<dim3(64, 2, 4), 256, 0, stream>>>(decn, t1wb, t1_b, t1out);
  k_mfma_t2<<<dim3(128, 4), 256, 0, stream>>>(t1out, w2pk, t2_b, out_img);
}

// Round 9
// 403.315 us; speedup vs baseline: 1.2442x; 1.0151x over previous
//
#include <hip/hip_runtime.h>
#include <math.h>

// ---------------------------------------------------------------------------
// VQ-VAE forward.
// Encoder: 256-ch convs as implicit-GEMM MFMA with 2-term bf16 split inputs
// (3 passes: w1x1 + w1x2 + w2x1). Big convs split-K=2 with PLAIN-STORE
// per-kz partial buffers. VQ: chunk-parallel partial argmin + reduce.
// Decoder: t1 + t2.
// R9: t1 -> per-c8 halo staging (R8's 3x3h pattern; 4 taps share a 6x34
//     halo, barriers 32->16, B bytes 256->104KB/block). t2 -> global_load_lds
//     staging (R5 pattern; linear LDS, dbuf, 1 barrier/chunk). Encoder
//     unchanged (conv2 at structure ceiling).
// ---------------------------------------------------------------------------

typedef unsigned int uint;
typedef unsigned short ushort_t;
using short8 = __attribute__((ext_vector_type(8))) short;
using f32x4  = __attribute__((ext_vector_type(4))) float;

// zero-initialized pad: invalid halo rows DMA from here (always zero)
__device__ __attribute__((aligned(16))) ushort_t g_zpad[512];

static __device__ __forceinline__ int rfl(int x) { return __builtin_amdgcn_readfirstlane(x); }
static __device__ __forceinline__ ushort_t f2bf(float f) {
  uint u = __float_as_uint(f);
  return (ushort_t)((u + 0x7fffu + ((u >> 16) & 1u)) >> 16);  // RNE; finite inputs
}
static __device__ __forceinline__ float bf2f(ushort_t b) {
  return __uint_as_float(((uint)b) << 16);
}
// direct global->LDS DMA, 16B per lane; lds dest = wave-uniform base + lane*16
static __device__ __forceinline__ void gload16(const ushort_t* g, void* l) {
  __builtin_amdgcn_global_load_lds(
      (const __attribute__((address_space(1))) void*)g,
      (__attribute__((address_space(3))) void*)l, 16, 0, 0);
}

// ---------- weight prep ----------
// merged small preps: 3 transposes + cnorm + t2w pack in one launch (434 blocks)
__global__ __launch_bounds__(256) void k_prep_misc(
    const float* __restrict__ c1w, float* __restrict__ wt_c1,
    const float* __restrict__ tozw, float* __restrict__ wt_toz,
    const float* __restrict__ fromzw, float* __restrict__ wt_fromz,
    const float* __restrict__ cb, float* __restrict__ cnorm,
    const float* __restrict__ t2w, ushort_t* __restrict__ w2pk)
{
  const int b = blockIdx.x, tid = threadIdx.x;
  if (b < 48) {            // c1 transpose: CO=256, CIKK=48 (12288 elems)
    int idx = b * 256 + tid;
    int co = idx % 256, i = idx / 256;
    wt_c1[idx] = c1w[co * 48 + i];
  } else if (b < 112) {    // to_z transpose: CO=64, CIKK=256 (16384)
    int idx = (b - 48) * 256 + tid;
    int co = idx % 64, i = idx / 64;
    wt_toz[idx] = tozw[co * 256 + i];
  } else if (b < 176) {    // from_z transpose: CO=256, CIKK=64 (16384)
    int idx = (b - 112) * 256 + tid;
    int co = idx % 256, i = idx / 256;
    wt_fromz[idx] = fromzw[co * 64 + i];
  } else if (b < 178) {    // cnorm[j] = sum_c cb[j][c]^2
    int idx = (b - 176) * 256 + tid;
    if (idx < 512) {
      float s = 0.f;
      for (int c = 0; c < 64; ++c) { float v = cb[idx * 64 + c]; s = fmaf(v, v, s); }
      cnorm[idx] = s;
    }
  } else {                 // t2_w pack: 65536 elems (256 blocks)
    int idx = (b - 178) * 256 + tid;
    int k = idx & 31, co = (idx >> 5) & 15, chunk = (idx >> 9) & 31, par = idx >> 14;
    int tap = chunk >> 3, cg = chunk & 7;
    int a = tap >> 1, bb = tap & 1;
    int ry = par & 1, rx = (par >> 1) & 1;
    int ky = ((ry + 1) & 1) + 2 * a;
    int kx = ((rx + 1) & 1) + 2 * bb;
    int ci = cg * 32 + k;
    float v = (co < 3) ? t2w[((ci * 3 + co) << 4) + ky * 4 + kx] : 0.f;
    w2pk[idx] = f2bf(v);
  }
}

// encoder MFMA weight pack: w[co][ci(256)][KH][KW] fp32 ->
// wp[chunk][coT(4)][pl(2)][row(64)][k(32)] bf16 split, chunk = tap*8 + cg
template<int KIND>  // 0: 4x4 (16 taps), 1: 3x3 (9 taps), 2: 1x1 (1 tap)
__global__ __launch_bounds__(256) void k_prep_enc(
    const float* __restrict__ w, ushort_t* __restrict__ wp)
{
  constexpr int KK = (KIND == 0) ? 16 : (KIND == 1 ? 9 : 1);
  constexpr int KW = (KIND == 0) ? 4  : (KIND == 1 ? 3 : 1);
  constexpr int NT = KK;  // taps
  const int tid = threadIdx.x;
  const int wvg = blockIdx.x * 4 + (tid >> 6);   // 0..1023
  const int lane = tid & 63;
  const int co = wvg >> 2;
  const int ci = (wvg & 3) * 64 + lane;
  const float* src = w + (size_t)(co * 256 + ci) * KK;
  const int coT = co >> 6, row = co & 63, cg = ci >> 5, k = ci & 31;
  float v[KK];
#pragma unroll
  for (int j = 0; j < KK; ++j) v[j] = src[j];
#pragma unroll
  for (int tap = 0; tap < NT; ++tap) {
    int ky, kx;
    if (KIND == 0)      { ky = tap >> 2; kx = tap & 3; }
    else if (KIND == 1) { ky = tap / 3;  kx = tap - ky * 3; }
    else                { ky = 0; kx = 0; }
    float val = v[ky * KW + kx];
    ushort_t b0 = f2bf(val);
    ushort_t b1 = f2bf(val - bf2f(b0));
    const int chunk = tap * 8 + cg;
    size_t base = ((size_t)(chunk * 4 + coT) << 12) + row * 32 + k;
    wp[base] = b0;          // pl=0
    wp[base + 2048] = b1;   // pl=1
  }
}

// paired variant: blocks 0..255 -> (wa,oa), 256..511 -> (wb2,ob)
template<int KIND>
__global__ __launch_bounds__(256) void k_prep_enc2(
    const float* __restrict__ wa, ushort_t* __restrict__ oa,
    const float* __restrict__ wb2, ushort_t* __restrict__ ob)
{
  constexpr int KK = (KIND == 0) ? 16 : (KIND == 1 ? 9 : 1);
  constexpr int KW = (KIND == 0) ? 4  : (KIND == 1 ? 3 : 1);
  constexpr int NT = KK;
  const float* w = (blockIdx.x < 256) ? wa : wb2;
  ushort_t* wp = (blockIdx.x < 256) ? oa : ob;
  const int bx = blockIdx.x & 255;
  const int tid = threadIdx.x;
  const int wvg = bx * 4 + (tid >> 6);
  const int lane = tid & 63;
  const int co = wvg >> 2;
  const int ci = (wvg & 3) * 64 + lane;
  const float* src = w + (size_t)(co * 256 + ci) * KK;
  const int coT = co >> 6, row = co & 63, cg = ci >> 5, k = ci & 31;
  float v[KK];
#pragma unroll
  for (int j = 0; j < KK; ++j) v[j] = src[j];
#pragma unroll
  for (int tap = 0; tap < NT; ++tap) {
    int ky, kx;
    if (KIND == 0)      { ky = tap >> 2; kx = tap & 3; }
    else if (KIND == 1) { ky = tap / 3;  kx = tap - ky * 3; }
    else                { ky = 0; kx = 0; }
    float val = v[ky * KW + kx];
    ushort_t b0 = f2bf(val);
    ushort_t b1 = f2bf(val - bf2f(b0));
    const int chunk = tap * 8 + cg;
    size_t base = ((size_t)(chunk * 4 + coT) << 12) + row * 32 + k;
    wp[base] = b0;
    wp[base + 2048] = b1;
  }
}

// t1_w [ci][co][ky][kx] -> bf16 [par][tap][c8][co][kk32]
__global__ void k_prep_t1w(const float* __restrict__ w, ushort_t* __restrict__ wb) {
  int idx = blockIdx.x * 256 + threadIdx.x;  // 1048576
  int kk  = idx & 31;
  int co  = (idx >> 5) & 255;
  int c8  = (idx >> 13) & 7;
  int tap = (idx >> 16) & 3;
  int par = idx >> 18;
  int ry = par & 1, rx = (par >> 1) & 1;
  int a = tap >> 1, b = tap & 1;
  int ky = ((ry + 1) & 1) + 2 * a;
  int kx = ((rx + 1) & 1) + 2 * b;
  int ci = c8 * 32 + kk;
  wb[idx] = f2bf(w[((ci * 256 + co) << 4) + ky * 4 + kx]);
}

// ---------- conv1: 3->256, 4x4 s2 p1, relu, output split-bf16 NHWC ----------
__global__ __launch_bounds__(256) void k_conv1_split(
    const float* __restrict__ in, ushort_t* __restrict__ o0, ushort_t* __restrict__ o1,
    const float* __restrict__ wT, const float* __restrict__ bias)
{
  __shared__ float s_in[3 * 360];  // parity-split cols, pitch 20 (2-way free)
  const int tid = threadIdx.x;
  const int lane = tid & 63;
  const int wv = rfl(tid >> 6);
  const int px = lane & 7, py = lane >> 3;
  const int tx = blockIdx.x & 7, ty = blockIdx.x >> 3;
  const int X = tx * 8, Y = ty * 8;
  const int cob = blockIdx.y * 64 + wv * 16;
  const int n = blockIdx.z;
  float acc[16];
#pragma unroll
  for (int i = 0; i < 16; ++i) acc[i] = bias[cob + i];
  const float* inN = in + (size_t)n * 3 * 16384;
  for (int e = tid; e < 3 * 360; e += 256) {
    int col2 = e % 20; int t = e / 20; int row = t % 18; int ci = t / 18;
    int pr = col2 / 10, hc = col2 % 10, ixl = 2 * hc + pr;
    int iy = 2 * Y - 1 + row, ix = 2 * X - 1 + ixl;
    float v = 0.f;
    if (ixl < 18 && (unsigned)iy < 128u && (unsigned)ix < 128u)
      v = inN[ci * 16384 + iy * 128 + ix];
    s_in[e] = v;
  }
  __syncthreads();
  const float* wc = wT + cob;
#pragma unroll
  for (int c = 0; c < 3; ++c) {
    const float* base = s_in + c * 360 + py * 40 + px;
#pragma unroll
    for (int ky = 0; ky < 4; ++ky) {
#pragma unroll
      for (int kx = 0; kx < 4; ++kx) {
        float iv = base[ky * 20 + (kx & 1) * 10 + (kx >> 1)];
        const float* w = wc + (size_t)(c * 16 + ky * 4 + kx) * 256;  // uniform
#pragma unroll
        for (int i = 0; i < 16; ++i) acc[i] = fmaf(iv, w[i], acc[i]);
      }
    }
  }
  const int pxg = n * 4096 + (Y + py) * 64 + (X + px);
  uint p0[8], p1[8];
#pragma unroll
  for (int i = 0; i < 8; ++i) {
    float va = fmaxf(acc[2 * i], 0.f), vb = fmaxf(acc[2 * i + 1], 0.f);
    ushort_t a0 = f2bf(va), b0 = f2bf(vb);
    ushort_t a1 = f2bf(va - bf2f(a0)), b1 = f2bf(vb - bf2f(b0));
    p0[i] = (uint)a0 | ((uint)b0 << 16);
    p1[i] = (uint)a1 | ((uint)b1 << 16);
  }
  ushort_t* d0 = o0 + (size_t)pxg * 256 + cob;
  ushort_t* d1 = o1 + (size_t)pxg * 256 + cob;
  uint4 v0a; v0a.x = p0[0]; v0a.y = p0[1]; v0a.z = p0[2]; v0a.w = p0[3];
  uint4 v0b; v0b.x = p0[4]; v0b.y = p0[5]; v0b.z = p0[6]; v0b.w = p0[7];
  uint4 v1a; v1a.x = p1[0]; v1a.y = p1[1]; v1a.z = p1[2]; v1a.w = p1[3];
  uint4 v1b; v1b.x = p1[4]; v1b.y = p1[5]; v1b.z = p1[6]; v1b.w = p1[7];
  *(uint4*)d0 = v0a; *(uint4*)(d0 + 8) = v0b;
  *(uint4*)d1 = v1a; *(uint4*)(d1 + 8) = v1b;
}

// ---------- conv2 implicit-GEMM MFMA, split-K=2, plain-store partial --------
// Block: 64co x 128px, 4 waves. grid (pxT 64, coT 4, kz 2).
// global_load_lds staging, linear LDS.
template<int KIND>  // 0: conv2 (128 chunks)
__global__ __launch_bounds__(256) void k_enc_mfma_split(
    const ushort_t* __restrict__ x0, const ushort_t* __restrict__ x1,
    const ushort_t* __restrict__ wp, float* __restrict__ part)
{
  __shared__ ushort_t smem[2][12288];   // per buf: sA 4096 us (8KB) | sB 8192 us (16KB)
  const int tid = threadIdx.x, lane = tid & 63, wv = tid >> 6;
  const int l15 = lane & 15, q = lane >> 4;
  const int pxT = blockIdx.x, coT = blockIdx.y;
  constexpr int NCH = (KIND == 0) ? 128 : 72;
  const int CH0 = blockIdx.z * (NCH / 2), CH1 = CH0 + NCH / 2;
  f32x4 acc[4][2];
#pragma unroll
  for (int m = 0; m < 4; ++m)
#pragma unroll
    for (int n = 0; n < 2; ++n) acc[m][n] = (f32x4){0.f, 0.f, 0.f, 0.f};

  // B staging: thread handles rows r0 and r0+64, 16B quarter kq
  const int r0 = tid >> 2, kq = tid & 3;
  int bimg[2], bu[2], bvc[2];
#pragma unroll
  for (int r = 0; r < 2; ++r) {
    int bpx = pxT * 128 + r0 + r * 64;
    bimg[r] = bpx >> 10; int bp = bpx & 1023; bu[r] = bp >> 5; bvc[r] = bp & 31;
  }
  const ushort_t* srcB[2][2];  // [row r][plane p], excludes cg offset
  int ptap = -1;
  auto retap = [&](int tap) {
    ptap = tap;
    int ky, kx;
    if (KIND == 0) { ky = tap >> 2; kx = tap & 3; }
    else           { ky = tap / 3;  kx = tap - ky * 3; }
#pragma unroll
    for (int r = 0; r < 2; ++r) {
      bool v; size_t rowb;
      if (KIND == 0) {
        int iy = 2 * bu[r] - 1 + ky, ix = 2 * bvc[r] - 1 + kx;
        v = ((unsigned)iy < 64u) && ((unsigned)ix < 64u);
        rowb = ((size_t)(bimg[r] * 4096 + iy * 64 + ix)) << 8;
      } else {
        int iy = bu[r] - 1 + ky, ix = bvc[r] - 1 + kx;
        v = ((unsigned)iy < 32u) && ((unsigned)ix < 32u);
        rowb = ((size_t)(bimg[r] * 1024 + iy * 32 + ix)) << 8;
      }
      srcB[r][0] = (v ? (x0 + rowb) : g_zpad) + kq * 8;
      srcB[r][1] = (v ? (x1 + rowb) : g_zpad) + kq * 8;
    }
  };

  const int wvb = wv * 1024;  // wave-uniform byte base (lane*16 auto)
  auto stage = [&](int chunk, int bi) {
    const int tap = chunk >> 3, cg = chunk & 7;
    if (tap != ptap) retap(tap);
    char* bufb = (char*)smem[bi];
    const ushort_t* ap = wp + ((size_t)(chunk * 4 + coT) << 12) + tid * 8;
    gload16(ap,        bufb + wvb);                        // sA pl0
    gload16(ap + 2048, bufb + 4096 + wvb);                 // sA pl1
    const int ko = cg * 32;
    gload16(srcB[0][0] + ko, bufb + 8192 + wvb);           // sB pl0 rows 0-63
    gload16(srcB[1][0] + ko, bufb + 8192 + 4096 + wvb);    // sB pl0 rows 64-127
    gload16(srcB[0][1] + ko, bufb + 16384 + wvb);          // sB pl1 rows 0-63
    gload16(srcB[1][1] + ko, bufb + 16384 + 4096 + wvb);   // sB pl1 rows 64-127
  };
  auto compute = [&](const ushort_t* buf) {
    const ushort_t* sA = buf;
    const ushort_t* sB = buf + 4096;
    short8 af[4][2], bf[2][2];
#pragma unroll
    for (int m = 0; m < 4; ++m)
#pragma unroll
      for (int pl = 0; pl < 2; ++pl)
        af[m][pl] = *(const short8*)(sA + pl * 2048 + (m * 16 + l15) * 32 + q * 8);
#pragma unroll
    for (int n = 0; n < 2; ++n)
#pragma unroll
      for (int pl = 0; pl < 2; ++pl)
        bf[n][pl] = *(const short8*)(sB + pl * 4096 + (wv * 32 + n * 16 + l15) * 32 + q * 8);
#pragma unroll
    for (int m = 0; m < 4; ++m)
#pragma unroll
      for (int n = 0; n < 2; ++n) {
        acc[m][n] = __builtin_amdgcn_mfma_f32_16x16x32_bf16(af[m][0], bf[n][0], acc[m][n], 0, 0, 0);
        acc[m][n] = __builtin_amdgcn_mfma_f32_16x16x32_bf16(af[m][0], bf[n][1], acc[m][n], 0, 0, 0);
        acc[m][n] = __builtin_amdgcn_mfma_f32_16x16x32_bf16(af[m][1], bf[n][0], acc[m][n], 0, 0, 0);
      }
  };

  stage(CH0, 0);
  __syncthreads();
  int cur = 0;
  for (int c = CH0; c < CH1; ++c) {
    if (c + 1 < CH1) stage(c + 1, cur ^ 1);   // DMA in flight under compute
    compute(smem[cur]);
    __syncthreads();                           // drains DMA; 1 barrier/chunk
    cur ^= 1;
  }

  // plain stores to this kz's private partial slice (deterministic)
  float* pz = part + ((size_t)blockIdx.z << 21);
#pragma unroll
  for (int m = 0; m < 4; ++m) {
#pragma unroll
    for (int n = 0; n < 2; ++n) {
#pragma unroll
      for (int r = 0; r < 4; ++r) {
        const int co_l = m * 16 + q * 4 + r;
        const int px_l = wv * 32 + n * 16 + l15;
        const int px = pxT * 128 + px_l;
        const int img = px >> 10, pp = px & 1023;
        const size_t ha = ((size_t)(img * 256 + coT * 64 + co_l)) * 1024 + pp;
        pz[ha] = acc[m][n][r];
      }
    }
  }
}

// ---------- 3x3 implicit-GEMM MFMA, split-K=2 (by cg), per-cg halo B --------
// Block 32co x 128px. Per cg: stage all 9 taps' A + 6x34 halo, 1 barrier,
// 108 MFMA, 1 barrier. grid (pxT 64, coT 8, kz 2).
__global__ __launch_bounds__(256) void k_enc_mfma_3x3h(
    const ushort_t* __restrict__ x0, const ushort_t* __restrict__ x1,
    const ushort_t* __restrict__ wp, float* __restrict__ part)
{
  __shared__ ushort_t smem[32768];  // A 18432 us | halo 14336 us (1632 used + pad)
  const int tid = threadIdx.x, lane = tid & 63, wv = tid >> 6;
  const int l15 = lane & 15, q = lane >> 4;
  const int pxT = blockIdx.x, coT = blockIdx.y;
  const int CG0 = blockIdx.z * 4;
  const int img = pxT >> 3;          // 8 blocks per 32x32 image
  const int U0 = (pxT & 7) * 4;      // base output row of this 128px strip
  f32x4 acc[2][2];
#pragma unroll
  for (int m = 0; m < 2; ++m)
#pragma unroll
    for (int n = 0; n < 2; ++n) acc[m][n] = (f32x4){0.f, 0.f, 0.f, 0.f};

  // halo DMA sources: slot = pl*816 + r*136 + c*4 + kq ; (pl, row U0-1+r, col c-1)
  const ushort_t* srcp[7];
#pragma unroll
  for (int i = 0; i < 7; ++i) {
    int slot = i * 256 + tid;
    int pl = slot >= 816 ? 1 : 0;
    int rem = slot - pl * 816;
    int rr = rem / 136;
    int c4 = rem - rr * 136;
    int cc = c4 >> 2, kq2 = c4 & 3;
    int iy = U0 - 1 + rr, ix = cc - 1;
    bool valid = (slot < 1632) && ((unsigned)iy < 32u) && ((unsigned)ix < 32u);
    const ushort_t* base = valid
        ? ((pl ? x1 : x0) + (((size_t)(img * 1024 + iy * 32 + ix)) << 8))
        : g_zpad;
    srcp[i] = base + kq2 * 8;
  }
  // A DMA source: per tap one 4KB DMA; threads 0..127 pl0, 128..255 pl1
  const int apl = tid >> 7;
  const int aus = apl * 2048 + (coT & 1) * 1024 + (tid & 127) * 8;
  const int coTq = coT >> 1;
  const int wvb = wv * 1024;
  char* bufb = (char*)smem;

  for (int cg = CG0; cg < CG0 + 4; ++cg) {
#pragma unroll
    for (int tap = 0; tap < 9; ++tap) {
      const int chunk = tap * 8 + cg;
      gload16(wp + ((size_t)(chunk * 4 + coTq) << 12) + aus, bufb + tap * 4096 + wvb);
    }
    const int ko = cg * 32;
#pragma unroll
    for (int i = 0; i < 7; ++i)
      gload16(srcp[i] + ko, bufb + 36864 + i * 4096 + wvb);
    __syncthreads();
    const ushort_t* Ab = smem;
    const ushort_t* Hb = smem + 18432;
#pragma unroll 3
    for (int tap = 0; tap < 9; ++tap) {
      const int ky = tap / 3, kx = tap - ky * 3;
      short8 af[2][2], bf[2][2];
#pragma unroll
      for (int m = 0; m < 2; ++m)
#pragma unroll
        for (int pl = 0; pl < 2; ++pl)
          af[m][pl] = *(const short8*)(Ab + tap * 2048 + pl * 1024 + (m * 16 + l15) * 32 + q * 8);
      const int r = wv + ky;
#pragma unroll
      for (int n = 0; n < 2; ++n)
#pragma unroll
        for (int pl = 0; pl < 2; ++pl)
          bf[n][pl] = *(const short8*)(Hb + pl * 6528 + r * 1088 + (n * 16 + l15 + kx) * 32 + q * 8);
#pragma unroll
      for (int m = 0; m < 2; ++m)
#pragma unroll
        for (int n = 0; n < 2; ++n) {
          acc[m][n] = __builtin_amdgcn_mfma_f32_16x16x32_bf16(af[m][0], bf[n][0], acc[m][n], 0, 0, 0);
          acc[m][n] = __builtin_amdgcn_mfma_f32_16x16x32_bf16(af[m][0], bf[n][1], acc[m][n], 0, 0, 0);
          acc[m][n] = __builtin_amdgcn_mfma_f32_16x16x32_bf16(af[m][1], bf[n][0], acc[m][n], 0, 0, 0);
        }
    }
    __syncthreads();   // before restage (single-buffered)
  }

  float* pz = part + ((size_t)blockIdx.z << 21);
#pragma unroll
  for (int m = 0; m < 2; ++m) {
#pragma unroll
    for (int n = 0; n < 2; ++n) {
#pragma unroll
      for (int r = 0; r < 4; ++r) {
        const int co_l = m * 16 + q * 4 + r;
        const int px_l = wv * 32 + n * 16 + l15;
        const int px = pxT * 128 + px_l;
        const int imgp = px >> 10, pp = px & 1023;
        const size_t ha = ((size_t)(imgp * 256 + coT * 32 + co_l)) * 1024 + pp;
        pz[ha] = acc[m][n][r];
      }
    }
  }
}

// ---------- epilogue for split convs ----------
template<bool WH>
__global__ __launch_bounds__(256) void k_enc_epi(
    const float* __restrict__ part, float* __restrict__ h32,
    ushort_t* __restrict__ s0, ushort_t* __restrict__ s1,
    const float* __restrict__ bias)
{
  const int px = blockIdx.x * 256 + threadIdx.x;  // 8192
  const int co0 = blockIdx.y * 16;
  const int img = px >> 10, pp = px & 1023;
  const float* part1 = part + (1u << 21);
  uint p0[8], p1[8];
#pragma unroll
  for (int i = 0; i < 8; ++i) {
    size_t ha = ((size_t)(img * 256 + co0 + 2 * i)) * 1024 + pp;
    size_t hb = ha + 1024;
    float va = part[ha] + part1[ha] + bias[co0 + 2 * i];
    float vb = part[hb] + part1[hb] + bias[co0 + 2 * i + 1];
    float sa, sb;
    if (WH) {
      va = fmaxf(va, 0.f); vb = fmaxf(vb, 0.f);
      h32[ha] = va; h32[hb] = vb; sa = va; sb = vb;
    } else { sa = fmaxf(va, 0.f); sb = fmaxf(vb, 0.f); }
    ushort_t a0 = f2bf(sa), b0 = f2bf(sb);
    p0[i] = (uint)a0 | ((uint)b0 << 16);
    p1[i] = (uint)f2bf(sa - bf2f(a0)) | ((uint)f2bf(sb - bf2f(b0)) << 16);
  }
  ushort_t* d0 = s0 + (size_t)px * 256 + co0;
  ushort_t* d1 = s1 + (size_t)px * 256 + co0;
  uint4 v0a; v0a.x = p0[0]; v0a.y = p0[1]; v0a.z = p0[2]; v0a.w = p0[3];
  uint4 v0b; v0b.x = p0[4]; v0b.y = p0[5]; v0b.z = p0[6]; v0b.w = p0[7];
  uint4 v1a; v1a.x = p1[0]; v1a.y = p1[1]; v1a.z = p1[2]; v1a.w = p1[3];
  uint4 v1b; v1b.x = p1[4]; v1b.y = p1[5]; v1b.z = p1[6]; v1b.w = p1[7];
  *(uint4*)d0 = v0a; *(uint4*)(d0 + 8) = v0b;
  *(uint4*)d1 = v1a; *(uint4*)(d1 + 8) = v1b;
}

// ---------- residual 1x1 MFMA (fused epilogue) ----------
template<bool WS>
__global__ __launch_bounds__(256) void k_enc_mfma(
    const ushort_t* __restrict__ x0, const ushort_t* __restrict__ x1,
    const ushort_t* __restrict__ wp, const float* __restrict__ bias,
    float* __restrict__ h32, ushort_t* __restrict__ sp0, ushort_t* __restrict__ sp1)
{
  __shared__ ushort_t smem[24576];   // dbuf 2x12288; WS epilogue reuses [0,18432)
  const int tid = threadIdx.x, lane = tid & 63, wv = tid >> 6;
  const int l15 = lane & 15, q = lane >> 4;
  const int pxT = blockIdx.x, coT = blockIdx.y;
  f32x4 acc[4][2];
#pragma unroll
  for (int m = 0; m < 4; ++m)
#pragma unroll
    for (int n = 0; n < 2; ++n) acc[m][n] = (f32x4){0.f, 0.f, 0.f, 0.f};

  const int r0 = tid >> 2, kq = tid & 3;
  const ushort_t* srcB[2][2];
#pragma unroll
  for (int r = 0; r < 2; ++r) {
    size_t rowb = ((size_t)(pxT * 128 + r0 + r * 64)) << 8;
    srcB[r][0] = x0 + rowb + kq * 8;
    srcB[r][1] = x1 + rowb + kq * 8;
  }
  const int wvb = wv * 1024;
  auto stage = [&](int c, int bi) {
    char* bufb = (char*)(smem + bi * 12288);
    const ushort_t* ap = wp + ((size_t)(c * 4 + coT) << 12) + tid * 8;
    gload16(ap,        bufb + wvb);
    gload16(ap + 2048, bufb + 4096 + wvb);
    const int ko = c * 32;
    gload16(srcB[0][0] + ko, bufb + 8192 + wvb);
    gload16(srcB[1][0] + ko, bufb + 8192 + 4096 + wvb);
    gload16(srcB[0][1] + ko, bufb + 16384 + wvb);
    gload16(srcB[1][1] + ko, bufb + 16384 + 4096 + wvb);
  };
  auto compute = [&](const ushort_t* buf) {
    const ushort_t* sA = buf;
    const ushort_t* sB = buf + 4096;
    short8 af[4][2], bf[2][2];
#pragma unroll
    for (int m = 0; m < 4; ++m)
#pragma unroll
      for (int pl = 0; pl < 2; ++pl)
        af[m][pl] = *(const short8*)(sA + pl * 2048 + (m * 16 + l15) * 32 + q * 8);
#pragma unroll
    for (int n = 0; n < 2; ++n)
#pragma unroll
      for (int pl = 0; pl < 2; ++pl)
        bf[n][pl] = *(const short8*)(sB + pl * 4096 + (wv * 32 + n * 16 + l15) * 32 + q * 8);
#pragma unroll
    for (int m = 0; m < 4; ++m)
#pragma unroll
      for (int n = 0; n < 2; ++n) {
        acc[m][n] = __builtin_amdgcn_mfma_f32_16x16x32_bf16(af[m][0], bf[n][0], acc[m][n], 0, 0, 0);
        acc[m][n] = __builtin_amdgcn_mfma_f32_16x16x32_bf16(af[m][0], bf[n][1], acc[m][n], 0, 0, 0);
        acc[m][n] = __builtin_amdgcn_mfma_f32_16x16x32_bf16(af[m][1], bf[n][0], acc[m][n], 0, 0, 0);
      }
  };

  stage(0, 0);
  __syncthreads();
  int cur = 0;
  for (int c = 0; c < 8; ++c) {
    if (c + 1 < 8) stage(c + 1, cur ^ 1);
    compute(smem + cur * 12288);
    __syncthreads();
    cur ^= 1;
  }

#pragma unroll
  for (int m = 0; m < 4; ++m) {
#pragma unroll
    for (int n = 0; n < 2; ++n) {
#pragma unroll
      for (int r = 0; r < 4; ++r) {
        const int co_l = m * 16 + q * 4 + r;
        const int px_l = wv * 32 + n * 16 + l15;
        float v = acc[m][n][r] + bias[coT * 64 + co_l];
        const int px = pxT * 128 + px_l;
        const int img = px >> 10, pp = px & 1023;
        const size_t ha = ((size_t)(img * 256 + coT * 64 + co_l)) * 1024 + pp;
        v += h32[ha];
        h32[ha] = v;
        if (WS) {
          float sv = fmaxf(v, 0.f);
          ushort_t b0 = f2bf(sv);
          smem[px_l * 72 + co_l] = b0;
          smem[9216 + px_l * 72 + co_l] = f2bf(sv - bf2f(b0));
        }
      }
    }
  }
  if (WS) {
    __syncthreads();
#pragma unroll
    for (int i = 0; i < 8; ++i) {
      int idx = tid + 256 * i;
      int pl = idx >> 10, w2 = idx & 1023, pxl = w2 >> 3, g = w2 & 7;
      uint4 vv = *(const uint4*)(smem + pl * 9216 + pxl * 72 + g * 8);
      ushort_t* dst = (pl ? sp1 : sp0) + ((size_t)(pxT * 128 + pxl)) * 256 + coT * 64 + g * 8;
      *(uint4*)dst = vv;
    }
  }
}

// ---------- 1x1 conv fp32 (to_z only) ----------
__global__ __launch_bounds__(256) void k_conv1x1(
    const float* __restrict__ in, float* __restrict__ out,
    const float* __restrict__ wT, const float* __restrict__ bias,
    int CI, int CO, int P)
{
  const int p = blockIdx.x * 256 + threadIdx.x;
  const int cob = blockIdx.y * 16;
  const int n = blockIdx.z;
  const float* inN = in + (size_t)n * CI * P + p;
  float acc[16];
#pragma unroll
  for (int i = 0; i < 16; ++i) acc[i] = bias[cob + i];
  const float* wr = wT + cob;
#pragma unroll 4
  for (int ci = 0; ci < CI; ++ci) {
    float iv = inN[(size_t)ci * P];
    const float* w = wr + (size_t)ci * CO;  // uniform
#pragma unroll
    for (int i = 0; i < 16; ++i) acc[i] = fmaf(iv, w[i], acc[i]);
  }
  float* outN = out + (size_t)n * CO * P + p;
#pragma unroll
  for (int i = 0; i < 16; ++i) outN[(size_t)(cob + i) * P] = acc[i];
}

// ---------- VQ partial: 16 chunks of 32 codes; per-j math identical ----------
__global__ __launch_bounds__(256) void k_vq_part(
    const float* __restrict__ z_e, const float* __restrict__ cb,
    const float* __restrict__ cnorm, float* __restrict__ pbest, int* __restrict__ pbid)
{
  int g = blockIdx.x * 256 + threadIdx.x;  // 8192 points
  int chunk = blockIdx.y;                  // 16 chunks
  int img = g >> 10, p = g & 1023;
  const float* zp = z_e + (size_t)img * 64 * 1024 + p;
  float z[64];
#pragma unroll
  for (int c = 0; c < 64; ++c) z[c] = zp[(size_t)c * 1024];
  float best = 3.4e38f; int bid = chunk << 5;
  const int j0 = chunk << 5;
  for (int j = j0; j < j0 + 32; ++j) {
    const float* cj = cb + j * 64;  // uniform -> scalar loads
    float m = 0.f;
#pragma unroll
    for (int c = 0; c < 64; ++c) m = fmaf(z[c], cj[c], m);
    float d = fmaf(-2.f, m, cnorm[j]);
    if (d < best) { best = d; bid = j; }  // strict <: first-min within chunk
  }
  pbest[chunk * 8192 + g] = best;
  pbid[chunk * 8192 + g] = bid;
}

// ---------- VQ reduce: argmin across chunks (ascending -> np.argmin) + e_k ----------
__global__ __launch_bounds__(256) void k_vq_reduce(
    const float* __restrict__ pbest, const int* __restrict__ pbid,
    const float* __restrict__ cb, float* __restrict__ ids_f, float* __restrict__ ek)
{
  int g = blockIdx.x * 256 + threadIdx.x;  // 8192
  float best = 3.4e38f; int bid = 0;
#pragma unroll
  for (int ch = 0; ch < 16; ++ch) {
    float d = pbest[ch * 8192 + g];
    int b = pbid[ch * 8192 + g];
    if (d < best) { best = d; bid = b; }
  }
  ids_f[g] = (float)bid;
  int img = g >> 10, p = g & 1023;
  const float* cbid = cb + bid * 64;
  float* ekp = ek + (size_t)img * 64 * 1024 + p;
#pragma unroll
  for (int c = 0; c < 64; ++c) ekp[(size_t)c * 1024] = cbid[c];
}

// ---------- from_z 1x1 (64->256) + relu -> NHWC bf16 ----------
__global__ __launch_bounds__(256) void k_from_z(
    const float* __restrict__ ek, ushort_t* __restrict__ nhwc,
    const float* __restrict__ wT, const float* __restrict__ bias)
{
  const int p = blockIdx.x * 256 + threadIdx.x;  // 0..1023
  const int co0 = blockIdx.y * 16;
  const int n = blockIdx.z;
  const float* inN = ek + (size_t)n * 64 * 1024 + p;
  float acc[16];
#pragma unroll
  for (int i = 0; i < 16; ++i) acc[i] = bias[co0 + i];
#pragma unroll 4
  for (int ci = 0; ci < 64; ++ci) {
    float iv = inN[(size_t)ci * 1024];
    const float* w = wT + (size_t)ci * 256 + co0;  // uniform
#pragma unroll
    for (int i = 0; i < 16; ++i) acc[i] = fmaf(iv, w[i], acc[i]);
  }
  uint pk[8];
#pragma unroll
  for (int i = 0; i < 8; ++i) {
    ushort_t lo = f2bf(fmaxf(acc[2 * i], 0.f));
    ushort_t hi = f2bf(fmaxf(acc[2 * i + 1], 0.f));
    pk[i] = (uint)lo | ((uint)hi << 16);
  }
  ushort_t* op = nhwc + (((size_t)n * 1024 + p) * 256 + co0);
  uint4 v0; v0.x = pk[0]; v0.y = pk[1]; v0.z = pk[2]; v0.w = pk[3];
  uint4 v1; v1.x = pk[4]; v1.y = pk[5]; v1.z = pk[6]; v1.w = pk[7];
  *(uint4*)(op) = v0;
  *(uint4*)(op + 8) = v1;
}

// ---------- t1 convtranspose 4x4 s2 p1, 256->256, bf16 MFMA, relu -> bf16 NHWC
// R9: per-c8 halo staging (3x3h pattern): 4 taps share a 6x34 halo tile.
// Block 128co x 128px; per c8: A 4 taps x 8KB + halo 13KB, 2 barriers.
__global__ __launch_bounds__(256) void k_mfma_t1(
    const ushort_t* __restrict__ nhwc, const ushort_t* __restrict__ wb,
    const float* __restrict__ bias, ushort_t* __restrict__ t1o)
{
  __shared__ ushort_t smem[24576];  // A 16384 us (4 taps x 4096) | halo 8192 us
  const int tid = threadIdx.x;
  const int lane = tid & 63;
  const int wv = tid >> 6;
  const int wm = wv & 1, wn = wv >> 1;
  const int l15 = lane & 15, q = lane >> 4;
  const int pxT = blockIdx.x, coT = blockIdx.y, par = blockIdx.z;
  const int ry = par & 1, rx = (par >> 1) & 1;
  const int pxbase = pxT * 128;
  const int img = pxbase >> 10;
  const int U0 = (pxT & 7) * 4;   // base input-grid row of this 128px strip
  f32x4 acc[4][4];
#pragma unroll
  for (int i = 0; i < 4; ++i)
#pragma unroll
    for (int j = 0; j < 4; ++j) acc[i][j] = (f32x4){0.f, 0.f, 0.f, 0.f};

  // halo DMA sources: slot = r*136 + c*4 + kq ; (row U0-1+r, col c-1), 816 slots
  const ushort_t* srcp[4];
#pragma unroll
  for (int i = 0; i < 4; ++i) {
    int slot = i * 256 + tid;
    int rr = slot / 136;
    int c4 = slot - rr * 136;
    int cc = c4 >> 2, kq2 = c4 & 3;
    int iy = U0 - 1 + rr, ix = cc - 1;
    bool valid = (slot < 816) && ((unsigned)iy < 32u) && ((unsigned)ix < 32u);
    const ushort_t* base = valid
        ? (nhwc + (((size_t)(img * 1024 + iy * 32 + ix)) << 8))
        : g_zpad;
    srcp[i] = base + kq2 * 8;
  }
  const int wvb = wv * 1024;
  char* bufb = (char*)smem;

  for (int c8 = 0; c8 < 8; ++c8) {
#pragma unroll
    for (int tap = 0; tap < 4; ++tap) {
      const ushort_t* Ab = wb + ((size_t)((par * 4 + tap) * 8 + c8) << 13)
                           + coT * 4096 + tid * 8;
      gload16(Ab,        bufb + tap * 8192 + wvb);
      gload16(Ab + 2048, bufb + tap * 8192 + 4096 + wvb);
    }
    const int ko = c8 * 32;
#pragma unroll
    for (int i = 0; i < 4; ++i)
      gload16(srcp[i] + ko, bufb + 32768 + i * 4096 + wvb);
    __syncthreads();
    const ushort_t* A = smem;
    const ushort_t* H = smem + 16384;
#pragma unroll
    for (int tap = 0; tap < 4; ++tap) {
      const int a = tap >> 1, b = tap & 1;
      const int dr = ry + 1 - a, dc = rx + 1 - b;
      short8 af[4], bfr[4];
#pragma unroll
      for (int i = 0; i < 4; ++i)
        af[i] = *(const short8*)(A + tap * 4096 + (wm * 64 + i * 16 + l15) * 32 + q * 8);
#pragma unroll
      for (int j = 0; j < 4; ++j) {
        const int row = wn * 64 + j * 16 + l15;
        const int rr = (row >> 5) + dr, cc = (row & 31) + dc;
        bfr[j] = *(const short8*)(H + rr * 1088 + cc * 32 + q * 8);
      }
#pragma unroll
      for (int i = 0; i < 4; ++i)
#pragma unroll
        for (int j = 0; j < 4; ++j)
          acc[i][j] = __builtin_amdgcn_mfma_f32_16x16x32_bf16(af[i], bfr[j], acc[i][j], 0, 0, 0);
    }
    __syncthreads();   // before restage (single-buffered)
  }

#pragma unroll
  for (int i = 0; i < 4; ++i) {
    int co = coT * 128 + wm * 64 + i * 16 + q * 4;
#pragma unroll
    for (int j = 0; j < 4; ++j) {
      int px = pxbase + wn * 64 + j * 16 + l15;
      int u = (px >> 5) & 31, vv = px & 31;
      int oy = 2 * u + ry, ox = 2 * vv + rx;
      ushort_t e0 = f2bf(fmaxf(acc[i][j][0] + bias[co + 0], 0.f));
      ushort_t e1 = f2bf(fmaxf(acc[i][j][1] + bias[co + 1], 0.f));
      ushort_t e2 = f2bf(fmaxf(acc[i][j][2] + bias[co + 2], 0.f));
      ushort_t e3 = f2bf(fmaxf(acc[i][j][3] + bias[co + 3], 0.f));
      uint2 pk; pk.x = (uint)e0 | ((uint)e1 << 16); pk.y = (uint)e2 | ((uint)e3 << 16);
      *(uint2*)(t1o + ((size_t)(img * 4096 + oy * 64 + ox) * 256 + co)) = pk;
    }
  }
}

// ---------- t2 convtranspose 4x4 s2 p1, 256->3, bf16 MFMA, sigmoid ----------
// R9: global_load_lds staging (linear LDS, dbuf, 1 barrier/chunk).
__global__ __launch_bounds__(256) void k_mfma_t2(
    const ushort_t* __restrict__ t1o, const ushort_t* __restrict__ wb,
    const float* __restrict__ bias, float* __restrict__ out)
{
  __shared__ ushort_t smem[2][8704];  // per buf: sA 8192 us | sB 512 us
  const int tid = threadIdx.x, lane = tid & 63, wv = tid >> 6;
  const int l15 = lane & 15, q = lane >> 4;
  const int pxb = blockIdx.x * 256;
  const int par = blockIdx.y;
  const int ry = par & 1, rx = (par >> 1) & 1;
  f32x4 acc[4];
#pragma unroll
  for (int m = 0; m < 4; ++m) acc[m] = (f32x4){0.f, 0.f, 0.f, 0.f};
  const int kg = tid & 3;
  const ushort_t* srcA[4];
  int ptap = -1;
  auto retap = [&](int tap) {
    ptap = tap;
    const int a = tap >> 1, b = tap & 1;
#pragma unroll
    for (int i = 0; i < 4; ++i) {
      int row = (tid >> 2) + 64 * i;
      int px = pxb + row;
      int img = px >> 12, p = px & 4095, u = p >> 6, v = p & 63;
      int iy = u + ry - a, ix = v + rx - b;
      bool valid = ((unsigned)iy < 64u) && ((unsigned)ix < 64u);
      srcA[i] = (valid ? (t1o + (((size_t)(img * 4096 + iy * 64 + ix)) << 8)) : g_zpad)
                + kg * 8;
    }
  };
  const int wvb = wv * 1024;
  auto stage = [&](int c, int bi) {
    const int tap = c >> 3, cg = c & 7;
    if (tap != ptap) retap(tap);
    char* bufb = (char*)smem[bi];
    const int ko = cg * 32;
#pragma unroll
    for (int i = 0; i < 4; ++i)
      gload16(srcA[i] + ko, bufb + i * 4096 + wvb);
    if (tid < 64)
      gload16(wb + ((size_t)(par * 32 + c)) * 512 + tid * 8, bufb + 16384);
  };
  auto compute = [&](const ushort_t* buf) {
    const ushort_t* sA = buf;
    const ushort_t* sB = buf + 8192;
    short8 bf = *(const short8*)(sB + l15 * 32 + q * 8);
#pragma unroll
    for (int m = 0; m < 4; ++m) {
      const int row = wv * 64 + m * 16 + l15;
      short8 af = *(const short8*)(sA + row * 32 + q * 8);
      acc[m] = __builtin_amdgcn_mfma_f32_16x16x32_bf16(af, bf, acc[m], 0, 0, 0);
    }
  };

  stage(0, 0);
  __syncthreads();
  int cur = 0;
  for (int c = 0; c < 32; ++c) {
    if (c + 1 < 32) stage(c + 1, cur ^ 1);
    compute(smem[cur]);
    __syncthreads();
    cur ^= 1;
  }

  const int co = l15;
  if (co < 3) {
    float bco = bias[co];
#pragma unroll
    for (int m = 0; m < 4; ++m) {
#pragma unroll
      for (int r = 0; r < 4; ++r) {
        int px = pxb + wv * 64 + m * 16 + q * 4 + r;
        int img = px >> 12, p = px & 4095, u = p >> 6, v = p & 63;
        size_t addr = ((size_t)(img * 3 + co)) * 16384 + (2 * u + ry) * 128 + (2 * v + rx);
        out[addr] = 1.f / (1.f + expf(-(acc[m][r] + bco)));
      }
    }
  }
}

// ---------------------------------------------------------------------------
extern "C" void kernel_launch(void* const* d_in, const int* in_sizes, int n_in,
                              void* d_out, int out_size, void* d_ws, size_t ws_size,
                              hipStream_t stream) {
  (void)in_sizes; (void)n_in; (void)out_size; (void)ws_size;
  const float* x      = (const float*)d_in[0];
  const float* c1_w   = (const float*)d_in[1];
  const float* c1_b   = (const float*)d_in[2];
  const float* c2_w   = (const float*)d_in[3];
  const float* c2_b   = (const float*)d_in[4];
  const float* r0_w3  = (const float*)d_in[5];
  const float* r0_b3  = (const float*)d_in[6];
  const float* r0_w1  = (const float*)d_in[7];
  const float* r0_b1  = (const float*)d_in[8];
  const float* r1_w3  = (const float*)d_in[9];
  const float* r1_b3  = (const float*)d_in[10];
  const float* r1_w1  = (const float*)d_in[11];
  const float* r1_b1  = (const float*)d_in[12];
  const float* to_z_w = (const float*)d_in[13];
  const float* to_z_b = (const float*)d_in[14];
  const float* cb     = (const float*)d_in[15];
  const float* from_z_w = (const float*)d_in[16];
  const float* from_z_b = (const float*)d_in[17];
  const float* t1_w   = (const float*)d_in[18];
  const float* t1_b   = (const float*)d_in[19];
  const float* t2_w   = (const float*)d_in[20];
  const float* t2_b   = (const float*)d_in[21];

  float* wsf = (float*)d_ws;
  // Era-choreographed regions (float offsets) — see R3 comments; unchanged.
  ushort_t* xs1p0 = (ushort_t*)(wsf + 0);
  ushort_t* xs1p1 = (ushort_t*)(wsf + 4194304);
  float*    cp0   = wsf + 8388608;               // conv2 partial kz0 (= h32 slot)
  float*    h32   = wsf + 8388608;
  float*    qp0   = wsf + 4194304;               // 3x3 partials (xs1p1 slot, dead)
  ushort_t* sE0   = (ushort_t*)(wsf + 0);        // split ping [0,1.05M)
  ushort_t* sE1   = (ushort_t*)(wsf + 1048576);  // split ping [1.05,2.1M)
  ushort_t* sF0   = (ushort_t*)(wsf + 2097152);  // split pong [2.1,3.15M)
  ushort_t* sF1   = (ushort_t*)(wsf + 3145728);  // split pong [3.15,4.19M)
  float*    pbest = wsf + 0;                     // vq-era
  int*      pbid  = (int*)(wsf + 131072);        // vq-era
  ushort_t* t1out = (ushort_t*)(wsf + 2097152);  // dec-era [2.1M, 6.29M)
  ushort_t* decn  = (ushort_t*)(wsf + 6291456);  // dec-era [6.29M, 7.34M)
  ushort_t* wp_c2   = (ushort_t*)(wsf + 12582912);
  ushort_t* wp_r0w3 = (ushort_t*)(wsf + 13631488);
  ushort_t* wp_r1w3 = (ushort_t*)(wsf + 14221312);
  ushort_t* wp_r0w1 = (ushort_t*)(wsf + 14811136);
  ushort_t* wp_r1w1 = (ushort_t*)(wsf + 14876672);
  float*    wt_c1   = wsf + 14942208;
  float*    wt_toz  = wsf + 14954496;
  float*    wt_fromz= wsf + 14970880;
  ushort_t* t1wb    = (ushort_t*)(wsf + 14987264);
  ushort_t* w2pk    = (ushort_t*)(wsf + 15511552);
  float*    cnorm   = wsf + 15544320;

  float* out_img = (float*)d_out;        // 393216
  float* z_e_out = out_img + 393216;     // 524288
  float* e_k_out = z_e_out + 524288;     // 524288
  float* ids_out = e_k_out + 524288;     // 8192 (stored as float)

  // ---- weight prep (merged: 5 dispatches) ----
  k_prep_misc<<<434, 256, 0, stream>>>(c1_w, wt_c1, to_z_w, wt_toz,
                                       from_z_w, wt_fromz, cb, cnorm, t2_w, w2pk);
  k_prep_enc<0><<<256, 256, 0, stream>>>(c2_w, wp_c2);
  k_prep_enc2<1><<<512, 256, 0, stream>>>(r0_w3, wp_r0w3, r1_w3, wp_r1w3);
  k_prep_enc2<2><<<512, 256, 0, stream>>>(r0_w1, wp_r0w1, r1_w1, wp_r1w1);
  k_prep_t1w<<<4096, 256, 0, stream>>>(t1_w, t1wb);

  // ---- encoder ----
  k_conv1_split<<<dim3(64, 4, 8), 256, 0, stream>>>(x, xs1p0, xs1p1, wt_c1, c1_b);
  // conv2: plain-store partials cp0/cp1, epilogue: sum+relu -> h32 + splits
  k_enc_mfma_split<0><<<dim3(64, 4, 2), 256, 0, stream>>>(xs1p0, xs1p1, wp_c2, cp0);
  k_enc_epi<true><<<dim3(32, 16), 256, 0, stream>>>(cp0, h32, sE0, sE1, c2_b);
  // r0 w3 (halo-staged, per-cg barriers)
  k_enc_mfma_3x3h<<<dim3(64, 8, 2), 256, 0, stream>>>(sE0, sE1, wp_r0w3, qp0);
  k_enc_epi<false><<<dim3(32, 16), 256, 0, stream>>>(qp0, nullptr, sE0, sE1, r0_b3);
  // r0 w1: h += conv; write h32 + split(relu(h))
  k_enc_mfma<true ><<<dim3(64, 4), 256, 0, stream>>>(
      sE0, sE1, wp_r0w1, r0_b1, h32, sF0, sF1);
  // r1 w3
  k_enc_mfma_3x3h<<<dim3(64, 8, 2), 256, 0, stream>>>(sF0, sF1, wp_r1w3, qp0);
  k_enc_epi<false><<<dim3(32, 16), 256, 0, stream>>>(qp0, nullptr, sE0, sE1, r1_b3);
  // r1 w1: h += conv; write h32 only
  k_enc_mfma<false><<<dim3(64, 4), 256, 0, stream>>>(
      sE0, sE1, wp_r1w1, r1_b1, h32, nullptr, nullptr);
  // to_z (fp32)
  k_conv1x1<<<dim3(4, 4, 8), 256, 0, stream>>>(h32, z_e_out, wt_toz, to_z_b, 256, 64, 1024);

  // ---- VQ (chunk-parallel; bit-identical argmin) ----
  k_vq_part<<<dim3(32, 16), 256, 0, stream>>>(z_e_out, cb, cnorm, pbest, pbid);
  k_vq_reduce<<<32, 256, 0, stream>>>(pbest, pbid, cb, ids_out, e_k_out);

  // ---- decoder (bf16) ----
  k_from_z<<<dim3(4, 16, 8), 256, 0, stream>>>(e_k_out, decn, wt_fromz, from_z_b);
  k_mfma_t1<<<dim3(64, 2, 4), 256, 0, stream>>>(decn, t1wb, t1_b, t1out);
  k_mfma_t2<<<dim3(128, 4), 256, 0, stream>>>(t1out, w2pk, t2_b, out_img);
}

// Round 10
// 392.165 us; speedup vs baseline: 1.2795x; 1.0284x over previous
//
#include <hip/hip_runtime.h>
#include <math.h>

// ---------------------------------------------------------------------------
// VQ-VAE forward.
// Encoder: 256-ch convs as implicit-GEMM MFMA with 2-term bf16 split inputs
// (3 passes: w1x1 + w1x2 + w2x1). conv2 split-K=2 with plain-store partials.
// 3x3 convs: kz=1 halo kernel with FUSED epilogue (no partials, no epi
// dispatch). VQ: chunk-parallel partial argmin + reduce. Decoder: t1 + t2.
// R10: fold 3x3 split-K into one block (occupancy unchanged: 64KB LDS caps
//      at 2 blocks/CU either way) + fuse relu/split epilogue via LDS
//      transpose (k_enc_mfma WS pattern). Deletes 2 epi dispatches and
//      ~32MB/conv of partial scaffolding traffic.
// ---------------------------------------------------------------------------

typedef unsigned int uint;
typedef unsigned short ushort_t;
using short8 = __attribute__((ext_vector_type(8))) short;
using f32x4  = __attribute__((ext_vector_type(4))) float;

// zero-initialized pad: invalid halo rows DMA from here (always zero)
__device__ __attribute__((aligned(16))) ushort_t g_zpad[512];

static __device__ __forceinline__ int rfl(int x) { return __builtin_amdgcn_readfirstlane(x); }
static __device__ __forceinline__ ushort_t f2bf(float f) {
  uint u = __float_as_uint(f);
  return (ushort_t)((u + 0x7fffu + ((u >> 16) & 1u)) >> 16);  // RNE; finite inputs
}
static __device__ __forceinline__ float bf2f(ushort_t b) {
  return __uint_as_float(((uint)b) << 16);
}
// direct global->LDS DMA, 16B per lane; lds dest = wave-uniform base + lane*16
static __device__ __forceinline__ void gload16(const ushort_t* g, void* l) {
  __builtin_amdgcn_global_load_lds(
      (const __attribute__((address_space(1))) void*)g,
      (__attribute__((address_space(3))) void*)l, 16, 0, 0);
}

// ---------- weight prep ----------
// merged small preps: 3 transposes + cnorm + t2w pack in one launch (434 blocks)
__global__ __launch_bounds__(256) void k_prep_misc(
    const float* __restrict__ c1w, float* __restrict__ wt_c1,
    const float* __restrict__ tozw, float* __restrict__ wt_toz,
    const float* __restrict__ fromzw, float* __restrict__ wt_fromz,
    const float* __restrict__ cb, float* __restrict__ cnorm,
    const float* __restrict__ t2w, ushort_t* __restrict__ w2pk)
{
  const int b = blockIdx.x, tid = threadIdx.x;
  if (b < 48) {            // c1 transpose: CO=256, CIKK=48 (12288 elems)
    int idx = b * 256 + tid;
    int co = idx % 256, i = idx / 256;
    wt_c1[idx] = c1w[co * 48 + i];
  } else if (b < 112) {    // to_z transpose: CO=64, CIKK=256 (16384)
    int idx = (b - 48) * 256 + tid;
    int co = idx % 64, i = idx / 64;
    wt_toz[idx] = tozw[co * 256 + i];
  } else if (b < 176) {    // from_z transpose: CO=256, CIKK=64 (16384)
    int idx = (b - 112) * 256 + tid;
    int co = idx % 256, i = idx / 256;
    wt_fromz[idx] = fromzw[co * 64 + i];
  } else if (b < 178) {    // cnorm[j] = sum_c cb[j][c]^2
    int idx = (b - 176) * 256 + tid;
    if (idx < 512) {
      float s = 0.f;
      for (int c = 0; c < 64; ++c) { float v = cb[idx * 64 + c]; s = fmaf(v, v, s); }
      cnorm[idx] = s;
    }
  } else {                 // t2_w pack: 65536 elems (256 blocks)
    int idx = (b - 178) * 256 + tid;
    int k = idx & 31, co = (idx >> 5) & 15, chunk = (idx >> 9) & 31, par = idx >> 14;
    int tap = chunk >> 3, cg = chunk & 7;
    int a = tap >> 1, bb = tap & 1;
    int ry = par & 1, rx = (par >> 1) & 1;
    int ky = ((ry + 1) & 1) + 2 * a;
    int kx = ((rx + 1) & 1) + 2 * bb;
    int ci = cg * 32 + k;
    float v = (co < 3) ? t2w[((ci * 3 + co) << 4) + ky * 4 + kx] : 0.f;
    w2pk[idx] = f2bf(v);
  }
}

// encoder MFMA weight pack: w[co][ci(256)][KH][KW] fp32 ->
// wp[chunk][coT(4)][pl(2)][row(64)][k(32)] bf16 split, chunk = tap*8 + cg
template<int KIND>  // 0: 4x4 (16 taps), 1: 3x3 (9 taps), 2: 1x1 (1 tap)
__global__ __launch_bounds__(256) void k_prep_enc(
    const float* __restrict__ w, ushort_t* __restrict__ wp)
{
  constexpr int KK = (KIND == 0) ? 16 : (KIND == 1 ? 9 : 1);
  constexpr int KW = (KIND == 0) ? 4  : (KIND == 1 ? 3 : 1);
  constexpr int NT = KK;  // taps
  const int tid = threadIdx.x;
  const int wvg = blockIdx.x * 4 + (tid >> 6);   // 0..1023
  const int lane = tid & 63;
  const int co = wvg >> 2;
  const int ci = (wvg & 3) * 64 + lane;
  const float* src = w + (size_t)(co * 256 + ci) * KK;
  const int coT = co >> 6, row = co & 63, cg = ci >> 5, k = ci & 31;
  float v[KK];
#pragma unroll
  for (int j = 0; j < KK; ++j) v[j] = src[j];
#pragma unroll
  for (int tap = 0; tap < NT; ++tap) {
    int ky, kx;
    if (KIND == 0)      { ky = tap >> 2; kx = tap & 3; }
    else if (KIND == 1) { ky = tap / 3;  kx = tap - ky * 3; }
    else                { ky = 0; kx = 0; }
    float val = v[ky * KW + kx];
    ushort_t b0 = f2bf(val);
    ushort_t b1 = f2bf(val - bf2f(b0));
    const int chunk = tap * 8 + cg;
    size_t base = ((size_t)(chunk * 4 + coT) << 12) + row * 32 + k;
    wp[base] = b0;          // pl=0
    wp[base + 2048] = b1;   // pl=1
  }
}

// paired variant: blocks 0..255 -> (wa,oa), 256..511 -> (wb2,ob)
template<int KIND>
__global__ __launch_bounds__(256) void k_prep_enc2(
    const float* __restrict__ wa, ushort_t* __restrict__ oa,
    const float* __restrict__ wb2, ushort_t* __restrict__ ob)
{
  constexpr int KK = (KIND == 0) ? 16 : (KIND == 1 ? 9 : 1);
  constexpr int KW = (KIND == 0) ? 4  : (KIND == 1 ? 3 : 1);
  constexpr int NT = KK;
  const float* w = (blockIdx.x < 256) ? wa : wb2;
  ushort_t* wp = (blockIdx.x < 256) ? oa : ob;
  const int bx = blockIdx.x & 255;
  const int tid = threadIdx.x;
  const int wvg = bx * 4 + (tid >> 6);
  const int lane = tid & 63;
  const int co = wvg >> 2;
  const int ci = (wvg & 3) * 64 + lane;
  const float* src = w + (size_t)(co * 256 + ci) * KK;
  const int coT = co >> 6, row = co & 63, cg = ci >> 5, k = ci & 31;
  float v[KK];
#pragma unroll
  for (int j = 0; j < KK; ++j) v[j] = src[j];
#pragma unroll
  for (int tap = 0; tap < NT; ++tap) {
    int ky, kx;
    if (KIND == 0)      { ky = tap >> 2; kx = tap & 3; }
    else if (KIND == 1) { ky = tap / 3;  kx = tap - ky * 3; }
    else                { ky = 0; kx = 0; }
    float val = v[ky * KW + kx];
    ushort_t b0 = f2bf(val);
    ushort_t b1 = f2bf(val - bf2f(b0));
    const int chunk = tap * 8 + cg;
    size_t base = ((size_t)(chunk * 4 + coT) << 12) + row * 32 + k;
    wp[base] = b0;
    wp[base + 2048] = b1;
  }
}

// t1_w [ci][co][ky][kx] -> bf16 [par][tap][c8][co][kk32]
__global__ void k_prep_t1w(const float* __restrict__ w, ushort_t* __restrict__ wb) {
  int idx = blockIdx.x * 256 + threadIdx.x;  // 1048576
  int kk  = idx & 31;
  int co  = (idx >> 5) & 255;
  int c8  = (idx >> 13) & 7;
  int tap = (idx >> 16) & 3;
  int par = idx >> 18;
  int ry = par & 1, rx = (par >> 1) & 1;
  int a = tap >> 1, b = tap & 1;
  int ky = ((ry + 1) & 1) + 2 * a;
  int kx = ((rx + 1) & 1) + 2 * b;
  int ci = c8 * 32 + kk;
  wb[idx] = f2bf(w[((ci * 256 + co) << 4) + ky * 4 + kx]);
}

// ---------- conv1: 3->256, 4x4 s2 p1, relu, output split-bf16 NHWC ----------
__global__ __launch_bounds__(256) void k_conv1_split(
    const float* __restrict__ in, ushort_t* __restrict__ o0, ushort_t* __restrict__ o1,
    const float* __restrict__ wT, const float* __restrict__ bias)
{
  __shared__ float s_in[3 * 360];  // parity-split cols, pitch 20 (2-way free)
  const int tid = threadIdx.x;
  const int lane = tid & 63;
  const int wv = rfl(tid >> 6);
  const int px = lane & 7, py = lane >> 3;
  const int tx = blockIdx.x & 7, ty = blockIdx.x >> 3;
  const int X = tx * 8, Y = ty * 8;
  const int cob = blockIdx.y * 64 + wv * 16;
  const int n = blockIdx.z;
  float acc[16];
#pragma unroll
  for (int i = 0; i < 16; ++i) acc[i] = bias[cob + i];
  const float* inN = in + (size_t)n * 3 * 16384;
  for (int e = tid; e < 3 * 360; e += 256) {
    int col2 = e % 20; int t = e / 20; int row = t % 18; int ci = t / 18;
    int pr = col2 / 10, hc = col2 % 10, ixl = 2 * hc + pr;
    int iy = 2 * Y - 1 + row, ix = 2 * X - 1 + ixl;
    float v = 0.f;
    if (ixl < 18 && (unsigned)iy < 128u && (unsigned)ix < 128u)
      v = inN[ci * 16384 + iy * 128 + ix];
    s_in[e] = v;
  }
  __syncthreads();
  const float* wc = wT + cob;
#pragma unroll
  for (int c = 0; c < 3; ++c) {
    const float* base = s_in + c * 360 + py * 40 + px;
#pragma unroll
    for (int ky = 0; ky < 4; ++ky) {
#pragma unroll
      for (int kx = 0; kx < 4; ++kx) {
        float iv = base[ky * 20 + (kx & 1) * 10 + (kx >> 1)];
        const float* w = wc + (size_t)(c * 16 + ky * 4 + kx) * 256;  // uniform
#pragma unroll
        for (int i = 0; i < 16; ++i) acc[i] = fmaf(iv, w[i], acc[i]);
      }
    }
  }
  const int pxg = n * 4096 + (Y + py) * 64 + (X + px);
  uint p0[8], p1[8];
#pragma unroll
  for (int i = 0; i < 8; ++i) {
    float va = fmaxf(acc[2 * i], 0.f), vb = fmaxf(acc[2 * i + 1], 0.f);
    ushort_t a0 = f2bf(va), b0 = f2bf(vb);
    ushort_t a1 = f2bf(va - bf2f(a0)), b1 = f2bf(vb - bf2f(b0));
    p0[i] = (uint)a0 | ((uint)b0 << 16);
    p1[i] = (uint)a1 | ((uint)b1 << 16);
  }
  ushort_t* d0 = o0 + (size_t)pxg * 256 + cob;
  ushort_t* d1 = o1 + (size_t)pxg * 256 + cob;
  uint4 v0a; v0a.x = p0[0]; v0a.y = p0[1]; v0a.z = p0[2]; v0a.w = p0[3];
  uint4 v0b; v0b.x = p0[4]; v0b.y = p0[5]; v0b.z = p0[6]; v0b.w = p0[7];
  uint4 v1a; v1a.x = p1[0]; v1a.y = p1[1]; v1a.z = p1[2]; v1a.w = p1[3];
  uint4 v1b; v1b.x = p1[4]; v1b.y = p1[5]; v1b.z = p1[6]; v1b.w = p1[7];
  *(uint4*)d0 = v0a; *(uint4*)(d0 + 8) = v0b;
  *(uint4*)d1 = v1a; *(uint4*)(d1 + 8) = v1b;
}

// ---------- conv2 implicit-GEMM MFMA, split-K=2, plain-store partial --------
// Block: 64co x 128px, 4 waves. grid (pxT 64, coT 4, kz 2).
// global_load_lds staging, linear LDS.
template<int KIND>  // 0: conv2 (128 chunks)
__global__ __launch_bounds__(256) void k_enc_mfma_split(
    const ushort_t* __restrict__ x0, const ushort_t* __restrict__ x1,
    const ushort_t* __restrict__ wp, float* __restrict__ part)
{
  __shared__ ushort_t smem[2][12288];   // per buf: sA 4096 us (8KB) | sB 8192 us (16KB)
  const int tid = threadIdx.x, lane = tid & 63, wv = tid >> 6;
  const int l15 = lane & 15, q = lane >> 4;
  const int pxT = blockIdx.x, coT = blockIdx.y;
  constexpr int NCH = (KIND == 0) ? 128 : 72;
  const int CH0 = blockIdx.z * (NCH / 2), CH1 = CH0 + NCH / 2;
  f32x4 acc[4][2];
#pragma unroll
  for (int m = 0; m < 4; ++m)
#pragma unroll
    for (int n = 0; n < 2; ++n) acc[m][n] = (f32x4){0.f, 0.f, 0.f, 0.f};

  // B staging: thread handles rows r0 and r0+64, 16B quarter kq
  const int r0 = tid >> 2, kq = tid & 3;
  int bimg[2], bu[2], bvc[2];
#pragma unroll
  for (int r = 0; r < 2; ++r) {
    int bpx = pxT * 128 + r0 + r * 64;
    bimg[r] = bpx >> 10; int bp = bpx & 1023; bu[r] = bp >> 5; bvc[r] = bp & 31;
  }
  const ushort_t* srcB[2][2];  // [row r][plane p], excludes cg offset
  int ptap = -1;
  auto retap = [&](int tap) {
    ptap = tap;
    int ky, kx;
    if (KIND == 0) { ky = tap >> 2; kx = tap & 3; }
    else           { ky = tap / 3;  kx = tap - ky * 3; }
#pragma unroll
    for (int r = 0; r < 2; ++r) {
      bool v; size_t rowb;
      if (KIND == 0) {
        int iy = 2 * bu[r] - 1 + ky, ix = 2 * bvc[r] - 1 + kx;
        v = ((unsigned)iy < 64u) && ((unsigned)ix < 64u);
        rowb = ((size_t)(bimg[r] * 4096 + iy * 64 + ix)) << 8;
      } else {
        int iy = bu[r] - 1 + ky, ix = bvc[r] - 1 + kx;
        v = ((unsigned)iy < 32u) && ((unsigned)ix < 32u);
        rowb = ((size_t)(bimg[r] * 1024 + iy * 32 + ix)) << 8;
      }
      srcB[r][0] = (v ? (x0 + rowb) : g_zpad) + kq * 8;
      srcB[r][1] = (v ? (x1 + rowb) : g_zpad) + kq * 8;
    }
  };

  const int wvb = wv * 1024;  // wave-uniform byte base (lane*16 auto)
  auto stage = [&](int chunk, int bi) {
    const int tap = chunk >> 3, cg = chunk & 7;
    if (tap != ptap) retap(tap);
    char* bufb = (char*)smem[bi];
    const ushort_t* ap = wp + ((size_t)(chunk * 4 + coT) << 12) + tid * 8;
    gload16(ap,        bufb + wvb);                        // sA pl0
    gload16(ap + 2048, bufb + 4096 + wvb);                 // sA pl1
    const int ko = cg * 32;
    gload16(srcB[0][0] + ko, bufb + 8192 + wvb);           // sB pl0 rows 0-63
    gload16(srcB[1][0] + ko, bufb + 8192 + 4096 + wvb);    // sB pl0 rows 64-127
    gload16(srcB[0][1] + ko, bufb + 16384 + wvb);          // sB pl1 rows 0-63
    gload16(srcB[1][1] + ko, bufb + 16384 + 4096 + wvb);   // sB pl1 rows 64-127
  };
  auto compute = [&](const ushort_t* buf) {
    const ushort_t* sA = buf;
    const ushort_t* sB = buf + 4096;
    short8 af[4][2], bf[2][2];
#pragma unroll
    for (int m = 0; m < 4; ++m)
#pragma unroll
      for (int pl = 0; pl < 2; ++pl)
        af[m][pl] = *(const short8*)(sA + pl * 2048 + (m * 16 + l15) * 32 + q * 8);
#pragma unroll
    for (int n = 0; n < 2; ++n)
#pragma unroll
      for (int pl = 0; pl < 2; ++pl)
        bf[n][pl] = *(const short8*)(sB + pl * 4096 + (wv * 32 + n * 16 + l15) * 32 + q * 8);
#pragma unroll
    for (int m = 0; m < 4; ++m)
#pragma unroll
      for (int n = 0; n < 2; ++n) {
        acc[m][n] = __builtin_amdgcn_mfma_f32_16x16x32_bf16(af[m][0], bf[n][0], acc[m][n], 0, 0, 0);
        acc[m][n] = __builtin_amdgcn_mfma_f32_16x16x32_bf16(af[m][0], bf[n][1], acc[m][n], 0, 0, 0);
        acc[m][n] = __builtin_amdgcn_mfma_f32_16x16x32_bf16(af[m][1], bf[n][0], acc[m][n], 0, 0, 0);
      }
  };

  stage(CH0, 0);
  __syncthreads();
  int cur = 0;
  for (int c = CH0; c < CH1; ++c) {
    if (c + 1 < CH1) stage(c + 1, cur ^ 1);   // DMA in flight under compute
    compute(smem[cur]);
    __syncthreads();                           // drains DMA; 1 barrier/chunk
    cur ^= 1;
  }

  // plain stores to this kz's private partial slice (deterministic)
  float* pz = part + ((size_t)blockIdx.z << 21);
#pragma unroll
  for (int m = 0; m < 4; ++m) {
#pragma unroll
    for (int n = 0; n < 2; ++n) {
#pragma unroll
      for (int r = 0; r < 4; ++r) {
        const int co_l = m * 16 + q * 4 + r;
        const int px_l = wv * 32 + n * 16 + l15;
        const int px = pxT * 128 + px_l;
        const int img = px >> 10, pp = px & 1023;
        const size_t ha = ((size_t)(img * 256 + coT * 64 + co_l)) * 1024 + pp;
        pz[ha] = acc[m][n][r];
      }
    }
  }
}

// ---------- 3x3 implicit-GEMM MFMA, kz=1, FUSED epilogue --------------------
// Block 32co x 128px. Per cg (0..7): stage all 9 taps' A + 6x34 halo,
// 1 barrier, 108 MFMA, 1 barrier. Then relu+split epilogue via LDS
// transpose (no partials, no epi dispatch). grid (pxT 64, coT 8).
__global__ __launch_bounds__(256) void k_enc_mfma_3x3f(
    const ushort_t* __restrict__ x0, const ushort_t* __restrict__ x1,
    const ushort_t* __restrict__ wp, const float* __restrict__ bias,
    ushort_t* __restrict__ s0, ushort_t* __restrict__ s1)
{
  __shared__ ushort_t smem[32768];  // A 18432 us | halo 14336 us; epi reuses [0,8192)
  const int tid = threadIdx.x, lane = tid & 63, wv = tid >> 6;
  const int l15 = lane & 15, q = lane >> 4;
  const int pxT = blockIdx.x, coT = blockIdx.y;
  const int img = pxT >> 3;          // 8 blocks per 32x32 image
  const int U0 = (pxT & 7) * 4;      // base output row of this 128px strip
  f32x4 acc[2][2];
#pragma unroll
  for (int m = 0; m < 2; ++m)
#pragma unroll
    for (int n = 0; n < 2; ++n) acc[m][n] = (f32x4){0.f, 0.f, 0.f, 0.f};

  // halo DMA sources: slot = pl*816 + r*136 + c*4 + kq ; (pl, row U0-1+r, col c-1)
  const ushort_t* srcp[7];
#pragma unroll
  for (int i = 0; i < 7; ++i) {
    int slot = i * 256 + tid;
    int pl = slot >= 816 ? 1 : 0;
    int rem = slot - pl * 816;
    int rr = rem / 136;
    int c4 = rem - rr * 136;
    int cc = c4 >> 2, kq2 = c4 & 3;
    int iy = U0 - 1 + rr, ix = cc - 1;
    bool valid = (slot < 1632) && ((unsigned)iy < 32u) && ((unsigned)ix < 32u);
    const ushort_t* base = valid
        ? ((pl ? x1 : x0) + (((size_t)(img * 1024 + iy * 32 + ix)) << 8))
        : g_zpad;
    srcp[i] = base + kq2 * 8;
  }
  // A DMA source: per tap one 4KB DMA; threads 0..127 pl0, 128..255 pl1
  const int apl = tid >> 7;
  const int aus = apl * 2048 + (coT & 1) * 1024 + (tid & 127) * 8;
  const int coTq = coT >> 1;
  const int wvb = wv * 1024;
  char* bufb = (char*)smem;

  for (int cg = 0; cg < 8; ++cg) {
#pragma unroll
    for (int tap = 0; tap < 9; ++tap) {
      const int chunk = tap * 8 + cg;
      gload16(wp + ((size_t)(chunk * 4 + coTq) << 12) + aus, bufb + tap * 4096 + wvb);
    }
    const int ko = cg * 32;
#pragma unroll
    for (int i = 0; i < 7; ++i)
      gload16(srcp[i] + ko, bufb + 36864 + i * 4096 + wvb);
    __syncthreads();
    const ushort_t* Ab = smem;
    const ushort_t* Hb = smem + 18432;
#pragma unroll 3
    for (int tap = 0; tap < 9; ++tap) {
      const int ky = tap / 3, kx = tap - ky * 3;
      short8 af[2][2], bf[2][2];
#pragma unroll
      for (int m = 0; m < 2; ++m)
#pragma unroll
        for (int pl = 0; pl < 2; ++pl)
          af[m][pl] = *(const short8*)(Ab + tap * 2048 + pl * 1024 + (m * 16 + l15) * 32 + q * 8);
      const int r = wv + ky;
#pragma unroll
      for (int n = 0; n < 2; ++n)
#pragma unroll
        for (int pl = 0; pl < 2; ++pl)
          bf[n][pl] = *(const short8*)(Hb + pl * 6528 + r * 1088 + (n * 16 + l15 + kx) * 32 + q * 8);
#pragma unroll
      for (int m = 0; m < 2; ++m)
#pragma unroll
        for (int n = 0; n < 2; ++n) {
          acc[m][n] = __builtin_amdgcn_mfma_f32_16x16x32_bf16(af[m][0], bf[n][0], acc[m][n], 0, 0, 0);
          acc[m][n] = __builtin_amdgcn_mfma_f32_16x16x32_bf16(af[m][0], bf[n][1], acc[m][n], 0, 0, 0);
          acc[m][n] = __builtin_amdgcn_mfma_f32_16x16x32_bf16(af[m][1], bf[n][0], acc[m][n], 0, 0, 0);
        }
    }
    __syncthreads();   // before restage; final one protects epilogue smem reuse
  }

  // fused epilogue: splits of relu(acc + bias) via LDS transpose
  // smem layout: [pl(2)][px_l(128)][co_l(32)] ushort = 8192 us
  const int cob = coT * 32;
#pragma unroll
  for (int m = 0; m < 2; ++m) {
#pragma unroll
    for (int n = 0; n < 2; ++n) {
#pragma unroll
      for (int r = 0; r < 4; ++r) {
        const int co_l = m * 16 + q * 4 + r;
        const int px_l = wv * 32 + n * 16 + l15;
        float sv = fmaxf(acc[m][n][r] + bias[cob + co_l], 0.f);
        ushort_t b0 = f2bf(sv);
        smem[px_l * 32 + co_l] = b0;
        smem[4096 + px_l * 32 + co_l] = f2bf(sv - bf2f(b0));
      }
    }
  }
  __syncthreads();
#pragma unroll
  for (int i = 0; i < 4; ++i) {
    int idx = tid + 256 * i;          // 0..1023 uint4 units
    int pl = idx >> 9;
    int rem = idx & 511;
    int px_l = rem >> 2, g = rem & 3;
    uint4 vv = *(const uint4*)(smem + pl * 4096 + px_l * 32 + g * 8);
    ushort_t* dst = (pl ? s1 : s0) + ((size_t)(pxT * 128 + px_l)) * 256 + cob + g * 8;
    *(uint4*)dst = vv;
  }
}

// ---------- epilogue for conv2 split ----------
// v = p0 + p1 + bias; relu; h32 = v; splits.
template<bool WH>
__global__ __launch_bounds__(256) void k_enc_epi(
    const float* __restrict__ part, float* __restrict__ h32,
    ushort_t* __restrict__ s0, ushort_t* __restrict__ s1,
    const float* __restrict__ bias)
{
  const int px = blockIdx.x * 256 + threadIdx.x;  // 8192
  const int co0 = blockIdx.y * 16;
  const int img = px >> 10, pp = px & 1023;
  const float* part1 = part + (1u << 21);
  uint p0[8], p1[8];
#pragma unroll
  for (int i = 0; i < 8; ++i) {
    size_t ha = ((size_t)(img * 256 + co0 + 2 * i)) * 1024 + pp;
    size_t hb = ha + 1024;
    float va = part[ha] + part1[ha] + bias[co0 + 2 * i];
    float vb = part[hb] + part1[hb] + bias[co0 + 2 * i + 1];
    float sa, sb;
    if (WH) {
      va = fmaxf(va, 0.f); vb = fmaxf(vb, 0.f);
      h32[ha] = va; h32[hb] = vb; sa = va; sb = vb;
    } else { sa = fmaxf(va, 0.f); sb = fmaxf(vb, 0.f); }
    ushort_t a0 = f2bf(sa), b0 = f2bf(sb);
    p0[i] = (uint)a0 | ((uint)b0 << 16);
    p1[i] = (uint)f2bf(sa - bf2f(a0)) | ((uint)f2bf(sb - bf2f(b0)) << 16);
  }
  ushort_t* d0 = s0 + (size_t)px * 256 + co0;
  ushort_t* d1 = s1 + (size_t)px * 256 + co0;
  uint4 v0a; v0a.x = p0[0]; v0a.y = p0[1]; v0a.z = p0[2]; v0a.w = p0[3];
  uint4 v0b; v0b.x = p0[4]; v0b.y = p0[5]; v0b.z = p0[6]; v0b.w = p0[7];
  uint4 v1a; v1a.x = p1[0]; v1a.y = p1[1]; v1a.z = p1[2]; v1a.w = p1[3];
  uint4 v1b; v1b.x = p1[4]; v1b.y = p1[5]; v1b.z = p1[6]; v1b.w = p1[7];
  *(uint4*)d0 = v0a; *(uint4*)(d0 + 8) = v0b;
  *(uint4*)d1 = v1a; *(uint4*)(d1 + 8) = v1b;
}

// ---------- residual 1x1 MFMA (fused epilogue) ----------
template<bool WS>
__global__ __launch_bounds__(256) void k_enc_mfma(
    const ushort_t* __restrict__ x0, const ushort_t* __restrict__ x1,
    const ushort_t* __restrict__ wp, const float* __restrict__ bias,
    float* __restrict__ h32, ushort_t* __restrict__ sp0, ushort_t* __restrict__ sp1)
{
  __shared__ ushort_t smem[24576];   // dbuf 2x12288; WS epilogue reuses [0,18432)
  const int tid = threadIdx.x, lane = tid & 63, wv = tid >> 6;
  const int l15 = lane & 15, q = lane >> 4;
  const int pxT = blockIdx.x, coT = blockIdx.y;
  f32x4 acc[4][2];
#pragma unroll
  for (int m = 0; m < 4; ++m)
#pragma unroll
    for (int n = 0; n < 2; ++n) acc[m][n] = (f32x4){0.f, 0.f, 0.f, 0.f};

  const int r0 = tid >> 2, kq = tid & 3;
  const ushort_t* srcB[2][2];
#pragma unroll
  for (int r = 0; r < 2; ++r) {
    size_t rowb = ((size_t)(pxT * 128 + r0 + r * 64)) << 8;
    srcB[r][0] = x0 + rowb + kq * 8;
    srcB[r][1] = x1 + rowb + kq * 8;
  }
  const int wvb = wv * 1024;
  auto stage = [&](int c, int bi) {
    char* bufb = (char*)(smem + bi * 12288);
    const ushort_t* ap = wp + ((size_t)(c * 4 + coT) << 12) + tid * 8;
    gload16(ap,        bufb + wvb);
    gload16(ap + 2048, bufb + 4096 + wvb);
    const int ko = c * 32;
    gload16(srcB[0][0] + ko, bufb + 8192 + wvb);
    gload16(srcB[1][0] + ko, bufb + 8192 + 4096 + wvb);
    gload16(srcB[0][1] + ko, bufb + 16384 + wvb);
    gload16(srcB[1][1] + ko, bufb + 16384 + 4096 + wvb);
  };
  auto compute = [&](const ushort_t* buf) {
    const ushort_t* sA = buf;
    const ushort_t* sB = buf + 4096;
    short8 af[4][2], bf[2][2];
#pragma unroll
    for (int m = 0; m < 4; ++m)
#pragma unroll
      for (int pl = 0; pl < 2; ++pl)
        af[m][pl] = *(const short8*)(sA + pl * 2048 + (m * 16 + l15) * 32 + q * 8);
#pragma unroll
    for (int n = 0; n < 2; ++n)
#pragma unroll
      for (int pl = 0; pl < 2; ++pl)
        bf[n][pl] = *(const short8*)(sB + pl * 4096 + (wv * 32 + n * 16 + l15) * 32 + q * 8);
#pragma unroll
    for (int m = 0; m < 4; ++m)
#pragma unroll
      for (int n = 0; n < 2; ++n) {
        acc[m][n] = __builtin_amdgcn_mfma_f32_16x16x32_bf16(af[m][0], bf[n][0], acc[m][n], 0, 0, 0);
        acc[m][n] = __builtin_amdgcn_mfma_f32_16x16x32_bf16(af[m][0], bf[n][1], acc[m][n], 0, 0, 0);
        acc[m][n] = __builtin_amdgcn_mfma_f32_16x16x32_bf16(af[m][1], bf[n][0], acc[m][n], 0, 0, 0);
      }
  };

  stage(0, 0);
  __syncthreads();
  int cur = 0;
  for (int c = 0; c < 8; ++c) {
    if (c + 1 < 8) stage(c + 1, cur ^ 1);
    compute(smem + cur * 12288);
    __syncthreads();
    cur ^= 1;
  }

#pragma unroll
  for (int m = 0; m < 4; ++m) {
#pragma unroll
    for (int n = 0; n < 2; ++n) {
#pragma unroll
      for (int r = 0; r < 4; ++r) {
        const int co_l = m * 16 + q * 4 + r;
        const int px_l = wv * 32 + n * 16 + l15;
        float v = acc[m][n][r] + bias[coT * 64 + co_l];
        const int px = pxT * 128 + px_l;
        const int img = px >> 10, pp = px & 1023;
        const size_t ha = ((size_t)(img * 256 + coT * 64 + co_l)) * 1024 + pp;
        v += h32[ha];
        h32[ha] = v;
        if (WS) {
          float sv = fmaxf(v, 0.f);
          ushort_t b0 = f2bf(sv);
          smem[px_l * 72 + co_l] = b0;
          smem[9216 + px_l * 72 + co_l] = f2bf(sv - bf2f(b0));
        }
      }
    }
  }
  if (WS) {
    __syncthreads();
#pragma unroll
    for (int i = 0; i < 8; ++i) {
      int idx = tid + 256 * i;
      int pl = idx >> 10, w2 = idx & 1023, pxl = w2 >> 3, g = w2 & 7;
      uint4 vv = *(const uint4*)(smem + pl * 9216 + pxl * 72 + g * 8);
      ushort_t* dst = (pl ? sp1 : sp0) + ((size_t)(pxT * 128 + pxl)) * 256 + coT * 64 + g * 8;
      *(uint4*)dst = vv;
    }
  }
}

// ---------- 1x1 conv fp32 (to_z only) ----------
__global__ __launch_bounds__(256) void k_conv1x1(
    const float* __restrict__ in, float* __restrict__ out,
    const float* __restrict__ wT, const float* __restrict__ bias,
    int CI, int CO, int P)
{
  const int p = blockIdx.x * 256 + threadIdx.x;
  const int cob = blockIdx.y * 16;
  const int n = blockIdx.z;
  const float* inN = in + (size_t)n * CI * P + p;
  float acc[16];
#pragma unroll
  for (int i = 0; i < 16; ++i) acc[i] = bias[cob + i];
  const float* wr = wT + cob;
#pragma unroll 4
  for (int ci = 0; ci < CI; ++ci) {
    float iv = inN[(size_t)ci * P];
    const float* w = wr + (size_t)ci * CO;  // uniform
#pragma unroll
    for (int i = 0; i < 16; ++i) acc[i] = fmaf(iv, w[i], acc[i]);
  }
  float* outN = out + (size_t)n * CO * P + p;
#pragma unroll
  for (int i = 0; i < 16; ++i) outN[(size_t)(cob + i) * P] = acc[i];
}

// ---------- VQ partial: 16 chunks of 32 codes; per-j math identical ----------
__global__ __launch_bounds__(256) void k_vq_part(
    const float* __restrict__ z_e, const float* __restrict__ cb,
    const float* __restrict__ cnorm, float* __restrict__ pbest, int* __restrict__ pbid)
{
  int g = blockIdx.x * 256 + threadIdx.x;  // 8192 points
  int chunk = blockIdx.y;                  // 16 chunks
  int img = g >> 10, p = g & 1023;
  const float* zp = z_e + (size_t)img * 64 * 1024 + p;
  float z[64];
#pragma unroll
  for (int c = 0; c < 64; ++c) z[c] = zp[(size_t)c * 1024];
  float best = 3.4e38f; int bid = chunk << 5;
  const int j0 = chunk << 5;
  for (int j = j0; j < j0 + 32; ++j) {
    const float* cj = cb + j * 64;  // uniform -> scalar loads
    float m = 0.f;
#pragma unroll
    for (int c = 0; c < 64; ++c) m = fmaf(z[c], cj[c], m);
    float d = fmaf(-2.f, m, cnorm[j]);
    if (d < best) { best = d; bid = j; }  // strict <: first-min within chunk
  }
  pbest[chunk * 8192 + g] = best;
  pbid[chunk * 8192 + g] = bid;
}

// ---------- VQ reduce: argmin across chunks (ascending -> np.argmin) + e_k ----------
__global__ __launch_bounds__(256) void k_vq_reduce(
    const float* __restrict__ pbest, const int* __restrict__ pbid,
    const float* __restrict__ cb, float* __restrict__ ids_f, float* __restrict__ ek)
{
  int g = blockIdx.x * 256 + threadIdx.x;  // 8192
  float best = 3.4e38f; int bid = 0;
#pragma unroll
  for (int ch = 0; ch < 16; ++ch) {
    float d = pbest[ch * 8192 + g];
    int b = pbid[ch * 8192 + g];
    if (d < best) { best = d; bid = b; }
  }
  ids_f[g] = (float)bid;
  int img = g >> 10, p = g & 1023;
  const float* cbid = cb + bid * 64;
  float* ekp = ek + (size_t)img * 64 * 1024 + p;
#pragma unroll
  for (int c = 0; c < 64; ++c) ekp[(size_t)c * 1024] = cbid[c];
}

// ---------- from_z 1x1 (64->256) + relu -> NHWC bf16 ----------
__global__ __launch_bounds__(256) void k_from_z(
    const float* __restrict__ ek, ushort_t* __restrict__ nhwc,
    const float* __restrict__ wT, const float* __restrict__ bias)
{
  const int p = blockIdx.x * 256 + threadIdx.x;  // 0..1023
  const int co0 = blockIdx.y * 16;
  const int n = blockIdx.z;
  const float* inN = ek + (size_t)n * 64 * 1024 + p;
  float acc[16];
#pragma unroll
  for (int i = 0; i < 16; ++i) acc[i] = bias[co0 + i];
#pragma unroll 4
  for (int ci = 0; ci < 64; ++ci) {
    float iv = inN[(size_t)ci * 1024];
    const float* w = wT + (size_t)ci * 256 + co0;  // uniform
#pragma unroll
    for (int i = 0; i < 16; ++i) acc[i] = fmaf(iv, w[i], acc[i]);
  }
  uint pk[8];
#pragma unroll
  for (int i = 0; i < 8; ++i) {
    ushort_t lo = f2bf(fmaxf(acc[2 * i], 0.f));
    ushort_t hi = f2bf(fmaxf(acc[2 * i + 1], 0.f));
    pk[i] = (uint)lo | ((uint)hi << 16);
  }
  ushort_t* op = nhwc + (((size_t)n * 1024 + p) * 256 + co0);
  uint4 v0; v0.x = pk[0]; v0.y = pk[1]; v0.z = pk[2]; v0.w = pk[3];
  uint4 v1; v1.x = pk[4]; v1.y = pk[5]; v1.z = pk[6]; v1.w = pk[7];
  *(uint4*)(op) = v0;
  *(uint4*)(op + 8) = v1;
}

// ---------- t1 convtranspose 4x4 s2 p1, 256->256, bf16 MFMA, relu -> bf16 NHWC
// per-c8 halo staging: 4 taps share a 6x34 halo tile. 2 barriers per c8.
__global__ __launch_bounds__(256) void k_mfma_t1(
    const ushort_t* __restrict__ nhwc, const ushort_t* __restrict__ wb,
    const float* __restrict__ bias, ushort_t* __restrict__ t1o)
{
  __shared__ ushort_t smem[24576];  // A 16384 us (4 taps x 4096) | halo 8192 us
  const int tid = threadIdx.x;
  const int lane = tid & 63;
  const int wv = tid >> 6;
  const int wm = wv & 1, wn = wv >> 1;
  const int l15 = lane & 15, q = lane >> 4;
  const int pxT = blockIdx.x, coT = blockIdx.y, par = blockIdx.z;
  const int ry = par & 1, rx = (par >> 1) & 1;
  const int pxbase = pxT * 128;
  const int img = pxbase >> 10;
  const int U0 = (pxT & 7) * 4;   // base input-grid row of this 128px strip
  f32x4 acc[4][4];
#pragma unroll
  for (int i = 0; i < 4; ++i)
#pragma unroll
    for (int j = 0; j < 4; ++j) acc[i][j] = (f32x4){0.f, 0.f, 0.f, 0.f};

  // halo DMA sources: slot = r*136 + c*4 + kq ; (row U0-1+r, col c-1), 816 slots
  const ushort_t* srcp[4];
#pragma unroll
  for (int i = 0; i < 4; ++i) {
    int slot = i * 256 + tid;
    int rr = slot / 136;
    int c4 = slot - rr * 136;
    int cc = c4 >> 2, kq2 = c4 & 3;
    int iy = U0 - 1 + rr, ix = cc - 1;
    bool valid = (slot < 816) && ((unsigned)iy < 32u) && ((unsigned)ix < 32u);
    const ushort_t* base = valid
        ? (nhwc + (((size_t)(img * 1024 + iy * 32 + ix)) << 8))
        : g_zpad;
    srcp[i] = base + kq2 * 8;
  }
  const int wvb = wv * 1024;
  char* bufb = (char*)smem;

  for (int c8 = 0; c8 < 8; ++c8) {
#pragma unroll
    for (int tap = 0; tap < 4; ++tap) {
      const ushort_t* Ab = wb + ((size_t)((par * 4 + tap) * 8 + c8) << 13)
                           + coT * 4096 + tid * 8;
      gload16(Ab,        bufb + tap * 8192 + wvb);
      gload16(Ab + 2048, bufb + tap * 8192 + 4096 + wvb);
    }
    const int ko = c8 * 32;
#pragma unroll
    for (int i = 0; i < 4; ++i)
      gload16(srcp[i] + ko, bufb + 32768 + i * 4096 + wvb);
    __syncthreads();
    const ushort_t* A = smem;
    const ushort_t* H = smem + 16384;
#pragma unroll
    for (int tap = 0; tap < 4; ++tap) {
      const int a = tap >> 1, b = tap & 1;
      const int dr = ry + 1 - a, dc = rx + 1 - b;
      short8 af[4], bfr[4];
#pragma unroll
      for (int i = 0; i < 4; ++i)
        af[i] = *(const short8*)(A + tap * 4096 + (wm * 64 + i * 16 + l15) * 32 + q * 8);
#pragma unroll
      for (int j = 0; j < 4; ++j) {
        const int row = wn * 64 + j * 16 + l15;
        const int rr = (row >> 5) + dr, cc = (row & 31) + dc;
        bfr[j] = *(const short8*)(H + rr * 1088 + cc * 32 + q * 8);
      }
#pragma unroll
      for (int i = 0; i < 4; ++i)
#pragma unroll
        for (int j = 0; j < 4; ++j)
          acc[i][j] = __builtin_amdgcn_mfma_f32_16x16x32_bf16(af[i], bfr[j], acc[i][j], 0, 0, 0);
    }
    __syncthreads();   // before restage (single-buffered)
  }

#pragma unroll
  for (int i = 0; i < 4; ++i) {
    int co = coT * 128 + wm * 64 + i * 16 + q * 4;
#pragma unroll
    for (int j = 0; j < 4; ++j) {
      int px = pxbase + wn * 64 + j * 16 + l15;
      int u = (px >> 5) & 31, vv = px & 31;
      int oy = 2 * u + ry, ox = 2 * vv + rx;
      ushort_t e0 = f2bf(fmaxf(acc[i][j][0] + bias[co + 0], 0.f));
      ushort_t e1 = f2bf(fmaxf(acc[i][j][1] + bias[co + 1], 0.f));
      ushort_t e2 = f2bf(fmaxf(acc[i][j][2] + bias[co + 2], 0.f));
      ushort_t e3 = f2bf(fmaxf(acc[i][j][3] + bias[co + 3], 0.f));
      uint2 pk; pk.x = (uint)e0 | ((uint)e1 << 16); pk.y = (uint)e2 | ((uint)e3 << 16);
      *(uint2*)(t1o + ((size_t)(img * 4096 + oy * 64 + ox) * 256 + co)) = pk;
    }
  }
}

// ---------- t2 convtranspose 4x4 s2 p1, 256->3, bf16 MFMA, sigmoid ----------
// global_load_lds staging (linear LDS, dbuf, 1 barrier/chunk).
__global__ __launch_bounds__(256) void k_mfma_t2(
    const ushort_t* __restrict__ t1o, const ushort_t* __restrict__ wb,
    const float* __restrict__ bias, float* __restrict__ out)
{
  __shared__ ushort_t smem[2][8704];  // per buf: sA 8192 us | sB 512 us
  const int tid = threadIdx.x, lane = tid & 63, wv = tid >> 6;
  const int l15 = lane & 15, q = lane >> 4;
  const int pxb = blockIdx.x * 256;
  const int par = blockIdx.y;
  const int ry = par & 1, rx = (par >> 1) & 1;
  f32x4 acc[4];
#pragma unroll
  for (int m = 0; m < 4; ++m) acc[m] = (f32x4){0.f, 0.f, 0.f, 0.f};
  const int kg = tid & 3;
  const ushort_t* srcA[4];
  int ptap = -1;
  auto retap = [&](int tap) {
    ptap = tap;
    const int a = tap >> 1, b = tap & 1;
#pragma unroll
    for (int i = 0; i < 4; ++i) {
      int row = (tid >> 2) + 64 * i;
      int px = pxb + row;
      int img = px >> 12, p = px & 4095, u = p >> 6, v = p & 63;
      int iy = u + ry - a, ix = v + rx - b;
      bool valid = ((unsigned)iy < 64u) && ((unsigned)ix < 64u);
      srcA[i] = (valid ? (t1o + (((size_t)(img * 4096 + iy * 64 + ix)) << 8)) : g_zpad)
                + kg * 8;
    }
  };
  const int wvb = wv * 1024;
  auto stage = [&](int c, int bi) {
    const int tap = c >> 3, cg = c & 7;
    if (tap != ptap) retap(tap);
    char* bufb = (char*)smem[bi];
    const int ko = cg * 32;
#pragma unroll
    for (int i = 0; i < 4; ++i)
      gload16(srcA[i] + ko, bufb + i * 4096 + wvb);
    if (tid < 64)
      gload16(wb + ((size_t)(par * 32 + c)) * 512 + tid * 8, bufb + 16384);
  };
  auto compute = [&](const ushort_t* buf) {
    const ushort_t* sA = buf;
    const ushort_t* sB = buf + 8192;
    short8 bf = *(const short8*)(sB + l15 * 32 + q * 8);
#pragma unroll
    for (int m = 0; m < 4; ++m) {
      const int row = wv * 64 + m * 16 + l15;
      short8 af = *(const short8*)(sA + row * 32 + q * 8);
      acc[m] = __builtin_amdgcn_mfma_f32_16x16x32_bf16(af, bf, acc[m], 0, 0, 0);
    }
  };

  stage(0, 0);
  __syncthreads();
  int cur = 0;
  for (int c = 0; c < 32; ++c) {
    if (c + 1 < 32) stage(c + 1, cur ^ 1);
    compute(smem[cur]);
    __syncthreads();
    cur ^= 1;
  }

  const int co = l15;
  if (co < 3) {
    float bco = bias[co];
#pragma unroll
    for (int m = 0; m < 4; ++m) {
#pragma unroll
      for (int r = 0; r < 4; ++r) {
        int px = pxb + wv * 64 + m * 16 + q * 4 + r;
        int img = px >> 12, p = px & 4095, u = p >> 6, v = p & 63;
        size_t addr = ((size_t)(img * 3 + co)) * 16384 + (2 * u + ry) * 128 + (2 * v + rx);
        out[addr] = 1.f / (1.f + expf(-(acc[m][r] + bco)));
      }
    }
  }
}

// ---------------------------------------------------------------------------
extern "C" void kernel_launch(void* const* d_in, const int* in_sizes, int n_in,
                              void* d_out, int out_size, void* d_ws, size_t ws_size,
                              hipStream_t stream) {
  (void)in_sizes; (void)n_in; (void)out_size; (void)ws_size;
  const float* x      = (const float*)d_in[0];
  const float* c1_w   = (const float*)d_in[1];
  const float* c1_b   = (const float*)d_in[2];
  const float* c2_w   = (const float*)d_in[3];
  const float* c2_b   = (const float*)d_in[4];
  const float* r0_w3  = (const float*)d_in[5];
  const float* r0_b3  = (const float*)d_in[6];
  const float* r0_w1  = (const float*)d_in[7];
  const float* r0_b1  = (const float*)d_in[8];
  const float* r1_w3  = (const float*)d_in[9];
  const float* r1_b3  = (const float*)d_in[10];
  const float* r1_w1  = (const float*)d_in[11];
  const float* r1_b1  = (const float*)d_in[12];
  const float* to_z_w = (const float*)d_in[13];
  const float* to_z_b = (const float*)d_in[14];
  const float* cb     = (const float*)d_in[15];
  const float* from_z_w = (const float*)d_in[16];
  const float* from_z_b = (const float*)d_in[17];
  const float* t1_w   = (const float*)d_in[18];
  const float* t1_b   = (const float*)d_in[19];
  const float* t2_w   = (const float*)d_in[20];
  const float* t2_b   = (const float*)d_in[21];

  float* wsf = (float*)d_ws;
  // Era-choreographed regions (float offsets):
  //  conv1 era:  xs1p0 [0,4.19M) | xs1p1 [4.19,8.39M)
  //  conv2 main: reads xs1; partials cp0 [8.39,10.49M) cp1 [10.49,12.58M)
  //  conv2 epi:  h32 := cp0 slot (in-place); splits -> sE [0,2.1M)
  //  3x3f#1:     reads sE -> splits sF [2.1,4.19M)
  //  res1x1#1:   reads sF; h32 RMW; splits -> sE
  //  3x3f#2:     reads sE -> splits sF
  //  res1x1#2:   reads sF; h32 RMW
  //  vq era:     pbest [0,131072) pbid [131072,...)
  //  dec era:    t1out [2.1,6.29M) | decn [6.29,7.34M)
  ushort_t* xs1p0 = (ushort_t*)(wsf + 0);
  ushort_t* xs1p1 = (ushort_t*)(wsf + 4194304);
  float*    cp0   = wsf + 8388608;               // conv2 partial kz0 (= h32 slot)
  float*    h32   = wsf + 8388608;
  ushort_t* sE0   = (ushort_t*)(wsf + 0);        // split ping [0,1.05M)
  ushort_t* sE1   = (ushort_t*)(wsf + 1048576);  // split ping [1.05,2.1M)
  ushort_t* sF0   = (ushort_t*)(wsf + 2097152);  // split pong [2.1,3.15M)
  ushort_t* sF1   = (ushort_t*)(wsf + 3145728);  // split pong [3.15,4.19M)
  float*    pbest = wsf + 0;                     // vq-era
  int*      pbid  = (int*)(wsf + 131072);        // vq-era
  ushort_t* t1out = (ushort_t*)(wsf + 2097152);  // dec-era [2.1M, 6.29M)
  ushort_t* decn  = (ushort_t*)(wsf + 6291456);  // dec-era [6.29M, 7.34M)
  ushort_t* wp_c2   = (ushort_t*)(wsf + 12582912);
  ushort_t* wp_r0w3 = (ushort_t*)(wsf + 13631488);
  ushort_t* wp_r1w3 = (ushort_t*)(wsf + 14221312);
  ushort_t* wp_r0w1 = (ushort_t*)(wsf + 14811136);
  ushort_t* wp_r1w1 = (ushort_t*)(wsf + 14876672);
  float*    wt_c1   = wsf + 14942208;
  float*    wt_toz  = wsf + 14954496;
  float*    wt_fromz= wsf + 14970880;
  ushort_t* t1wb    = (ushort_t*)(wsf + 14987264);
  ushort_t* w2pk    = (ushort_t*)(wsf + 15511552);
  float*    cnorm   = wsf + 15544320;

  float* out_img = (float*)d_out;        // 393216
  float* z_e_out = out_img + 393216;     // 524288
  float* e_k_out = z_e_out + 524288;     // 524288
  float* ids_out = e_k_out + 524288;     // 8192 (stored as float)

  // ---- weight prep (merged: 5 dispatches) ----
  k_prep_misc<<<434, 256, 0, stream>>>(c1_w, wt_c1, to_z_w, wt_toz,
                                       from_z_w, wt_fromz, cb, cnorm, t2_w, w2pk);
  k_prep_enc<0><<<256, 256, 0, stream>>>(c2_w, wp_c2);
  k_prep_enc2<1><<<512, 256, 0, stream>>>(r0_w3, wp_r0w3, r1_w3, wp_r1w3);
  k_prep_enc2<2><<<512, 256, 0, stream>>>(r0_w1, wp_r0w1, r1_w1, wp_r1w1);
  k_prep_t1w<<<4096, 256, 0, stream>>>(t1_w, t1wb);

  // ---- encoder ----
  k_conv1_split<<<dim3(64, 4, 8), 256, 0, stream>>>(x, xs1p0, xs1p1, wt_c1, c1_b);
  // conv2: plain-store partials cp0/cp1, epilogue: sum+relu -> h32 + splits
  k_enc_mfma_split<0><<<dim3(64, 4, 2), 256, 0, stream>>>(xs1p0, xs1p1, wp_c2, cp0);
  k_enc_epi<true><<<dim3(32, 16), 256, 0, stream>>>(cp0, h32, sE0, sE1, c2_b);
  // r0 w3 (kz=1 halo, fused epilogue): sE -> sF
  k_enc_mfma_3x3f<<<dim3(64, 8), 256, 0, stream>>>(sE0, sE1, wp_r0w3, r0_b3, sF0, sF1);
  // r0 w1: h += conv; write h32 + split(relu(h)): sF -> sE
  k_enc_mfma<true ><<<dim3(64, 4), 256, 0, stream>>>(
      sF0, sF1, wp_r0w1, r0_b1, h32, sE0, sE1);
  // r1 w3: sE -> sF
  k_enc_mfma_3x3f<<<dim3(64, 8), 256, 0, stream>>>(sE0, sE1, wp_r1w3, r1_b3, sF0, sF1);
  // r1 w1: h += conv; write h32 only: reads sF
  k_enc_mfma<false><<<dim3(64, 4), 256, 0, stream>>>(
      sF0, sF1, wp_r1w1, r1_b1, h32, nullptr, nullptr);
  // to_z (fp32)
  k_conv1x1<<<dim3(4, 4, 8), 256, 0, stream>>>(h32, z_e_out, wt_toz, to_z_b, 256, 64, 1024);

  // ---- VQ (chunk-parallel; bit-identical argmin) ----
  k_vq_part<<<dim3(32, 16), 256, 0, stream>>>(z_e_out, cb, cnorm, pbest, pbid);
  k_vq_reduce<<<32, 256, 0, stream>>>(pbest, pbid, cb, ids_out, e_k_out);

  // ---- decoder (bf16) ----
  k_from_z<<<dim3(4, 16, 8), 256, 0, stream>>>(e_k_out, decn, wt_fromz, from_z_b);
  k_mfma_t1<<<dim3(64, 2, 4), 256, 0, stream>>>(decn, t1wb, t1_b, t1out);
  k_mfma_t2<<<dim3(128, 4), 256, 0, stream>>>(t1out, w2pk, t2_b, out_img);
}

// Round 11
// 370.524 us; speedup vs baseline: 1.3543x; 1.0584x over previous
//
#include <hip/hip_runtime.h>
#include <math.h>

// ---------------------------------------------------------------------------
// VQ-VAE forward.
// Encoder: 256-ch convs as implicit-GEMM MFMA with 2-term bf16 split inputs.
// conv2 split-K=2 plain-store partials + epi. 3x3 convs: kz=1 halo kernel,
// fused epilogue. VQ: chunk-parallel argmin. Decoder: t1 halo + t2 DMA.
// R11: res1x1 -> 32-co tile (grid 512 = 2 blocks/CU, was 1) with 3x3f-style
//      fused split epilogue; to_z grid 128->256; preps merged 5->2 launches.
// ---------------------------------------------------------------------------

typedef unsigned int uint;
typedef unsigned short ushort_t;
using short8 = __attribute__((ext_vector_type(8))) short;
using f32x4  = __attribute__((ext_vector_type(4))) float;

// zero-initialized pad: invalid halo rows DMA from here (always zero)
__device__ __attribute__((aligned(16))) ushort_t g_zpad[512];

static __device__ __forceinline__ int rfl(int x) { return __builtin_amdgcn_readfirstlane(x); }
static __device__ __forceinline__ ushort_t f2bf(float f) {
  uint u = __float_as_uint(f);
  return (ushort_t)((u + 0x7fffu + ((u >> 16) & 1u)) >> 16);  // RNE; finite inputs
}
static __device__ __forceinline__ float bf2f(ushort_t b) {
  return __uint_as_float(((uint)b) << 16);
}
// direct global->LDS DMA, 16B per lane; lds dest = wave-uniform base + lane*16
static __device__ __forceinline__ void gload16(const ushort_t* g, void* l) {
  __builtin_amdgcn_global_load_lds(
      (const __attribute__((address_space(1))) void*)g,
      (__attribute__((address_space(3))) void*)l, 16, 0, 0);
}

// ---------- weight prep ----------
// encoder MFMA weight pack body: w[co][ci(256)][KH][KW] fp32 ->
// wp[chunk][coT(4)][pl(2)][row(64)][k(32)] bf16 split, chunk = tap*8 + cg
template<int KIND>  // 0: 4x4 (16 taps), 1: 3x3 (9 taps), 2: 1x1 (1 tap)
static __device__ __forceinline__ void d_prep_enc_body(
    int bx, int tid, const float* __restrict__ w, ushort_t* __restrict__ wp)
{
  constexpr int KK = (KIND == 0) ? 16 : (KIND == 1 ? 9 : 1);
  constexpr int KW = (KIND == 0) ? 4  : (KIND == 1 ? 3 : 1);
  constexpr int NT = KK;
  const int wvg = bx * 4 + (tid >> 6);   // 0..1023
  const int lane = tid & 63;
  const int co = wvg >> 2;
  const int ci = (wvg & 3) * 64 + lane;
  const float* src = w + (size_t)(co * 256 + ci) * KK;
  const int coT = co >> 6, row = co & 63, cg = ci >> 5, k = ci & 31;
  float v[KK];
#pragma unroll
  for (int j = 0; j < KK; ++j) v[j] = src[j];
#pragma unroll
  for (int tap = 0; tap < NT; ++tap) {
    int ky, kx;
    if (KIND == 0)      { ky = tap >> 2; kx = tap & 3; }
    else if (KIND == 1) { ky = tap / 3;  kx = tap - ky * 3; }
    else                { ky = 0; kx = 0; }
    float val = v[ky * KW + kx];
    ushort_t b0 = f2bf(val);
    ushort_t b1 = f2bf(val - bf2f(b0));
    const int chunk = tap * 8 + cg;
    size_t base = ((size_t)(chunk * 4 + coT) << 12) + row * 32 + k;
    wp[base] = b0;          // pl=0
    wp[base + 2048] = b1;   // pl=1
  }
}

// mega prep: misc (434) | enc0 c2 (256) | enc1 r0w3/r1w3 (512) | enc2 r0w1/r1w1 (512)
__global__ __launch_bounds__(256) void k_prep_all(
    const float* __restrict__ c1w, float* __restrict__ wt_c1,
    const float* __restrict__ tozw, float* __restrict__ wt_toz,
    const float* __restrict__ fromzw, float* __restrict__ wt_fromz,
    const float* __restrict__ cb, float* __restrict__ cnorm,
    const float* __restrict__ t2w, ushort_t* __restrict__ w2pk,
    const float* __restrict__ c2w, ushort_t* __restrict__ wp_c2,
    const float* __restrict__ r0w3, ushort_t* __restrict__ wp_r0w3,
    const float* __restrict__ r1w3, ushort_t* __restrict__ wp_r1w3,
    const float* __restrict__ r0w1, ushort_t* __restrict__ wp_r0w1,
    const float* __restrict__ r1w1, ushort_t* __restrict__ wp_r1w1)
{
  const int b = blockIdx.x, tid = threadIdx.x;
  if (b < 434) {
    if (b < 48) {            // c1 transpose: CO=256, CIKK=48 (12288 elems)
      int idx = b * 256 + tid;
      int co = idx % 256, i = idx / 256;
      wt_c1[idx] = c1w[co * 48 + i];
    } else if (b < 112) {    // to_z transpose: CO=64, CIKK=256 (16384)
      int idx = (b - 48) * 256 + tid;
      int co = idx % 64, i = idx / 64;
      wt_toz[idx] = tozw[co * 256 + i];
    } else if (b < 176) {    // from_z transpose: CO=256, CIKK=64 (16384)
      int idx = (b - 112) * 256 + tid;
      int co = idx % 256, i = idx / 256;
      wt_fromz[idx] = fromzw[co * 64 + i];
    } else if (b < 178) {    // cnorm[j] = sum_c cb[j][c]^2
      int idx = (b - 176) * 256 + tid;
      if (idx < 512) {
        float s = 0.f;
        for (int c = 0; c < 64; ++c) { float v = cb[idx * 64 + c]; s = fmaf(v, v, s); }
        cnorm[idx] = s;
      }
    } else {                 // t2_w pack: 65536 elems (256 blocks)
      int idx = (b - 178) * 256 + tid;
      int k = idx & 31, co = (idx >> 5) & 15, chunk = (idx >> 9) & 31, par = idx >> 14;
      int tap = chunk >> 3, cg = chunk & 7;
      int a = tap >> 1, bb = tap & 1;
      int ry = par & 1, rx = (par >> 1) & 1;
      int ky = ((ry + 1) & 1) + 2 * a;
      int kx = ((rx + 1) & 1) + 2 * bb;
      int ci = cg * 32 + k;
      float v = (co < 3) ? t2w[((ci * 3 + co) << 4) + ky * 4 + kx] : 0.f;
      w2pk[idx] = f2bf(v);
    }
  } else if (b < 690) {
    d_prep_enc_body<0>(b - 434, tid, c2w, wp_c2);
  } else if (b < 1202) {
    int bx = b - 690;
    if (bx < 256) d_prep_enc_body<1>(bx, tid, r0w3, wp_r0w3);
    else          d_prep_enc_body<1>(bx - 256, tid, r1w3, wp_r1w3);
  } else {
    int bx = b - 1202;
    if (bx < 256) d_prep_enc_body<2>(bx, tid, r0w1, wp_r0w1);
    else          d_prep_enc_body<2>(bx - 256, tid, r1w1, wp_r1w1);
  }
}

// t1_w [ci][co][ky][kx] -> bf16 [par][tap][c8][co][kk32]
__global__ void k_prep_t1w(const float* __restrict__ w, ushort_t* __restrict__ wb) {
  int idx = blockIdx.x * 256 + threadIdx.x;  // 1048576
  int kk  = idx & 31;
  int co  = (idx >> 5) & 255;
  int c8  = (idx >> 13) & 7;
  int tap = (idx >> 16) & 3;
  int par = idx >> 18;
  int ry = par & 1, rx = (par >> 1) & 1;
  int a = tap >> 1, b = tap & 1;
  int ky = ((ry + 1) & 1) + 2 * a;
  int kx = ((rx + 1) & 1) + 2 * b;
  int ci = c8 * 32 + kk;
  wb[idx] = f2bf(w[((ci * 256 + co) << 4) + ky * 4 + kx]);
}

// ---------- conv1: 3->256, 4x4 s2 p1, relu, output split-bf16 NHWC ----------
__global__ __launch_bounds__(256) void k_conv1_split(
    const float* __restrict__ in, ushort_t* __restrict__ o0, ushort_t* __restrict__ o1,
    const float* __restrict__ wT, const float* __restrict__ bias)
{
  __shared__ float s_in[3 * 360];  // parity-split cols, pitch 20 (2-way free)
  const int tid = threadIdx.x;
  const int lane = tid & 63;
  const int wv = rfl(tid >> 6);
  const int px = lane & 7, py = lane >> 3;
  const int tx = blockIdx.x & 7, ty = blockIdx.x >> 3;
  const int X = tx * 8, Y = ty * 8;
  const int cob = blockIdx.y * 64 + wv * 16;
  const int n = blockIdx.z;
  float acc[16];
#pragma unroll
  for (int i = 0; i < 16; ++i) acc[i] = bias[cob + i];
  const float* inN = in + (size_t)n * 3 * 16384;
  for (int e = tid; e < 3 * 360; e += 256) {
    int col2 = e % 20; int t = e / 20; int row = t % 18; int ci = t / 18;
    int pr = col2 / 10, hc = col2 % 10, ixl = 2 * hc + pr;
    int iy = 2 * Y - 1 + row, ix = 2 * X - 1 + ixl;
    float v = 0.f;
    if (ixl < 18 && (unsigned)iy < 128u && (unsigned)ix < 128u)
      v = inN[ci * 16384 + iy * 128 + ix];
    s_in[e] = v;
  }
  __syncthreads();
  const float* wc = wT + cob;
#pragma unroll
  for (int c = 0; c < 3; ++c) {
    const float* base = s_in + c * 360 + py * 40 + px;
#pragma unroll
    for (int ky = 0; ky < 4; ++ky) {
#pragma unroll
      for (int kx = 0; kx < 4; ++kx) {
        float iv = base[ky * 20 + (kx & 1) * 10 + (kx >> 1)];
        const float* w = wc + (size_t)(c * 16 + ky * 4 + kx) * 256;  // uniform
#pragma unroll
        for (int i = 0; i < 16; ++i) acc[i] = fmaf(iv, w[i], acc[i]);
      }
    }
  }
  const int pxg = n * 4096 + (Y + py) * 64 + (X + px);
  uint p0[8], p1[8];
#pragma unroll
  for (int i = 0; i < 8; ++i) {
    float va = fmaxf(acc[2 * i], 0.f), vb = fmaxf(acc[2 * i + 1], 0.f);
    ushort_t a0 = f2bf(va), b0 = f2bf(vb);
    ushort_t a1 = f2bf(va - bf2f(a0)), b1 = f2bf(vb - bf2f(b0));
    p0[i] = (uint)a0 | ((uint)b0 << 16);
    p1[i] = (uint)a1 | ((uint)b1 << 16);
  }
  ushort_t* d0 = o0 + (size_t)pxg * 256 + cob;
  ushort_t* d1 = o1 + (size_t)pxg * 256 + cob;
  uint4 v0a; v0a.x = p0[0]; v0a.y = p0[1]; v0a.z = p0[2]; v0a.w = p0[3];
  uint4 v0b; v0b.x = p0[4]; v0b.y = p0[5]; v0b.z = p0[6]; v0b.w = p0[7];
  uint4 v1a; v1a.x = p1[0]; v1a.y = p1[1]; v1a.z = p1[2]; v1a.w = p1[3];
  uint4 v1b; v1b.x = p1[4]; v1b.y = p1[5]; v1b.z = p1[6]; v1b.w = p1[7];
  *(uint4*)d0 = v0a; *(uint4*)(d0 + 8) = v0b;
  *(uint4*)d1 = v1a; *(uint4*)(d1 + 8) = v1b;
}

// ---------- conv2 implicit-GEMM MFMA, split-K=2, plain-store partial --------
// Block: 64co x 128px, 4 waves. grid (pxT 64, coT 4, kz 2).
// global_load_lds staging, linear LDS.
template<int KIND>  // 0: conv2 (128 chunks)
__global__ __launch_bounds__(256) void k_enc_mfma_split(
    const ushort_t* __restrict__ x0, const ushort_t* __restrict__ x1,
    const ushort_t* __restrict__ wp, float* __restrict__ part)
{
  __shared__ ushort_t smem[2][12288];   // per buf: sA 4096 us (8KB) | sB 8192 us (16KB)
  const int tid = threadIdx.x, lane = tid & 63, wv = tid >> 6;
  const int l15 = lane & 15, q = lane >> 4;
  const int pxT = blockIdx.x, coT = blockIdx.y;
  constexpr int NCH = (KIND == 0) ? 128 : 72;
  const int CH0 = blockIdx.z * (NCH / 2), CH1 = CH0 + NCH / 2;
  f32x4 acc[4][2];
#pragma unroll
  for (int m = 0; m < 4; ++m)
#pragma unroll
    for (int n = 0; n < 2; ++n) acc[m][n] = (f32x4){0.f, 0.f, 0.f, 0.f};

  // B staging: thread handles rows r0 and r0+64, 16B quarter kq
  const int r0 = tid >> 2, kq = tid & 3;
  int bimg[2], bu[2], bvc[2];
#pragma unroll
  for (int r = 0; r < 2; ++r) {
    int bpx = pxT * 128 + r0 + r * 64;
    bimg[r] = bpx >> 10; int bp = bpx & 1023; bu[r] = bp >> 5; bvc[r] = bp & 31;
  }
  const ushort_t* srcB[2][2];  // [row r][plane p], excludes cg offset
  int ptap = -1;
  auto retap = [&](int tap) {
    ptap = tap;
    int ky, kx;
    if (KIND == 0) { ky = tap >> 2; kx = tap & 3; }
    else           { ky = tap / 3;  kx = tap - ky * 3; }
#pragma unroll
    for (int r = 0; r < 2; ++r) {
      bool v; size_t rowb;
      if (KIND == 0) {
        int iy = 2 * bu[r] - 1 + ky, ix = 2 * bvc[r] - 1 + kx;
        v = ((unsigned)iy < 64u) && ((unsigned)ix < 64u);
        rowb = ((size_t)(bimg[r] * 4096 + iy * 64 + ix)) << 8;
      } else {
        int iy = bu[r] - 1 + ky, ix = bvc[r] - 1 + kx;
        v = ((unsigned)iy < 32u) && ((unsigned)ix < 32u);
        rowb = ((size_t)(bimg[r] * 1024 + iy * 32 + ix)) << 8;
      }
      srcB[r][0] = (v ? (x0 + rowb) : g_zpad) + kq * 8;
      srcB[r][1] = (v ? (x1 + rowb) : g_zpad) + kq * 8;
    }
  };

  const int wvb = wv * 1024;  // wave-uniform byte base (lane*16 auto)
  auto stage = [&](int chunk, int bi) {
    const int tap = chunk >> 3, cg = chunk & 7;
    if (tap != ptap) retap(tap);
    char* bufb = (char*)smem[bi];
    const ushort_t* ap = wp + ((size_t)(chunk * 4 + coT) << 12) + tid * 8;
    gload16(ap,        bufb + wvb);                        // sA pl0
    gload16(ap + 2048, bufb + 4096 + wvb);                 // sA pl1
    const int ko = cg * 32;
    gload16(srcB[0][0] + ko, bufb + 8192 + wvb);           // sB pl0 rows 0-63
    gload16(srcB[1][0] + ko, bufb + 8192 + 4096 + wvb);    // sB pl0 rows 64-127
    gload16(srcB[0][1] + ko, bufb + 16384 + wvb);          // sB pl1 rows 0-63
    gload16(srcB[1][1] + ko, bufb + 16384 + 4096 + wvb);   // sB pl1 rows 64-127
  };
  auto compute = [&](const ushort_t* buf) {
    const ushort_t* sA = buf;
    const ushort_t* sB = buf + 4096;
    short8 af[4][2], bf[2][2];
#pragma unroll
    for (int m = 0; m < 4; ++m)
#pragma unroll
      for (int pl = 0; pl < 2; ++pl)
        af[m][pl] = *(const short8*)(sA + pl * 2048 + (m * 16 + l15) * 32 + q * 8);
#pragma unroll
    for (int n = 0; n < 2; ++n)
#pragma unroll
      for (int pl = 0; pl < 2; ++pl)
        bf[n][pl] = *(const short8*)(sB + pl * 4096 + (wv * 32 + n * 16 + l15) * 32 + q * 8);
#pragma unroll
    for (int m = 0; m < 4; ++m)
#pragma unroll
      for (int n = 0; n < 2; ++n) {
        acc[m][n] = __builtin_amdgcn_mfma_f32_16x16x32_bf16(af[m][0], bf[n][0], acc[m][n], 0, 0, 0);
        acc[m][n] = __builtin_amdgcn_mfma_f32_16x16x32_bf16(af[m][0], bf[n][1], acc[m][n], 0, 0, 0);
        acc[m][n] = __builtin_amdgcn_mfma_f32_16x16x32_bf16(af[m][1], bf[n][0], acc[m][n], 0, 0, 0);
      }
  };

  stage(CH0, 0);
  __syncthreads();
  int cur = 0;
  for (int c = CH0; c < CH1; ++c) {
    if (c + 1 < CH1) stage(c + 1, cur ^ 1);   // DMA in flight under compute
    compute(smem[cur]);
    __syncthreads();                           // drains DMA; 1 barrier/chunk
    cur ^= 1;
  }

  // plain stores to this kz's private partial slice (deterministic)
  float* pz = part + ((size_t)blockIdx.z << 21);
#pragma unroll
  for (int m = 0; m < 4; ++m) {
#pragma unroll
    for (int n = 0; n < 2; ++n) {
#pragma unroll
      for (int r = 0; r < 4; ++r) {
        const int co_l = m * 16 + q * 4 + r;
        const int px_l = wv * 32 + n * 16 + l15;
        const int px = pxT * 128 + px_l;
        const int img = px >> 10, pp = px & 1023;
        const size_t ha = ((size_t)(img * 256 + coT * 64 + co_l)) * 1024 + pp;
        pz[ha] = acc[m][n][r];
      }
    }
  }
}

// ---------- 3x3 implicit-GEMM MFMA, kz=1, FUSED epilogue --------------------
// Block 32co x 128px. Per cg (0..7): stage all 9 taps' A + 6x34 halo,
// 1 barrier, 108 MFMA, 1 barrier. Then relu+split epilogue via LDS
// transpose. grid (pxT 64, coT 8).
__global__ __launch_bounds__(256) void k_enc_mfma_3x3f(
    const ushort_t* __restrict__ x0, const ushort_t* __restrict__ x1,
    const ushort_t* __restrict__ wp, const float* __restrict__ bias,
    ushort_t* __restrict__ s0, ushort_t* __restrict__ s1)
{
  __shared__ ushort_t smem[32768];  // A 18432 us | halo 14336 us; epi reuses [0,8192)
  const int tid = threadIdx.x, lane = tid & 63, wv = tid >> 6;
  const int l15 = lane & 15, q = lane >> 4;
  const int pxT = blockIdx.x, coT = blockIdx.y;
  const int img = pxT >> 3;          // 8 blocks per 32x32 image
  const int U0 = (pxT & 7) * 4;      // base output row of this 128px strip
  f32x4 acc[2][2];
#pragma unroll
  for (int m = 0; m < 2; ++m)
#pragma unroll
    for (int n = 0; n < 2; ++n) acc[m][n] = (f32x4){0.f, 0.f, 0.f, 0.f};

  // halo DMA sources: slot = pl*816 + r*136 + c*4 + kq ; (pl, row U0-1+r, col c-1)
  const ushort_t* srcp[7];
#pragma unroll
  for (int i = 0; i < 7; ++i) {
    int slot = i * 256 + tid;
    int pl = slot >= 816 ? 1 : 0;
    int rem = slot - pl * 816;
    int rr = rem / 136;
    int c4 = rem - rr * 136;
    int cc = c4 >> 2, kq2 = c4 & 3;
    int iy = U0 - 1 + rr, ix = cc - 1;
    bool valid = (slot < 1632) && ((unsigned)iy < 32u) && ((unsigned)ix < 32u);
    const ushort_t* base = valid
        ? ((pl ? x1 : x0) + (((size_t)(img * 1024 + iy * 32 + ix)) << 8))
        : g_zpad;
    srcp[i] = base + kq2 * 8;
  }
  // A DMA source: per tap one 4KB DMA; threads 0..127 pl0, 128..255 pl1
  const int apl = tid >> 7;
  const int aus = apl * 2048 + (coT & 1) * 1024 + (tid & 127) * 8;
  const int coTq = coT >> 1;
  const int wvb = wv * 1024;
  char* bufb = (char*)smem;

  for (int cg = 0; cg < 8; ++cg) {
#pragma unroll
    for (int tap = 0; tap < 9; ++tap) {
      const int chunk = tap * 8 + cg;
      gload16(wp + ((size_t)(chunk * 4 + coTq) << 12) + aus, bufb + tap * 4096 + wvb);
    }
    const int ko = cg * 32;
#pragma unroll
    for (int i = 0; i < 7; ++i)
      gload16(srcp[i] + ko, bufb + 36864 + i * 4096 + wvb);
    __syncthreads();
    const ushort_t* Ab = smem;
    const ushort_t* Hb = smem + 18432;
#pragma unroll 3
    for (int tap = 0; tap < 9; ++tap) {
      const int ky = tap / 3, kx = tap - ky * 3;
      short8 af[2][2], bf[2][2];
#pragma unroll
      for (int m = 0; m < 2; ++m)
#pragma unroll
        for (int pl = 0; pl < 2; ++pl)
          af[m][pl] = *(const short8*)(Ab + tap * 2048 + pl * 1024 + (m * 16 + l15) * 32 + q * 8);
      const int r = wv + ky;
#pragma unroll
      for (int n = 0; n < 2; ++n)
#pragma unroll
        for (int pl = 0; pl < 2; ++pl)
          bf[n][pl] = *(const short8*)(Hb + pl * 6528 + r * 1088 + (n * 16 + l15 + kx) * 32 + q * 8);
#pragma unroll
      for (int m = 0; m < 2; ++m)
#pragma unroll
        for (int n = 0; n < 2; ++n) {
          acc[m][n] = __builtin_amdgcn_mfma_f32_16x16x32_bf16(af[m][0], bf[n][0], acc[m][n], 0, 0, 0);
          acc[m][n] = __builtin_amdgcn_mfma_f32_16x16x32_bf16(af[m][0], bf[n][1], acc[m][n], 0, 0, 0);
          acc[m][n] = __builtin_amdgcn_mfma_f32_16x16x32_bf16(af[m][1], bf[n][0], acc[m][n], 0, 0, 0);
        }
    }
    __syncthreads();   // before restage; final one protects epilogue smem reuse
  }

  // fused epilogue: splits of relu(acc + bias) via LDS transpose
  // smem layout: [pl(2)][px_l(128)][co_l(32)] ushort = 8192 us
  const int cob = coT * 32;
#pragma unroll
  for (int m = 0; m < 2; ++m) {
#pragma unroll
    for (int n = 0; n < 2; ++n) {
#pragma unroll
      for (int r = 0; r < 4; ++r) {
        const int co_l = m * 16 + q * 4 + r;
        const int px_l = wv * 32 + n * 16 + l15;
        float sv = fmaxf(acc[m][n][r] + bias[cob + co_l], 0.f);
        ushort_t b0 = f2bf(sv);
        smem[px_l * 32 + co_l] = b0;
        smem[4096 + px_l * 32 + co_l] = f2bf(sv - bf2f(b0));
      }
    }
  }
  __syncthreads();
#pragma unroll
  for (int i = 0; i < 4; ++i) {
    int idx = tid + 256 * i;          // 0..1023 uint4 units
    int pl = idx >> 9;
    int rem = idx & 511;
    int px_l = rem >> 2, g = rem & 3;
    uint4 vv = *(const uint4*)(smem + pl * 4096 + px_l * 32 + g * 8);
    ushort_t* dst = (pl ? s1 : s0) + ((size_t)(pxT * 128 + px_l)) * 256 + cob + g * 8;
    *(uint4*)dst = vv;
  }
}

// ---------- epilogue for conv2 split ----------
// v = p0 + p1 + bias; relu; h32 = v; splits.
template<bool WH>
__global__ __launch_bounds__(256) void k_enc_epi(
    const float* __restrict__ part, float* __restrict__ h32,
    ushort_t* __restrict__ s0, ushort_t* __restrict__ s1,
    const float* __restrict__ bias)
{
  const int px = blockIdx.x * 256 + threadIdx.x;  // 8192
  const int co0 = blockIdx.y * 16;
  const int img = px >> 10, pp = px & 1023;
  const float* part1 = part + (1u << 21);
  uint p0[8], p1[8];
#pragma unroll
  for (int i = 0; i < 8; ++i) {
    size_t ha = ((size_t)(img * 256 + co0 + 2 * i)) * 1024 + pp;
    size_t hb = ha + 1024;
    float va = part[ha] + part1[ha] + bias[co0 + 2 * i];
    float vb = part[hb] + part1[hb] + bias[co0 + 2 * i + 1];
    float sa, sb;
    if (WH) {
      va = fmaxf(va, 0.f); vb = fmaxf(vb, 0.f);
      h32[ha] = va; h32[hb] = vb; sa = va; sb = vb;
    } else { sa = fmaxf(va, 0.f); sb = fmaxf(vb, 0.f); }
    ushort_t a0 = f2bf(sa), b0 = f2bf(sb);
    p0[i] = (uint)a0 | ((uint)b0 << 16);
    p1[i] = (uint)f2bf(sa - bf2f(a0)) | ((uint)f2bf(sb - bf2f(b0)) << 16);
  }
  ushort_t* d0 = s0 + (size_t)px * 256 + co0;
  ushort_t* d1 = s1 + (size_t)px * 256 + co0;
  uint4 v0a; v0a.x = p0[0]; v0a.y = p0[1]; v0a.z = p0[2]; v0a.w = p0[3];
  uint4 v0b; v0b.x = p0[4]; v0b.y = p0[5]; v0b.z = p0[6]; v0b.w = p0[7];
  uint4 v1a; v1a.x = p1[0]; v1a.y = p1[1]; v1a.z = p1[2]; v1a.w = p1[3];
  uint4 v1b; v1b.x = p1[4]; v1b.y = p1[5]; v1b.z = p1[6]; v1b.w = p1[7];
  *(uint4*)d0 = v0a; *(uint4*)(d0 + 8) = v0b;
  *(uint4*)d1 = v1a; *(uint4*)(d1 + 8) = v1b;
}

// ---------- residual 1x1 MFMA, 32-co tile (R11), fused epilogue ----------
// h += conv1x1(x) + bias; write h32; if WS also split(relu(h)) via LDS
// transpose. Block 32co x 128px, 4 waves, acc 2x2; grid (pxT 64, coT 8)
// = 512 blocks = 2/CU. LDS per buf: A 4KB + B 16KB = 20KB; dbuf 40KB.
template<bool WS>
__global__ __launch_bounds__(256) void k_enc_mfma(
    const ushort_t* __restrict__ x0, const ushort_t* __restrict__ x1,
    const ushort_t* __restrict__ wp, const float* __restrict__ bias,
    float* __restrict__ h32, ushort_t* __restrict__ sp0, ushort_t* __restrict__ sp1)
{
  __shared__ ushort_t smem[20480];   // dbuf 2x10240 us; WS epilogue reuses [0,8192)
  const int tid = threadIdx.x, lane = tid & 63, wv = tid >> 6;
  const int l15 = lane & 15, q = lane >> 4;
  const int pxT = blockIdx.x, coT = blockIdx.y;
  const int coT4 = coT >> 1, half = coT & 1;
  f32x4 acc[2][2];
#pragma unroll
  for (int m = 0; m < 2; ++m)
#pragma unroll
    for (int n = 0; n < 2; ++n) acc[m][n] = (f32x4){0.f, 0.f, 0.f, 0.f};

  const int r0 = tid >> 2, kq = tid & 3;
  const ushort_t* srcB[2][2];
#pragma unroll
  for (int r = 0; r < 2; ++r) {
    size_t rowb = ((size_t)(pxT * 128 + r0 + r * 64)) << 8;
    srcB[r][0] = x0 + rowb + kq * 8;
    srcB[r][1] = x1 + rowb + kq * 8;
  }
  // A source: wave w loads 1KB: pl = w>>1, sub = w&1 (rows sub*16..+16 of 32)
  const int apl = wv >> 1, asub = wv & 1;
  const int aoff = apl * 2048 + half * 1024 + asub * 512 + lane * 8;  // us
  const int wvb = wv * 1024;  // bytes
  auto stage = [&](int c, int bi) {
    char* bufb = (char*)(smem + bi * 10240);
    const ushort_t* ap = wp + ((size_t)(c * 4 + coT4) << 12) + aoff;
    gload16(ap, bufb + wvb);                              // A: wave slice
    const int ko = c * 32;
    gload16(srcB[0][0] + ko, bufb + 4096 + wvb);          // B pl0 rows 0-63
    gload16(srcB[1][0] + ko, bufb + 8192 + wvb);          // B pl0 rows 64-127
    gload16(srcB[0][1] + ko, bufb + 12288 + wvb);         // B pl1 rows 0-63
    gload16(srcB[1][1] + ko, bufb + 16384 + wvb);         // B pl1 rows 64-127
  };
  auto compute = [&](const ushort_t* buf) {
    const ushort_t* sA = buf;           // [pl][row32][k32] us
    const ushort_t* sB = buf + 2048;    // [pl][row128][k32] us
    short8 af[2][2], bf[2][2];
#pragma unroll
    for (int m = 0; m < 2; ++m)
#pragma unroll
      for (int pl = 0; pl < 2; ++pl)
        af[m][pl] = *(const short8*)(sA + pl * 1024 + (m * 16 + l15) * 32 + q * 8);
#pragma unroll
    for (int n = 0; n < 2; ++n)
#pragma unroll
      for (int pl = 0; pl < 2; ++pl)
        bf[n][pl] = *(const short8*)(sB + pl * 4096 + (wv * 32 + n * 16 + l15) * 32 + q * 8);
#pragma unroll
    for (int m = 0; m < 2; ++m)
#pragma unroll
      for (int n = 0; n < 2; ++n) {
        acc[m][n] = __builtin_amdgcn_mfma_f32_16x16x32_bf16(af[m][0], bf[n][0], acc[m][n], 0, 0, 0);
        acc[m][n] = __builtin_amdgcn_mfma_f32_16x16x32_bf16(af[m][0], bf[n][1], acc[m][n], 0, 0, 0);
        acc[m][n] = __builtin_amdgcn_mfma_f32_16x16x32_bf16(af[m][1], bf[n][0], acc[m][n], 0, 0, 0);
      }
  };

  stage(0, 0);
  __syncthreads();
  int cur = 0;
  for (int c = 0; c < 8; ++c) {
    if (c + 1 < 8) stage(c + 1, cur ^ 1);
    compute(smem + cur * 10240);
    __syncthreads();
    cur ^= 1;
  }

  // epilogue: h32 RMW (+ optional splits via LDS transpose, 3x3f pattern)
  const int cob = coT * 32;
#pragma unroll
  for (int m = 0; m < 2; ++m) {
#pragma unroll
    for (int n = 0; n < 2; ++n) {
#pragma unroll
      for (int r = 0; r < 4; ++r) {
        const int co_l = m * 16 + q * 4 + r;
        const int px_l = wv * 32 + n * 16 + l15;
        float v = acc[m][n][r] + bias[cob + co_l];
        const int px = pxT * 128 + px_l;
        const int img = px >> 10, pp = px & 1023;
        const size_t ha = ((size_t)(img * 256 + cob + co_l)) * 1024 + pp;
        v += h32[ha];
        h32[ha] = v;
        if (WS) {
          float sv = fmaxf(v, 0.f);
          ushort_t b0 = f2bf(sv);
          smem[px_l * 32 + co_l] = b0;
          smem[4096 + px_l * 32 + co_l] = f2bf(sv - bf2f(b0));
        }
      }
    }
  }
  if (WS) {
    __syncthreads();
#pragma unroll
    for (int i = 0; i < 4; ++i) {
      int idx = tid + 256 * i;          // 0..1023 uint4 units
      int pl = idx >> 9;
      int rem = idx & 511;
      int px_l = rem >> 2, g = rem & 3;
      uint4 vv = *(const uint4*)(smem + pl * 4096 + px_l * 32 + g * 8);
      ushort_t* dst = (pl ? sp1 : sp0) + ((size_t)(pxT * 128 + px_l)) * 256 + cob + g * 8;
      *(uint4*)dst = vv;
    }
  }
}

// ---------- 1x1 conv fp32 (to_z only) ----------
// R11: cob granularity 8 -> grid (4, 8, 8) = 256 blocks.
__global__ __launch_bounds__(256) void k_conv1x1(
    const float* __restrict__ in, float* __restrict__ out,
    const float* __restrict__ wT, const float* __restrict__ bias,
    int CI, int CO, int P)
{
  const int p = blockIdx.x * 256 + threadIdx.x;
  const int cob = blockIdx.y * 8;
  const int n = blockIdx.z;
  const float* inN = in + (size_t)n * CI * P + p;
  float acc[8];
#pragma unroll
  for (int i = 0; i < 8; ++i) acc[i] = bias[cob + i];
  const float* wr = wT + cob;
#pragma unroll 4
  for (int ci = 0; ci < CI; ++ci) {
    float iv = inN[(size_t)ci * P];
    const float* w = wr + (size_t)ci * CO;  // uniform
#pragma unroll
    for (int i = 0; i < 8; ++i) acc[i] = fmaf(iv, w[i], acc[i]);
  }
  float* outN = out + (size_t)n * CO * P + p;
#pragma unroll
  for (int i = 0; i < 8; ++i) outN[(size_t)(cob + i) * P] = acc[i];
}

// ---------- VQ partial: 16 chunks of 32 codes; per-j math identical ----------
__global__ __launch_bounds__(256) void k_vq_part(
    const float* __restrict__ z_e, const float* __restrict__ cb,
    const float* __restrict__ cnorm, float* __restrict__ pbest, int* __restrict__ pbid)
{
  int g = blockIdx.x * 256 + threadIdx.x;  // 8192 points
  int chunk = blockIdx.y;                  // 16 chunks
  int img = g >> 10, p = g & 1023;
  const float* zp = z_e + (size_t)img * 64 * 1024 + p;
  float z[64];
#pragma unroll
  for (int c = 0; c < 64; ++c) z[c] = zp[(size_t)c * 1024];
  float best = 3.4e38f; int bid = chunk << 5;
  const int j0 = chunk << 5;
  for (int j = j0; j < j0 + 32; ++j) {
    const float* cj = cb + j * 64;  // uniform -> scalar loads
    float m = 0.f;
#pragma unroll
    for (int c = 0; c < 64; ++c) m = fmaf(z[c], cj[c], m);
    float d = fmaf(-2.f, m, cnorm[j]);
    if (d < best) { best = d; bid = j; }  // strict <: first-min within chunk
  }
  pbest[chunk * 8192 + g] = best;
  pbid[chunk * 8192 + g] = bid;
}

// ---------- VQ reduce: argmin across chunks (ascending -> np.argmin) + e_k ----------
__global__ __launch_bounds__(256) void k_vq_reduce(
    const float* __restrict__ pbest, const int* __restrict__ pbid,
    const float* __restrict__ cb, float* __restrict__ ids_f, float* __restrict__ ek)
{
  int g = blockIdx.x * 256 + threadIdx.x;  // 8192
  float best = 3.4e38f; int bid = 0;
#pragma unroll
  for (int ch = 0; ch < 16; ++ch) {
    float d = pbest[ch * 8192 + g];
    int b = pbid[ch * 8192 + g];
    if (d < best) { best = d; bid = b; }
  }
  ids_f[g] = (float)bid;
  int img = g >> 10, p = g & 1023;
  const float* cbid = cb + bid * 64;
  float* ekp = ek + (size_t)img * 64 * 1024 + p;
#pragma unroll
  for (int c = 0; c < 64; ++c) ekp[(size_t)c * 1024] = cbid[c];
}

// ---------- from_z 1x1 (64->256) + relu -> NHWC bf16 ----------
__global__ __launch_bounds__(256) void k_from_z(
    const float* __restrict__ ek, ushort_t* __restrict__ nhwc,
    const float* __restrict__ wT, const float* __restrict__ bias)
{
  const int p = blockIdx.x * 256 + threadIdx.x;  // 0..1023
  const int co0 = blockIdx.y * 16;
  const int n = blockIdx.z;
  const float* inN = ek + (size_t)n * 64 * 1024 + p;
  float acc[16];
#pragma unroll
  for (int i = 0; i < 16; ++i) acc[i] = bias[co0 + i];
#pragma unroll 4
  for (int ci = 0; ci < 64; ++ci) {
    float iv = inN[(size_t)ci * 1024];
    const float* w = wT + (size_t)ci * 256 + co0;  // uniform
#pragma unroll
    for (int i = 0; i < 16; ++i) acc[i] = fmaf(iv, w[i], acc[i]);
  }
  uint pk[8];
#pragma unroll
  for (int i = 0; i < 8; ++i) {
    ushort_t lo = f2bf(fmaxf(acc[2 * i], 0.f));
    ushort_t hi = f2bf(fmaxf(acc[2 * i + 1], 0.f));
    pk[i] = (uint)lo | ((uint)hi << 16);
  }
  ushort_t* op = nhwc + (((size_t)n * 1024 + p) * 256 + co0);
  uint4 v0; v0.x = pk[0]; v0.y = pk[1]; v0.z = pk[2]; v0.w = pk[3];
  uint4 v1; v1.x = pk[4]; v1.y = pk[5]; v1.z = pk[6]; v1.w = pk[7];
  *(uint4*)(op) = v0;
  *(uint4*)(op + 8) = v1;
}

// ---------- t1 convtranspose 4x4 s2 p1, 256->256, bf16 MFMA, relu -> bf16 NHWC
// per-c8 halo staging: 4 taps share a 6x34 halo tile. 2 barriers per c8.
__global__ __launch_bounds__(256) void k_mfma_t1(
    const ushort_t* __restrict__ nhwc, const ushort_t* __restrict__ wb,
    const float* __restrict__ bias, ushort_t* __restrict__ t1o)
{
  __shared__ ushort_t smem[24576];  // A 16384 us (4 taps x 4096) | halo 8192 us
  const int tid = threadIdx.x;
  const int lane = tid & 63;
  const int wv = tid >> 6;
  const int wm = wv & 1, wn = wv >> 1;
  const int l15 = lane & 15, q = lane >> 4;
  const int pxT = blockIdx.x, coT = blockIdx.y, par = blockIdx.z;
  const int ry = par & 1, rx = (par >> 1) & 1;
  const int pxbase = pxT * 128;
  const int img = pxbase >> 10;
  const int U0 = (pxT & 7) * 4;   // base input-grid row of this 128px strip
  f32x4 acc[4][4];
#pragma unroll
  for (int i = 0; i < 4; ++i)
#pragma unroll
    for (int j = 0; j < 4; ++j) acc[i][j] = (f32x4){0.f, 0.f, 0.f, 0.f};

  // halo DMA sources: slot = r*136 + c*4 + kq ; (row U0-1+r, col c-1), 816 slots
  const ushort_t* srcp[4];
#pragma unroll
  for (int i = 0; i < 4; ++i) {
    int slot = i * 256 + tid;
    int rr = slot / 136;
    int c4 = slot - rr * 136;
    int cc = c4 >> 2, kq2 = c4 & 3;
    int iy = U0 - 1 + rr, ix = cc - 1;
    bool valid = (slot < 816) && ((unsigned)iy < 32u) && ((unsigned)ix < 32u);
    const ushort_t* base = valid
        ? (nhwc + (((size_t)(img * 1024 + iy * 32 + ix)) << 8))
        : g_zpad;
    srcp[i] = base + kq2 * 8;
  }
  const int wvb = wv * 1024;
  char* bufb = (char*)smem;

  for (int c8 = 0; c8 < 8; ++c8) {
#pragma unroll
    for (int tap = 0; tap < 4; ++tap) {
      const ushort_t* Ab = wb + ((size_t)((par * 4 + tap) * 8 + c8) << 13)
                           + coT * 4096 + tid * 8;
      gload16(Ab,        bufb + tap * 8192 + wvb);
      gload16(Ab + 2048, bufb + tap * 8192 + 4096 + wvb);
    }
    const int ko = c8 * 32;
#pragma unroll
    for (int i = 0; i < 4; ++i)
      gload16(srcp[i] + ko, bufb + 32768 + i * 4096 + wvb);
    __syncthreads();
    const ushort_t* A = smem;
    const ushort_t* H = smem + 16384;
#pragma unroll
    for (int tap = 0; tap < 4; ++tap) {
      const int a = tap >> 1, b = tap & 1;
      const int dr = ry + 1 - a, dc = rx + 1 - b;
      short8 af[4], bfr[4];
#pragma unroll
      for (int i = 0; i < 4; ++i)
        af[i] = *(const short8*)(A + tap * 4096 + (wm * 64 + i * 16 + l15) * 32 + q * 8);
#pragma unroll
      for (int j = 0; j < 4; ++j) {
        const int row = wn * 64 + j * 16 + l15;
        const int rr = (row >> 5) + dr, cc = (row & 31) + dc;
        bfr[j] = *(const short8*)(H + rr * 1088 + cc * 32 + q * 8);
      }
#pragma unroll
      for (int i = 0; i < 4; ++i)
#pragma unroll
        for (int j = 0; j < 4; ++j)
          acc[i][j] = __builtin_amdgcn_mfma_f32_16x16x32_bf16(af[i], bfr[j], acc[i][j], 0, 0, 0);
    }
    __syncthreads();   // before restage (single-buffered)
  }

#pragma unroll
  for (int i = 0; i < 4; ++i) {
    int co = coT * 128 + wm * 64 + i * 16 + q * 4;
#pragma unroll
    for (int j = 0; j < 4; ++j) {
      int px = pxbase + wn * 64 + j * 16 + l15;
      int u = (px >> 5) & 31, vv = px & 31;
      int oy = 2 * u + ry, ox = 2 * vv + rx;
      ushort_t e0 = f2bf(fmaxf(acc[i][j][0] + bias[co + 0], 0.f));
      ushort_t e1 = f2bf(fmaxf(acc[i][j][1] + bias[co + 1], 0.f));
      ushort_t e2 = f2bf(fmaxf(acc[i][j][2] + bias[co + 2], 0.f));
      ushort_t e3 = f2bf(fmaxf(acc[i][j][3] + bias[co + 3], 0.f));
      uint2 pk; pk.x = (uint)e0 | ((uint)e1 << 16); pk.y = (uint)e2 | ((uint)e3 << 16);
      *(uint2*)(t1o + ((size_t)(img * 4096 + oy * 64 + ox) * 256 + co)) = pk;
    }
  }
}

// ---------- t2 convtranspose 4x4 s2 p1, 256->3, bf16 MFMA, sigmoid ----------
// global_load_lds staging (linear LDS, dbuf, 1 barrier/chunk).
__global__ __launch_bounds__(256) void k_mfma_t2(
    const ushort_t* __restrict__ t1o, const ushort_t* __restrict__ wb,
    const float* __restrict__ bias, float* __restrict__ out)
{
  __shared__ ushort_t smem[2][8704];  // per buf: sA 8192 us | sB 512 us
  const int tid = threadIdx.x, lane = tid & 63, wv = tid >> 6;
  const int l15 = lane & 15, q = lane >> 4;
  const int pxb = blockIdx.x * 256;
  const int par = blockIdx.y;
  const int ry = par & 1, rx = (par >> 1) & 1;
  f32x4 acc[4];
#pragma unroll
  for (int m = 0; m < 4; ++m) acc[m] = (f32x4){0.f, 0.f, 0.f, 0.f};
  const int kg = tid & 3;
  const ushort_t* srcA[4];
  int ptap = -1;
  auto retap = [&](int tap) {
    ptap = tap;
    const int a = tap >> 1, b = tap & 1;
#pragma unroll
    for (int i = 0; i < 4; ++i) {
      int row = (tid >> 2) + 64 * i;
      int px = pxb + row;
      int img = px >> 12, p = px & 4095, u = p >> 6, v = p & 63;
      int iy = u + ry - a, ix = v + rx - b;
      bool valid = ((unsigned)iy < 64u) && ((unsigned)ix < 64u);
      srcA[i] = (valid ? (t1o + (((size_t)(img * 4096 + iy * 64 + ix)) << 8)) : g_zpad)
                + kg * 8;
    }
  };
  const int wvb = wv * 1024;
  auto stage = [&](int c, int bi) {
    const int tap = c >> 3, cg = c & 7;
    if (tap != ptap) retap(tap);
    char* bufb = (char*)smem[bi];
    const int ko = cg * 32;
#pragma unroll
    for (int i = 0; i < 4; ++i)
      gload16(srcA[i] + ko, bufb + i * 4096 + wvb);
    if (tid < 64)
      gload16(wb + ((size_t)(par * 32 + c)) * 512 + tid * 8, bufb + 16384);
  };
  auto compute = [&](const ushort_t* buf) {
    const ushort_t* sA = buf;
    const ushort_t* sB = buf + 8192;
    short8 bf = *(const short8*)(sB + l15 * 32 + q * 8);
#pragma unroll
    for (int m = 0; m < 4; ++m) {
      const int row = wv * 64 + m * 16 + l15;
      short8 af = *(const short8*)(sA + row * 32 + q * 8);
      acc[m] = __builtin_amdgcn_mfma_f32_16x16x32_bf16(af, bf, acc[m], 0, 0, 0);
    }
  };

  stage(0, 0);
  __syncthreads();
  int cur = 0;
  for (int c = 0; c < 32; ++c) {
    if (c + 1 < 32) stage(c + 1, cur ^ 1);
    compute(smem[cur]);
    __syncthreads();
    cur ^= 1;
  }

  const int co = l15;
  if (co < 3) {
    float bco = bias[co];
#pragma unroll
    for (int m = 0; m < 4; ++m) {
#pragma unroll
      for (int r = 0; r < 4; ++r) {
        int px = pxb + wv * 64 + m * 16 + q * 4 + r;
        int img = px >> 12, p = px & 4095, u = p >> 6, v = p & 63;
        size_t addr = ((size_t)(img * 3 + co)) * 16384 + (2 * u + ry) * 128 + (2 * v + rx);
        out[addr] = 1.f / (1.f + expf(-(acc[m][r] + bco)));
      }
    }
  }
}

// ---------------------------------------------------------------------------
extern "C" void kernel_launch(void* const* d_in, const int* in_sizes, int n_in,
                              void* d_out, int out_size, void* d_ws, size_t ws_size,
                              hipStream_t stream) {
  (void)in_sizes; (void)n_in; (void)out_size; (void)ws_size;
  const float* x      = (const float*)d_in[0];
  const float* c1_w   = (const float*)d_in[1];
  const float* c1_b   = (const float*)d_in[2];
  const float* c2_w   = (const float*)d_in[3];
  const float* c2_b   = (const float*)d_in[4];
  const float* r0_w3  = (const float*)d_in[5];
  const float* r0_b3  = (const float*)d_in[6];
  const float* r0_w1  = (const float*)d_in[7];
  const float* r0_b1  = (const float*)d_in[8];
  const float* r1_w3  = (const float*)d_in[9];
  const float* r1_b3  = (const float*)d_in[10];
  const float* r1_w1  = (const float*)d_in[11];
  const float* r1_b1  = (const float*)d_in[12];
  const float* to_z_w = (const float*)d_in[13];
  const float* to_z_b = (const float*)d_in[14];
  const float* cb     = (const float*)d_in[15];
  const float* from_z_w = (const float*)d_in[16];
  const float* from_z_b = (const float*)d_in[17];
  const float* t1_w   = (const float*)d_in[18];
  const float* t1_b   = (const float*)d_in[19];
  const float* t2_w   = (const float*)d_in[20];
  const float* t2_b   = (const float*)d_in[21];

  float* wsf = (float*)d_ws;
  // Era-choreographed regions (float offsets) — unchanged from R10.
  ushort_t* xs1p0 = (ushort_t*)(wsf + 0);
  ushort_t* xs1p1 = (ushort_t*)(wsf + 4194304);
  float*    cp0   = wsf + 8388608;               // conv2 partial kz0 (= h32 slot)
  float*    h32   = wsf + 8388608;
  ushort_t* sE0   = (ushort_t*)(wsf + 0);        // split ping [0,1.05M)
  ushort_t* sE1   = (ushort_t*)(wsf + 1048576);  // split ping [1.05,2.1M)
  ushort_t* sF0   = (ushort_t*)(wsf + 2097152);  // split pong [2.1,3.15M)
  ushort_t* sF1   = (ushort_t*)(wsf + 3145728);  // split pong [3.15,4.19M)
  float*    pbest = wsf + 0;                     // vq-era
  int*      pbid  = (int*)(wsf + 131072);        // vq-era
  ushort_t* t1out = (ushort_t*)(wsf + 2097152);  // dec-era [2.1M, 6.29M)
  ushort_t* decn  = (ushort_t*)(wsf + 6291456);  // dec-era [6.29M, 7.34M)
  ushort_t* wp_c2   = (ushort_t*)(wsf + 12582912);
  ushort_t* wp_r0w3 = (ushort_t*)(wsf + 13631488);
  ushort_t* wp_r1w3 = (ushort_t*)(wsf + 14221312);
  ushort_t* wp_r0w1 = (ushort_t*)(wsf + 14811136);
  ushort_t* wp_r1w1 = (ushort_t*)(wsf + 14876672);
  float*    wt_c1   = wsf + 14942208;
  float*    wt_toz  = wsf + 14954496;
  float*    wt_fromz= wsf + 14970880;
  ushort_t* t1wb    = (ushort_t*)(wsf + 14987264);
  ushort_t* w2pk    = (ushort_t*)(wsf + 15511552);
  float*    cnorm   = wsf + 15544320;

  float* out_img = (float*)d_out;        // 393216
  float* z_e_out = out_img + 393216;     // 524288
  float* e_k_out = z_e_out + 524288;     // 524288
  float* ids_out = e_k_out + 524288;     // 8192 (stored as float)

  // ---- weight prep (merged: 2 dispatches) ----
  k_prep_all<<<1714, 256, 0, stream>>>(
      c1_w, wt_c1, to_z_w, wt_toz, from_z_w, wt_fromz, cb, cnorm, t2_w, w2pk,
      c2_w, wp_c2, r0_w3, wp_r0w3, r1_w3, wp_r1w3, r0_w1, wp_r0w1, r1_w1, wp_r1w1);
  k_prep_t1w<<<4096, 256, 0, stream>>>(t1_w, t1wb);

  // ---- encoder ----
  k_conv1_split<<<dim3(64, 4, 8), 256, 0, stream>>>(x, xs1p0, xs1p1, wt_c1, c1_b);
  // conv2: plain-store partials cp0/cp1, epilogue: sum+relu -> h32 + splits
  k_enc_mfma_split<0><<<dim3(64, 4, 2), 256, 0, stream>>>(xs1p0, xs1p1, wp_c2, cp0);
  k_enc_epi<true><<<dim3(32, 16), 256, 0, stream>>>(cp0, h32, sE0, sE1, c2_b);
  // r0 w3 (kz=1 halo, fused epilogue): sE -> sF
  k_enc_mfma_3x3f<<<dim3(64, 8), 256, 0, stream>>>(sE0, sE1, wp_r0w3, r0_b3, sF0, sF1);
  // r0 w1: h += conv; write h32 + split(relu(h)): sF -> sE
  k_enc_mfma<true ><<<dim3(64, 8), 256, 0, stream>>>(
      sF0, sF1, wp_r0w1, r0_b1, h32, sE0, sE1);
  // r1 w3: sE -> sF
  k_enc_mfma_3x3f<<<dim3(64, 8), 256, 0, stream>>>(sE0, sE1, wp_r1w3, r1_b3, sF0, sF1);
  // r1 w1: h += conv; write h32 only: reads sF
  k_enc_mfma<false><<<dim3(64, 8), 256, 0, stream>>>(
      sF0, sF1, wp_r1w1, r1_b1, h32, nullptr, nullptr);
  // to_z (fp32)
  k_conv1x1<<<dim3(4, 8, 8), 256, 0, stream>>>(h32, z_e_out, wt_toz, to_z_b, 256, 64, 1024);

  // ---- VQ (chunk-parallel; bit-identical argmin) ----
  k_vq_part<<<dim3(32, 16), 256, 0, stream>>>(z_e_out, cb, cnorm, pbest, pbid);
  k_vq_reduce<<<32, 256, 0, stream>>>(pbest, pbid, cb, ids_out, e_k_out);

  // ---- decoder (bf16) ----
  k_from_z<<<dim3(4, 16, 8), 256, 0, stream>>>(e_k_out, decn, wt_fromz, from_z_b);
  k_mfma_t1<<<dim3(64, 2, 4), 256, 0, stream>>>(decn, t1wb, t1_b, t1out);
  k_mfma_t2<<<dim3(128, 4), 256, 0, stream>>>(t1out, w2pk, t2_b, out_img);
}

// Round 12
// 366.522 us; speedup vs baseline: 1.3691x; 1.0109x over previous
//
#include <hip/hip_runtime.h>
#include <math.h>

// ---------------------------------------------------------------------------
// VQ-VAE forward.
// Encoder: 256-ch convs as implicit-GEMM MFMA with 2-term bf16 split inputs.
// conv2 split-K=2 plain-store partials + epi. 3x3 convs: kz=1 halo kernel,
// fused epilogue. VQ: chunk-parallel argmin. Decoder: t1 halo + t2 DMA.
// R12: k_prep_t1w coalesced rewrite (reads full 64B lines via LDS transpose;
//      was 16x overfetch ~67MB). from_z ELIMINATED: precompute
//      T[512][256] = f2bf(relu(W@cb[j]+b)) once (bit-identical FMA order),
//      gather T[bid] inside vq_reduce. T lives in dead cp1 partial slot.
// ---------------------------------------------------------------------------

typedef unsigned int uint;
typedef unsigned short ushort_t;
using short8 = __attribute__((ext_vector_type(8))) short;
using f32x4  = __attribute__((ext_vector_type(4))) float;

// zero-initialized pad: invalid halo rows DMA from here (always zero)
__device__ __attribute__((aligned(16))) ushort_t g_zpad[512];

static __device__ __forceinline__ int rfl(int x) { return __builtin_amdgcn_readfirstlane(x); }
static __device__ __forceinline__ ushort_t f2bf(float f) {
  uint u = __float_as_uint(f);
  return (ushort_t)((u + 0x7fffu + ((u >> 16) & 1u)) >> 16);  // RNE; finite inputs
}
static __device__ __forceinline__ float bf2f(ushort_t b) {
  return __uint_as_float(((uint)b) << 16);
}
// direct global->LDS DMA, 16B per lane; lds dest = wave-uniform base + lane*16
static __device__ __forceinline__ void gload16(const ushort_t* g, void* l) {
  __builtin_amdgcn_global_load_lds(
      (const __attribute__((address_space(1))) void*)g,
      (__attribute__((address_space(3))) void*)l, 16, 0, 0);
}

// ---------- weight prep ----------
// encoder MFMA weight pack body: w[co][ci(256)][KH][KW] fp32 ->
// wp[chunk][coT(4)][pl(2)][row(64)][k(32)] bf16 split, chunk = tap*8 + cg
template<int KIND>  // 0: 4x4 (16 taps), 1: 3x3 (9 taps), 2: 1x1 (1 tap)
static __device__ __forceinline__ void d_prep_enc_body(
    int bx, int tid, const float* __restrict__ w, ushort_t* __restrict__ wp)
{
  constexpr int KK = (KIND == 0) ? 16 : (KIND == 1 ? 9 : 1);
  constexpr int KW = (KIND == 0) ? 4  : (KIND == 1 ? 3 : 1);
  constexpr int NT = KK;
  const int wvg = bx * 4 + (tid >> 6);   // 0..1023
  const int lane = tid & 63;
  const int co = wvg >> 2;
  const int ci = (wvg & 3) * 64 + lane;
  const float* src = w + (size_t)(co * 256 + ci) * KK;
  const int coT = co >> 6, row = co & 63, cg = ci >> 5, k = ci & 31;
  float v[KK];
#pragma unroll
  for (int j = 0; j < KK; ++j) v[j] = src[j];
#pragma unroll
  for (int tap = 0; tap < NT; ++tap) {
    int ky, kx;
    if (KIND == 0)      { ky = tap >> 2; kx = tap & 3; }
    else if (KIND == 1) { ky = tap / 3;  kx = tap - ky * 3; }
    else                { ky = 0; kx = 0; }
    float val = v[ky * KW + kx];
    ushort_t b0 = f2bf(val);
    ushort_t b1 = f2bf(val - bf2f(b0));
    const int chunk = tap * 8 + cg;
    size_t base = ((size_t)(chunk * 4 + coT) << 12) + row * 32 + k;
    wp[base] = b0;          // pl=0
    wp[base + 2048] = b1;   // pl=1
  }
}

// mega prep: misc (434) | enc0 c2 (256) | enc1 r0w3/r1w3 (512) | enc2 r0w1/r1w1 (512)
__global__ __launch_bounds__(256) void k_prep_all(
    const float* __restrict__ c1w, float* __restrict__ wt_c1,
    const float* __restrict__ tozw, float* __restrict__ wt_toz,
    const float* __restrict__ fromzw, float* __restrict__ wt_fromz,
    const float* __restrict__ cb, float* __restrict__ cnorm,
    const float* __restrict__ t2w, ushort_t* __restrict__ w2pk,
    const float* __restrict__ c2w, ushort_t* __restrict__ wp_c2,
    const float* __restrict__ r0w3, ushort_t* __restrict__ wp_r0w3,
    const float* __restrict__ r1w3, ushort_t* __restrict__ wp_r1w3,
    const float* __restrict__ r0w1, ushort_t* __restrict__ wp_r0w1,
    const float* __restrict__ r1w1, ushort_t* __restrict__ wp_r1w1)
{
  const int b = blockIdx.x, tid = threadIdx.x;
  if (b < 434) {
    if (b < 48) {            // c1 transpose: CO=256, CIKK=48 (12288 elems)
      int idx = b * 256 + tid;
      int co = idx % 256, i = idx / 256;
      wt_c1[idx] = c1w[co * 48 + i];
    } else if (b < 112) {    // to_z transpose: CO=64, CIKK=256 (16384)
      int idx = (b - 48) * 256 + tid;
      int co = idx % 64, i = idx / 64;
      wt_toz[idx] = tozw[co * 256 + i];
    } else if (b < 176) {    // from_z transpose (kept for layout stability; unused)
      int idx = (b - 112) * 256 + tid;
      int co = idx % 256, i = idx / 256;
      wt_fromz[idx] = fromzw[co * 64 + i];
    } else if (b < 178) {    // cnorm[j] = sum_c cb[j][c]^2
      int idx = (b - 176) * 256 + tid;
      if (idx < 512) {
        float s = 0.f;
        for (int c = 0; c < 64; ++c) { float v = cb[idx * 64 + c]; s = fmaf(v, v, s); }
        cnorm[idx] = s;
      }
    } else {                 // t2_w pack: 65536 elems (256 blocks)
      int idx = (b - 178) * 256 + tid;
      int k = idx & 31, co = (idx >> 5) & 15, chunk = (idx >> 9) & 31, par = idx >> 14;
      int tap = chunk >> 3, cg = chunk & 7;
      int a = tap >> 1, bb = tap & 1;
      int ry = par & 1, rx = (par >> 1) & 1;
      int ky = ((ry + 1) & 1) + 2 * a;
      int kx = ((rx + 1) & 1) + 2 * bb;
      int ci = cg * 32 + k;
      float v = (co < 3) ? t2w[((ci * 3 + co) << 4) + ky * 4 + kx] : 0.f;
      w2pk[idx] = f2bf(v);
    }
  } else if (b < 690) {
    d_prep_enc_body<0>(b - 434, tid, c2w, wp_c2);
  } else if (b < 1202) {
    int bx = b - 690;
    if (bx < 256) d_prep_enc_body<1>(bx, tid, r0w3, wp_r0w3);
    else          d_prep_enc_body<1>(bx - 256, tid, r1w3, wp_r1w3);
  } else {
    int bx = b - 1202;
    if (bx < 256) d_prep_enc_body<2>(bx, tid, r0w1, wp_r0w1);
    else          d_prep_enc_body<2>(bx - 256, tid, r1w1, wp_r1w1);
  }
}

// t1_w [ci][co][ky][kx] -> bf16 [par][tap][c8][co][kk32]
// R12: coalesced. Block = (c8, co-block-of-8); read full 64B lines (16 floats
// per thread), LDS transpose, write 512B-contiguous per (par,tap).
__global__ __launch_bounds__(256) void k_prep_t1w(
    const float* __restrict__ w, ushort_t* __restrict__ wb)
{
  __shared__ ushort_t s[32][8][17];   // [ci5][co8][k], padded
  const int b = blockIdx.x;           // 256
  const int c8 = b >> 5, cbk = b & 31;
  const int tid = threadIdx.x;
  // read phase: co fastest for coalescing
  {
    const int co8 = tid & 7, ci5 = tid >> 3;
    const int ci = c8 * 32 + ci5, co = cbk * 8 + co8;
    const float* src = w + ((size_t)(ci * 256 + co) << 4);
#pragma unroll
    for (int k = 0; k < 16; ++k) s[ci5][co8][k] = f2bf(src[k]);
  }
  __syncthreads();
  // write phase: kk (=ci5) fastest -> contiguous 512B per (par,tap)
  const int ci5 = tid & 31, co8 = tid >> 5;
  const int co = cbk * 8 + co8;
#pragma unroll
  for (int par = 0; par < 4; ++par) {
    const int ry = par & 1, rx = (par >> 1) & 1;
#pragma unroll
    for (int tap = 0; tap < 4; ++tap) {
      const int a = tap >> 1, bb = tap & 1;
      const int ky = ((ry + 1) & 1) + 2 * a;
      const int kx = ((rx + 1) & 1) + 2 * bb;
      size_t dst = ((size_t)par << 18) | ((size_t)tap << 16) | ((size_t)c8 << 13)
                 | ((size_t)co << 5) | (size_t)ci5;
      wb[dst] = s[ci5][co8][ky * 4 + kx];
    }
  }
}

// from_z table: T[j][co] = f2bf(relu(bias[co] + sum_ci cb[j][ci]*W[co][ci]))
// FMA order identical to old k_from_z -> bit-identical results.
__global__ __launch_bounds__(256) void k_prep_fzT(
    const float* __restrict__ cb, const float* __restrict__ fzw,
    const float* __restrict__ bias, ushort_t* __restrict__ T)
{
  const int j = blockIdx.x;        // 512
  const int co = threadIdx.x;      // 256
  const float* c = cb + j * 64;
  const float* w = fzw + co * 64;
  float acc = bias[co];
#pragma unroll 4
  for (int ci = 0; ci < 64; ++ci) acc = fmaf(c[ci], w[ci], acc);
  T[(size_t)j * 256 + co] = f2bf(fmaxf(acc, 0.f));
}

// ---------- conv1: 3->256, 4x4 s2 p1, relu, output split-bf16 NHWC ----------
__global__ __launch_bounds__(256) void k_conv1_split(
    const float* __restrict__ in, ushort_t* __restrict__ o0, ushort_t* __restrict__ o1,
    const float* __restrict__ wT, const float* __restrict__ bias)
{
  __shared__ float s_in[3 * 360];  // parity-split cols, pitch 20 (2-way free)
  const int tid = threadIdx.x;
  const int lane = tid & 63;
  const int wv = rfl(tid >> 6);
  const int px = lane & 7, py = lane >> 3;
  const int tx = blockIdx.x & 7, ty = blockIdx.x >> 3;
  const int X = tx * 8, Y = ty * 8;
  const int cob = blockIdx.y * 64 + wv * 16;
  const int n = blockIdx.z;
  float acc[16];
#pragma unroll
  for (int i = 0; i < 16; ++i) acc[i] = bias[cob + i];
  const float* inN = in + (size_t)n * 3 * 16384;
  for (int e = tid; e < 3 * 360; e += 256) {
    int col2 = e % 20; int t = e / 20; int row = t % 18; int ci = t / 18;
    int pr = col2 / 10, hc = col2 % 10, ixl = 2 * hc + pr;
    int iy = 2 * Y - 1 + row, ix = 2 * X - 1 + ixl;
    float v = 0.f;
    if (ixl < 18 && (unsigned)iy < 128u && (unsigned)ix < 128u)
      v = inN[ci * 16384 + iy * 128 + ix];
    s_in[e] = v;
  }
  __syncthreads();
  const float* wc = wT + cob;
#pragma unroll
  for (int c = 0; c < 3; ++c) {
    const float* base = s_in + c * 360 + py * 40 + px;
#pragma unroll
    for (int ky = 0; ky < 4; ++ky) {
#pragma unroll
      for (int kx = 0; kx < 4; ++kx) {
        float iv = base[ky * 20 + (kx & 1) * 10 + (kx >> 1)];
        const float* w = wc + (size_t)(c * 16 + ky * 4 + kx) * 256;  // uniform
#pragma unroll
        for (int i = 0; i < 16; ++i) acc[i] = fmaf(iv, w[i], acc[i]);
      }
    }
  }
  const int pxg = n * 4096 + (Y + py) * 64 + (X + px);
  uint p0[8], p1[8];
#pragma unroll
  for (int i = 0; i < 8; ++i) {
    float va = fmaxf(acc[2 * i], 0.f), vb = fmaxf(acc[2 * i + 1], 0.f);
    ushort_t a0 = f2bf(va), b0 = f2bf(vb);
    ushort_t a1 = f2bf(va - bf2f(a0)), b1 = f2bf(vb - bf2f(b0));
    p0[i] = (uint)a0 | ((uint)b0 << 16);
    p1[i] = (uint)a1 | ((uint)b1 << 16);
  }
  ushort_t* d0 = o0 + (size_t)pxg * 256 + cob;
  ushort_t* d1 = o1 + (size_t)pxg * 256 + cob;
  uint4 v0a; v0a.x = p0[0]; v0a.y = p0[1]; v0a.z = p0[2]; v0a.w = p0[3];
  uint4 v0b; v0b.x = p0[4]; v0b.y = p0[5]; v0b.z = p0[6]; v0b.w = p0[7];
  uint4 v1a; v1a.x = p1[0]; v1a.y = p1[1]; v1a.z = p1[2]; v1a.w = p1[3];
  uint4 v1b; v1b.x = p1[4]; v1b.y = p1[5]; v1b.z = p1[6]; v1b.w = p1[7];
  *(uint4*)d0 = v0a; *(uint4*)(d0 + 8) = v0b;
  *(uint4*)d1 = v1a; *(uint4*)(d1 + 8) = v1b;
}

// ---------- conv2 implicit-GEMM MFMA, split-K=2, plain-store partial --------
// Block: 64co x 128px, 4 waves. grid (pxT 64, coT 4, kz 2).
// global_load_lds staging, linear LDS.
template<int KIND>  // 0: conv2 (128 chunks)
__global__ __launch_bounds__(256) void k_enc_mfma_split(
    const ushort_t* __restrict__ x0, const ushort_t* __restrict__ x1,
    const ushort_t* __restrict__ wp, float* __restrict__ part)
{
  __shared__ ushort_t smem[2][12288];   // per buf: sA 4096 us (8KB) | sB 8192 us (16KB)
  const int tid = threadIdx.x, lane = tid & 63, wv = tid >> 6;
  const int l15 = lane & 15, q = lane >> 4;
  const int pxT = blockIdx.x, coT = blockIdx.y;
  constexpr int NCH = (KIND == 0) ? 128 : 72;
  const int CH0 = blockIdx.z * (NCH / 2), CH1 = CH0 + NCH / 2;
  f32x4 acc[4][2];
#pragma unroll
  for (int m = 0; m < 4; ++m)
#pragma unroll
    for (int n = 0; n < 2; ++n) acc[m][n] = (f32x4){0.f, 0.f, 0.f, 0.f};

  // B staging: thread handles rows r0 and r0+64, 16B quarter kq
  const int r0 = tid >> 2, kq = tid & 3;
  int bimg[2], bu[2], bvc[2];
#pragma unroll
  for (int r = 0; r < 2; ++r) {
    int bpx = pxT * 128 + r0 + r * 64;
    bimg[r] = bpx >> 10; int bp = bpx & 1023; bu[r] = bp >> 5; bvc[r] = bp & 31;
  }
  const ushort_t* srcB[2][2];  // [row r][plane p], excludes cg offset
  int ptap = -1;
  auto retap = [&](int tap) {
    ptap = tap;
    int ky, kx;
    if (KIND == 0) { ky = tap >> 2; kx = tap & 3; }
    else           { ky = tap / 3;  kx = tap - ky * 3; }
#pragma unroll
    for (int r = 0; r < 2; ++r) {
      bool v; size_t rowb;
      if (KIND == 0) {
        int iy = 2 * bu[r] - 1 + ky, ix = 2 * bvc[r] - 1 + kx;
        v = ((unsigned)iy < 64u) && ((unsigned)ix < 64u);
        rowb = ((size_t)(bimg[r] * 4096 + iy * 64 + ix)) << 8;
      } else {
        int iy = bu[r] - 1 + ky, ix = bvc[r] - 1 + kx;
        v = ((unsigned)iy < 32u) && ((unsigned)ix < 32u);
        rowb = ((size_t)(bimg[r] * 1024 + iy * 32 + ix)) << 8;
      }
      srcB[r][0] = (v ? (x0 + rowb) : g_zpad) + kq * 8;
      srcB[r][1] = (v ? (x1 + rowb) : g_zpad) + kq * 8;
    }
  };

  const int wvb = wv * 1024;  // wave-uniform byte base (lane*16 auto)
  auto stage = [&](int chunk, int bi) {
    const int tap = chunk >> 3, cg = chunk & 7;
    if (tap != ptap) retap(tap);
    char* bufb = (char*)smem[bi];
    const ushort_t* ap = wp + ((size_t)(chunk * 4 + coT) << 12) + tid * 8;
    gload16(ap,        bufb + wvb);                        // sA pl0
    gload16(ap + 2048, bufb + 4096 + wvb);                 // sA pl1
    const int ko = cg * 32;
    gload16(srcB[0][0] + ko, bufb + 8192 + wvb);           // sB pl0 rows 0-63
    gload16(srcB[1][0] + ko, bufb + 8192 + 4096 + wvb);    // sB pl0 rows 64-127
    gload16(srcB[0][1] + ko, bufb + 16384 + wvb);          // sB pl1 rows 0-63
    gload16(srcB[1][1] + ko, bufb + 16384 + 4096 + wvb);   // sB pl1 rows 64-127
  };
  auto compute = [&](const ushort_t* buf) {
    const ushort_t* sA = buf;
    const ushort_t* sB = buf + 4096;
    short8 af[4][2], bf[2][2];
#pragma unroll
    for (int m = 0; m < 4; ++m)
#pragma unroll
      for (int pl = 0; pl < 2; ++pl)
        af[m][pl] = *(const short8*)(sA + pl * 2048 + (m * 16 + l15) * 32 + q * 8);
#pragma unroll
    for (int n = 0; n < 2; ++n)
#pragma unroll
      for (int pl = 0; pl < 2; ++pl)
        bf[n][pl] = *(const short8*)(sB + pl * 4096 + (wv * 32 + n * 16 + l15) * 32 + q * 8);
#pragma unroll
    for (int m = 0; m < 4; ++m)
#pragma unroll
      for (int n = 0; n < 2; ++n) {
        acc[m][n] = __builtin_amdgcn_mfma_f32_16x16x32_bf16(af[m][0], bf[n][0], acc[m][n], 0, 0, 0);
        acc[m][n] = __builtin_amdgcn_mfma_f32_16x16x32_bf16(af[m][0], bf[n][1], acc[m][n], 0, 0, 0);
        acc[m][n] = __builtin_amdgcn_mfma_f32_16x16x32_bf16(af[m][1], bf[n][0], acc[m][n], 0, 0, 0);
      }
  };

  stage(CH0, 0);
  __syncthreads();
  int cur = 0;
  for (int c = CH0; c < CH1; ++c) {
    if (c + 1 < CH1) stage(c + 1, cur ^ 1);   // DMA in flight under compute
    compute(smem[cur]);
    __syncthreads();                           // drains DMA; 1 barrier/chunk
    cur ^= 1;
  }

  // plain stores to this kz's private partial slice (deterministic)
  float* pz = part + ((size_t)blockIdx.z << 21);
#pragma unroll
  for (int m = 0; m < 4; ++m) {
#pragma unroll
    for (int n = 0; n < 2; ++n) {
#pragma unroll
      for (int r = 0; r < 4; ++r) {
        const int co_l = m * 16 + q * 4 + r;
        const int px_l = wv * 32 + n * 16 + l15;
        const int px = pxT * 128 + px_l;
        const int img = px >> 10, pp = px & 1023;
        const size_t ha = ((size_t)(img * 256 + coT * 64 + co_l)) * 1024 + pp;
        pz[ha] = acc[m][n][r];
      }
    }
  }
}

// ---------- 3x3 implicit-GEMM MFMA, kz=1, FUSED epilogue --------------------
// Block 32co x 128px. Per cg (0..7): stage all 9 taps' A + 6x34 halo,
// 1 barrier, 108 MFMA, 1 barrier. Then relu+split epilogue via LDS
// transpose. grid (pxT 64, coT 8).
__global__ __launch_bounds__(256) void k_enc_mfma_3x3f(
    const ushort_t* __restrict__ x0, const ushort_t* __restrict__ x1,
    const ushort_t* __restrict__ wp, const float* __restrict__ bias,
    ushort_t* __restrict__ s0, ushort_t* __restrict__ s1)
{
  __shared__ ushort_t smem[32768];  // A 18432 us | halo 14336 us; epi reuses [0,8192)
  const int tid = threadIdx.x, lane = tid & 63, wv = tid >> 6;
  const int l15 = lane & 15, q = lane >> 4;
  const int pxT = blockIdx.x, coT = blockIdx.y;
  const int img = pxT >> 3;          // 8 blocks per 32x32 image
  const int U0 = (pxT & 7) * 4;      // base output row of this 128px strip
  f32x4 acc[2][2];
#pragma unroll
  for (int m = 0; m < 2; ++m)
#pragma unroll
    for (int n = 0; n < 2; ++n) acc[m][n] = (f32x4){0.f, 0.f, 0.f, 0.f};

  // halo DMA sources: slot = pl*816 + r*136 + c*4 + kq ; (pl, row U0-1+r, col c-1)
  const ushort_t* srcp[7];
#pragma unroll
  for (int i = 0; i < 7; ++i) {
    int slot = i * 256 + tid;
    int pl = slot >= 816 ? 1 : 0;
    int rem = slot - pl * 816;
    int rr = rem / 136;
    int c4 = rem - rr * 136;
    int cc = c4 >> 2, kq2 = c4 & 3;
    int iy = U0 - 1 + rr, ix = cc - 1;
    bool valid = (slot < 1632) && ((unsigned)iy < 32u) && ((unsigned)ix < 32u);
    const ushort_t* base = valid
        ? ((pl ? x1 : x0) + (((size_t)(img * 1024 + iy * 32 + ix)) << 8))
        : g_zpad;
    srcp[i] = base + kq2 * 8;
  }
  // A DMA source: per tap one 4KB DMA; threads 0..127 pl0, 128..255 pl1
  const int apl = tid >> 7;
  const int aus = apl * 2048 + (coT & 1) * 1024 + (tid & 127) * 8;
  const int coTq = coT >> 1;
  const int wvb = wv * 1024;
  char* bufb = (char*)smem;

  for (int cg = 0; cg < 8; ++cg) {
#pragma unroll
    for (int tap = 0; tap < 9; ++tap) {
      const int chunk = tap * 8 + cg;
      gload16(wp + ((size_t)(chunk * 4 + coTq) << 12) + aus, bufb + tap * 4096 + wvb);
    }
    const int ko = cg * 32;
#pragma unroll
    for (int i = 0; i < 7; ++i)
      gload16(srcp[i] + ko, bufb + 36864 + i * 4096 + wvb);
    __syncthreads();
    const ushort_t* Ab = smem;
    const ushort_t* Hb = smem + 18432;
#pragma unroll 3
    for (int tap = 0; tap < 9; ++tap) {
      const int ky = tap / 3, kx = tap - ky * 3;
      short8 af[2][2], bf[2][2];
#pragma unroll
      for (int m = 0; m < 2; ++m)
#pragma unroll
        for (int pl = 0; pl < 2; ++pl)
          af[m][pl] = *(const short8*)(Ab + tap * 2048 + pl * 1024 + (m * 16 + l15) * 32 + q * 8);
      const int r = wv + ky;
#pragma unroll
      for (int n = 0; n < 2; ++n)
#pragma unroll
        for (int pl = 0; pl < 2; ++pl)
          bf[n][pl] = *(const short8*)(Hb + pl * 6528 + r * 1088 + (n * 16 + l15 + kx) * 32 + q * 8);
#pragma unroll
      for (int m = 0; m < 2; ++m)
#pragma unroll
        for (int n = 0; n < 2; ++n) {
          acc[m][n] = __builtin_amdgcn_mfma_f32_16x16x32_bf16(af[m][0], bf[n][0], acc[m][n], 0, 0, 0);
          acc[m][n] = __builtin_amdgcn_mfma_f32_16x16x32_bf16(af[m][0], bf[n][1], acc[m][n], 0, 0, 0);
          acc[m][n] = __builtin_amdgcn_mfma_f32_16x16x32_bf16(af[m][1], bf[n][0], acc[m][n], 0, 0, 0);
        }
    }
    __syncthreads();   // before restage; final one protects epilogue smem reuse
  }

  // fused epilogue: splits of relu(acc + bias) via LDS transpose
  // smem layout: [pl(2)][px_l(128)][co_l(32)] ushort = 8192 us
  const int cob = coT * 32;
#pragma unroll
  for (int m = 0; m < 2; ++m) {
#pragma unroll
    for (int n = 0; n < 2; ++n) {
#pragma unroll
      for (int r = 0; r < 4; ++r) {
        const int co_l = m * 16 + q * 4 + r;
        const int px_l = wv * 32 + n * 16 + l15;
        float sv = fmaxf(acc[m][n][r] + bias[cob + co_l], 0.f);
        ushort_t b0 = f2bf(sv);
        smem[px_l * 32 + co_l] = b0;
        smem[4096 + px_l * 32 + co_l] = f2bf(sv - bf2f(b0));
      }
    }
  }
  __syncthreads();
#pragma unroll
  for (int i = 0; i < 4; ++i) {
    int idx = tid + 256 * i;          // 0..1023 uint4 units
    int pl = idx >> 9;
    int rem = idx & 511;
    int px_l = rem >> 2, g = rem & 3;
    uint4 vv = *(const uint4*)(smem + pl * 4096 + px_l * 32 + g * 8);
    ushort_t* dst = (pl ? s1 : s0) + ((size_t)(pxT * 128 + px_l)) * 256 + cob + g * 8;
    *(uint4*)dst = vv;
  }
}

// ---------- epilogue for conv2 split ----------
// v = p0 + p1 + bias; relu; h32 = v; splits.
template<bool WH>
__global__ __launch_bounds__(256) void k_enc_epi(
    const float* __restrict__ part, float* __restrict__ h32,
    ushort_t* __restrict__ s0, ushort_t* __restrict__ s1,
    const float* __restrict__ bias)
{
  const int px = blockIdx.x * 256 + threadIdx.x;  // 8192
  const int co0 = blockIdx.y * 16;
  const int img = px >> 10, pp = px & 1023;
  const float* part1 = part + (1u << 21);
  uint p0[8], p1[8];
#pragma unroll
  for (int i = 0; i < 8; ++i) {
    size_t ha = ((size_t)(img * 256 + co0 + 2 * i)) * 1024 + pp;
    size_t hb = ha + 1024;
    float va = part[ha] + part1[ha] + bias[co0 + 2 * i];
    float vb = part[hb] + part1[hb] + bias[co0 + 2 * i + 1];
    float sa, sb;
    if (WH) {
      va = fmaxf(va, 0.f); vb = fmaxf(vb, 0.f);
      h32[ha] = va; h32[hb] = vb; sa = va; sb = vb;
    } else { sa = fmaxf(va, 0.f); sb = fmaxf(vb, 0.f); }
    ushort_t a0 = f2bf(sa), b0 = f2bf(sb);
    p0[i] = (uint)a0 | ((uint)b0 << 16);
    p1[i] = (uint)f2bf(sa - bf2f(a0)) | ((uint)f2bf(sb - bf2f(b0)) << 16);
  }
  ushort_t* d0 = s0 + (size_t)px * 256 + co0;
  ushort_t* d1 = s1 + (size_t)px * 256 + co0;
  uint4 v0a; v0a.x = p0[0]; v0a.y = p0[1]; v0a.z = p0[2]; v0a.w = p0[3];
  uint4 v0b; v0b.x = p0[4]; v0b.y = p0[5]; v0b.z = p0[6]; v0b.w = p0[7];
  uint4 v1a; v1a.x = p1[0]; v1a.y = p1[1]; v1a.z = p1[2]; v1a.w = p1[3];
  uint4 v1b; v1b.x = p1[4]; v1b.y = p1[5]; v1b.z = p1[6]; v1b.w = p1[7];
  *(uint4*)d0 = v0a; *(uint4*)(d0 + 8) = v0b;
  *(uint4*)d1 = v1a; *(uint4*)(d1 + 8) = v1b;
}

// ---------- residual 1x1 MFMA, 32-co tile, fused epilogue ----------
// h += conv1x1(x) + bias; write h32; if WS also split(relu(h)) via LDS
// transpose. Block 32co x 128px, 4 waves, acc 2x2; grid (pxT 64, coT 8).
template<bool WS>
__global__ __launch_bounds__(256) void k_enc_mfma(
    const ushort_t* __restrict__ x0, const ushort_t* __restrict__ x1,
    const ushort_t* __restrict__ wp, const float* __restrict__ bias,
    float* __restrict__ h32, ushort_t* __restrict__ sp0, ushort_t* __restrict__ sp1)
{
  __shared__ ushort_t smem[20480];   // dbuf 2x10240 us; WS epilogue reuses [0,8192)
  const int tid = threadIdx.x, lane = tid & 63, wv = tid >> 6;
  const int l15 = lane & 15, q = lane >> 4;
  const int pxT = blockIdx.x, coT = blockIdx.y;
  const int coT4 = coT >> 1, half = coT & 1;
  f32x4 acc[2][2];
#pragma unroll
  for (int m = 0; m < 2; ++m)
#pragma unroll
    for (int n = 0; n < 2; ++n) acc[m][n] = (f32x4){0.f, 0.f, 0.f, 0.f};

  const int r0 = tid >> 2, kq = tid & 3;
  const ushort_t* srcB[2][2];
#pragma unroll
  for (int r = 0; r < 2; ++r) {
    size_t rowb = ((size_t)(pxT * 128 + r0 + r * 64)) << 8;
    srcB[r][0] = x0 + rowb + kq * 8;
    srcB[r][1] = x1 + rowb + kq * 8;
  }
  // A source: wave w loads 1KB: pl = w>>1, sub = w&1 (rows sub*16..+16 of 32)
  const int apl = wv >> 1, asub = wv & 1;
  const int aoff = apl * 2048 + half * 1024 + asub * 512 + lane * 8;  // us
  const int wvb = wv * 1024;  // bytes
  auto stage = [&](int c, int bi) {
    char* bufb = (char*)(smem + bi * 10240);
    const ushort_t* ap = wp + ((size_t)(c * 4 + coT4) << 12) + aoff;
    gload16(ap, bufb + wvb);                              // A: wave slice
    const int ko = c * 32;
    gload16(srcB[0][0] + ko, bufb + 4096 + wvb);          // B pl0 rows 0-63
    gload16(srcB[1][0] + ko, bufb + 8192 + wvb);          // B pl0 rows 64-127
    gload16(srcB[0][1] + ko, bufb + 12288 + wvb);         // B pl1 rows 0-63
    gload16(srcB[1][1] + ko, bufb + 16384 + wvb);         // B pl1 rows 64-127
  };
  auto compute = [&](const ushort_t* buf) {
    const ushort_t* sA = buf;           // [pl][row32][k32] us
    const ushort_t* sB = buf + 2048;    // [pl][row128][k32] us
    short8 af[2][2], bf[2][2];
#pragma unroll
    for (int m = 0; m < 2; ++m)
#pragma unroll
      for (int pl = 0; pl < 2; ++pl)
        af[m][pl] = *(const short8*)(sA + pl * 1024 + (m * 16 + l15) * 32 + q * 8);
#pragma unroll
    for (int n = 0; n < 2; ++n)
#pragma unroll
      for (int pl = 0; pl < 2; ++pl)
        bf[n][pl] = *(const short8*)(sB + pl * 4096 + (wv * 32 + n * 16 + l15) * 32 + q * 8);
#pragma unroll
    for (int m = 0; m < 2; ++m)
#pragma unroll
      for (int n = 0; n < 2; ++n) {
        acc[m][n] = __builtin_amdgcn_mfma_f32_16x16x32_bf16(af[m][0], bf[n][0], acc[m][n], 0, 0, 0);
        acc[m][n] = __builtin_amdgcn_mfma_f32_16x16x32_bf16(af[m][0], bf[n][1], acc[m][n], 0, 0, 0);
        acc[m][n] = __builtin_amdgcn_mfma_f32_16x16x32_bf16(af[m][1], bf[n][0], acc[m][n], 0, 0, 0);
      }
  };

  stage(0, 0);
  __syncthreads();
  int cur = 0;
  for (int c = 0; c < 8; ++c) {
    if (c + 1 < 8) stage(c + 1, cur ^ 1);
    compute(smem + cur * 10240);
    __syncthreads();
    cur ^= 1;
  }

  // epilogue: h32 RMW (+ optional splits via LDS transpose)
  const int cob = coT * 32;
#pragma unroll
  for (int m = 0; m < 2; ++m) {
#pragma unroll
    for (int n = 0; n < 2; ++n) {
#pragma unroll
      for (int r = 0; r < 4; ++r) {
        const int co_l = m * 16 + q * 4 + r;
        const int px_l = wv * 32 + n * 16 + l15;
        float v = acc[m][n][r] + bias[cob + co_l];
        const int px = pxT * 128 + px_l;
        const int img = px >> 10, pp = px & 1023;
        const size_t ha = ((size_t)(img * 256 + cob + co_l)) * 1024 + pp;
        v += h32[ha];
        h32[ha] = v;
        if (WS) {
          float sv = fmaxf(v, 0.f);
          ushort_t b0 = f2bf(sv);
          smem[px_l * 32 + co_l] = b0;
          smem[4096 + px_l * 32 + co_l] = f2bf(sv - bf2f(b0));
        }
      }
    }
  }
  if (WS) {
    __syncthreads();
#pragma unroll
    for (int i = 0; i < 4; ++i) {
      int idx = tid + 256 * i;          // 0..1023 uint4 units
      int pl = idx >> 9;
      int rem = idx & 511;
      int px_l = rem >> 2, g = rem & 3;
      uint4 vv = *(const uint4*)(smem + pl * 4096 + px_l * 32 + g * 8);
      ushort_t* dst = (pl ? sp1 : sp0) + ((size_t)(pxT * 128 + px_l)) * 256 + cob + g * 8;
      *(uint4*)dst = vv;
    }
  }
}

// ---------- 1x1 conv fp32 (to_z only) ----------
__global__ __launch_bounds__(256) void k_conv1x1(
    const float* __restrict__ in, float* __restrict__ out,
    const float* __restrict__ wT, const float* __restrict__ bias,
    int CI, int CO, int P)
{
  const int p = blockIdx.x * 256 + threadIdx.x;
  const int cob = blockIdx.y * 8;
  const int n = blockIdx.z;
  const float* inN = in + (size_t)n * CI * P + p;
  float acc[8];
#pragma unroll
  for (int i = 0; i < 8; ++i) acc[i] = bias[cob + i];
  const float* wr = wT + cob;
#pragma unroll 4
  for (int ci = 0; ci < CI; ++ci) {
    float iv = inN[(size_t)ci * P];
    const float* w = wr + (size_t)ci * CO;  // uniform
#pragma unroll
    for (int i = 0; i < 8; ++i) acc[i] = fmaf(iv, w[i], acc[i]);
  }
  float* outN = out + (size_t)n * CO * P + p;
#pragma unroll
  for (int i = 0; i < 8; ++i) outN[(size_t)(cob + i) * P] = acc[i];
}

// ---------- VQ partial: 16 chunks of 32 codes; per-j math identical ----------
__global__ __launch_bounds__(256) void k_vq_part(
    const float* __restrict__ z_e, const float* __restrict__ cb,
    const float* __restrict__ cnorm, float* __restrict__ pbest, int* __restrict__ pbid)
{
  int g = blockIdx.x * 256 + threadIdx.x;  // 8192 points
  int chunk = blockIdx.y;                  // 16 chunks
  int img = g >> 10, p = g & 1023;
  const float* zp = z_e + (size_t)img * 64 * 1024 + p;
  float z[64];
#pragma unroll
  for (int c = 0; c < 64; ++c) z[c] = zp[(size_t)c * 1024];
  float best = 3.4e38f; int bid = chunk << 5;
  const int j0 = chunk << 5;
  for (int j = j0; j < j0 + 32; ++j) {
    const float* cj = cb + j * 64;  // uniform -> scalar loads
    float m = 0.f;
#pragma unroll
    for (int c = 0; c < 64; ++c) m = fmaf(z[c], cj[c], m);
    float d = fmaf(-2.f, m, cnorm[j]);
    if (d < best) { best = d; bid = j; }  // strict <: first-min within chunk
  }
  pbest[chunk * 8192 + g] = best;
  pbid[chunk * 8192 + g] = bid;
}

// ---------- VQ reduce: argmin across chunks + e_k + decn gather -------------
__global__ __launch_bounds__(256) void k_vq_reduce(
    const float* __restrict__ pbest, const int* __restrict__ pbid,
    const float* __restrict__ cb, const ushort_t* __restrict__ T,
    float* __restrict__ ids_f, float* __restrict__ ek, ushort_t* __restrict__ decn)
{
  int g = blockIdx.x * 256 + threadIdx.x;  // 8192
  float best = 3.4e38f; int bid = 0;
#pragma unroll
  for (int ch = 0; ch < 16; ++ch) {
    float d = pbest[ch * 8192 + g];
    int b = pbid[ch * 8192 + g];
    if (d < best) { best = d; bid = b; }
  }
  ids_f[g] = (float)bid;
  int img = g >> 10, p = g & 1023;
  const float* cbid = cb + bid * 64;
  float* ekp = ek + (size_t)img * 64 * 1024 + p;
#pragma unroll
  for (int c = 0; c < 64; ++c) ekp[(size_t)c * 1024] = cbid[c];
  // decn[px] = T[bid] (precomputed relu(W@cb[bid]+b) in bf16)
  const ushort_t* Trow = T + (size_t)bid * 256;
  ushort_t* drow = decn + (size_t)g * 256;
#pragma unroll
  for (int i = 0; i < 16; ++i)
    *(uint4*)(drow + i * 16) = *(const uint4*)(Trow + i * 16);
}

// ---------- t1 convtranspose 4x4 s2 p1, 256->256, bf16 MFMA, relu -> bf16 NHWC
// per-c8 halo staging: 4 taps share a 6x34 halo tile. 2 barriers per c8.
__global__ __launch_bounds__(256) void k_mfma_t1(
    const ushort_t* __restrict__ nhwc, const ushort_t* __restrict__ wb,
    const float* __restrict__ bias, ushort_t* __restrict__ t1o)
{
  __shared__ ushort_t smem[24576];  // A 16384 us (4 taps x 4096) | halo 8192 us
  const int tid = threadIdx.x;
  const int lane = tid & 63;
  const int wv = tid >> 6;
  const int wm = wv & 1, wn = wv >> 1;
  const int l15 = lane & 15, q = lane >> 4;
  const int pxT = blockIdx.x, coT = blockIdx.y, par = blockIdx.z;
  const int ry = par & 1, rx = (par >> 1) & 1;
  const int pxbase = pxT * 128;
  const int img = pxbase >> 10;
  const int U0 = (pxT & 7) * 4;   // base input-grid row of this 128px strip
  f32x4 acc[4][4];
#pragma unroll
  for (int i = 0; i < 4; ++i)
#pragma unroll
    for (int j = 0; j < 4; ++j) acc[i][j] = (f32x4){0.f, 0.f, 0.f, 0.f};

  // halo DMA sources: slot = r*136 + c*4 + kq ; (row U0-1+r, col c-1), 816 slots
  const ushort_t* srcp[4];
#pragma unroll
  for (int i = 0; i < 4; ++i) {
    int slot = i * 256 + tid;
    int rr = slot / 136;
    int c4 = slot - rr * 136;
    int cc = c4 >> 2, kq2 = c4 & 3;
    int iy = U0 - 1 + rr, ix = cc - 1;
    bool valid = (slot < 816) && ((unsigned)iy < 32u) && ((unsigned)ix < 32u);
    const ushort_t* base = valid
        ? (nhwc + (((size_t)(img * 1024 + iy * 32 + ix)) << 8))
        : g_zpad;
    srcp[i] = base + kq2 * 8;
  }
  const int wvb = wv * 1024;
  char* bufb = (char*)smem;

  for (int c8 = 0; c8 < 8; ++c8) {
#pragma unroll
    for (int tap = 0; tap < 4; ++tap) {
      const ushort_t* Ab = wb + ((size_t)((par * 4 + tap) * 8 + c8) << 13)
                           + coT * 4096 + tid * 8;
      gload16(Ab,        bufb + tap * 8192 + wvb);
      gload16(Ab + 2048, bufb + tap * 8192 + 4096 + wvb);
    }
    const int ko = c8 * 32;
#pragma unroll
    for (int i = 0; i < 4; ++i)
      gload16(srcp[i] + ko, bufb + 32768 + i * 4096 + wvb);
    __syncthreads();
    const ushort_t* A = smem;
    const ushort_t* H = smem + 16384;
#pragma unroll
    for (int tap = 0; tap < 4; ++tap) {
      const int a = tap >> 1, b = tap & 1;
      const int dr = ry + 1 - a, dc = rx + 1 - b;
      short8 af[4], bfr[4];
#pragma unroll
      for (int i = 0; i < 4; ++i)
        af[i] = *(const short8*)(A + tap * 4096 + (wm * 64 + i * 16 + l15) * 32 + q * 8);
#pragma unroll
      for (int j = 0; j < 4; ++j) {
        const int row = wn * 64 + j * 16 + l15;
        const int rr = (row >> 5) + dr, cc = (row & 31) + dc;
        bfr[j] = *(const short8*)(H + rr * 1088 + cc * 32 + q * 8);
      }
#pragma unroll
      for (int i = 0; i < 4; ++i)
#pragma unroll
        for (int j = 0; j < 4; ++j)
          acc[i][j] = __builtin_amdgcn_mfma_f32_16x16x32_bf16(af[i], bfr[j], acc[i][j], 0, 0, 0);
    }
    __syncthreads();   // before restage (single-buffered)
  }

#pragma unroll
  for (int i = 0; i < 4; ++i) {
    int co = coT * 128 + wm * 64 + i * 16 + q * 4;
#pragma unroll
    for (int j = 0; j < 4; ++j) {
      int px = pxbase + wn * 64 + j * 16 + l15;
      int u = (px >> 5) & 31, vv = px & 31;
      int oy = 2 * u + ry, ox = 2 * vv + rx;
      ushort_t e0 = f2bf(fmaxf(acc[i][j][0] + bias[co + 0], 0.f));
      ushort_t e1 = f2bf(fmaxf(acc[i][j][1] + bias[co + 1], 0.f));
      ushort_t e2 = f2bf(fmaxf(acc[i][j][2] + bias[co + 2], 0.f));
      ushort_t e3 = f2bf(fmaxf(acc[i][j][3] + bias[co + 3], 0.f));
      uint2 pk; pk.x = (uint)e0 | ((uint)e1 << 16); pk.y = (uint)e2 | ((uint)e3 << 16);
      *(uint2*)(t1o + ((size_t)(img * 4096 + oy * 64 + ox) * 256 + co)) = pk;
    }
  }
}

// ---------- t2 convtranspose 4x4 s2 p1, 256->3, bf16 MFMA, sigmoid ----------
// global_load_lds staging (linear LDS, dbuf, 1 barrier/chunk).
__global__ __launch_bounds__(256) void k_mfma_t2(
    const ushort_t* __restrict__ t1o, const ushort_t* __restrict__ wb,
    const float* __restrict__ bias, float* __restrict__ out)
{
  __shared__ ushort_t smem[2][8704];  // per buf: sA 8192 us | sB 512 us
  const int tid = threadIdx.x, lane = tid & 63, wv = tid >> 6;
  const int l15 = lane & 15, q = lane >> 4;
  const int pxb = blockIdx.x * 256;
  const int par = blockIdx.y;
  const int ry = par & 1, rx = (par >> 1) & 1;
  f32x4 acc[4];
#pragma unroll
  for (int m = 0; m < 4; ++m) acc[m] = (f32x4){0.f, 0.f, 0.f, 0.f};
  const int kg = tid & 3;
  const ushort_t* srcA[4];
  int ptap = -1;
  auto retap = [&](int tap) {
    ptap = tap;
    const int a = tap >> 1, b = tap & 1;
#pragma unroll
    for (int i = 0; i < 4; ++i) {
      int row = (tid >> 2) + 64 * i;
      int px = pxb + row;
      int img = px >> 12, p = px & 4095, u = p >> 6, v = p & 63;
      int iy = u + ry - a, ix = v + rx - b;
      bool valid = ((unsigned)iy < 64u) && ((unsigned)ix < 64u);
      srcA[i] = (valid ? (t1o + (((size_t)(img * 4096 + iy * 64 + ix)) << 8)) : g_zpad)
                + kg * 8;
    }
  };
  const int wvb = wv * 1024;
  auto stage = [&](int c, int bi) {
    const int tap = c >> 3, cg = c & 7;
    if (tap != ptap) retap(tap);
    char* bufb = (char*)smem[bi];
    const int ko = cg * 32;
#pragma unroll
    for (int i = 0; i < 4; ++i)
      gload16(srcA[i] + ko, bufb + i * 4096 + wvb);
    if (tid < 64)
      gload16(wb + ((size_t)(par * 32 + c)) * 512 + tid * 8, bufb + 16384);
  };
  auto compute = [&](const ushort_t* buf) {
    const ushort_t* sA = buf;
    const ushort_t* sB = buf + 8192;
    short8 bf = *(const short8*)(sB + l15 * 32 + q * 8);
#pragma unroll
    for (int m = 0; m < 4; ++m) {
      const int row = wv * 64 + m * 16 + l15;
      short8 af = *(const short8*)(sA + row * 32 + q * 8);
      acc[m] = __builtin_amdgcn_mfma_f32_16x16x32_bf16(af, bf, acc[m], 0, 0, 0);
    }
  };

  stage(0, 0);
  __syncthreads();
  int cur = 0;
  for (int c = 0; c < 32; ++c) {
    if (c + 1 < 32) stage(c + 1, cur ^ 1);
    compute(smem[cur]);
    __syncthreads();
    cur ^= 1;
  }

  const int co = l15;
  if (co < 3) {
    float bco = bias[co];
#pragma unroll
    for (int m = 0; m < 4; ++m) {
#pragma unroll
      for (int r = 0; r < 4; ++r) {
        int px = pxb + wv * 64 + m * 16 + q * 4 + r;
        int img = px >> 12, p = px & 4095, u = p >> 6, v = p & 63;
        size_t addr = ((size_t)(img * 3 + co)) * 16384 + (2 * u + ry) * 128 + (2 * v + rx);
        out[addr] = 1.f / (1.f + expf(-(acc[m][r] + bco)));
      }
    }
  }
}

// ---------------------------------------------------------------------------
extern "C" void kernel_launch(void* const* d_in, const int* in_sizes, int n_in,
                              void* d_out, int out_size, void* d_ws, size_t ws_size,
                              hipStream_t stream) {
  (void)in_sizes; (void)n_in; (void)out_size; (void)ws_size;
  const float* x      = (const float*)d_in[0];
  const float* c1_w   = (const float*)d_in[1];
  const float* c1_b   = (const float*)d_in[2];
  const float* c2_w   = (const float*)d_in[3];
  const float* c2_b   = (const float*)d_in[4];
  const float* r0_w3  = (const float*)d_in[5];
  const float* r0_b3  = (const float*)d_in[6];
  const float* r0_w1  = (const float*)d_in[7];
  const float* r0_b1  = (const float*)d_in[8];
  const float* r1_w3  = (const float*)d_in[9];
  const float* r1_b3  = (const float*)d_in[10];
  const float* r1_w1  = (const float*)d_in[11];
  const float* r1_b1  = (const float*)d_in[12];
  const float* to_z_w = (const float*)d_in[13];
  const float* to_z_b = (const float*)d_in[14];
  const float* cb     = (const float*)d_in[15];
  const float* from_z_w = (const float*)d_in[16];
  const float* from_z_b = (const float*)d_in[17];
  const float* t1_w   = (const float*)d_in[18];
  const float* t1_b   = (const float*)d_in[19];
  const float* t2_w   = (const float*)d_in[20];
  const float* t2_b   = (const float*)d_in[21];

  float* wsf = (float*)d_ws;
  // Era-choreographed regions (float offsets):
  //  conv1 era:  xs1p0 [0,4.19M) | xs1p1 [4.19,8.39M)
  //  conv2 main: partials cp0 [8.39,10.49M) cp1 [10.49,12.58M)
  //  conv2 epi:  h32 := cp0 slot; splits -> sE [0,2.1M); cp1 dead after
  //  fzT:        T -> cp1 slot [10.49M, +65536 fl) (written after epi)
  //  3x3f/res:   sE <-> sF ping-pong
  //  vq era:     pbest [0,131072) pbid [131072,...); vq_reduce gathers T
  //  dec era:    t1out [2.1,6.29M) | decn [6.29,7.34M)
  ushort_t* xs1p0 = (ushort_t*)(wsf + 0);
  ushort_t* xs1p1 = (ushort_t*)(wsf + 4194304);
  float*    cp0   = wsf + 8388608;               // conv2 partial kz0 (= h32 slot)
  float*    h32   = wsf + 8388608;
  ushort_t* fzT   = (ushort_t*)(wsf + 10485760); // T[512][256] bf16 (cp1 slot)
  ushort_t* sE0   = (ushort_t*)(wsf + 0);        // split ping [0,1.05M)
  ushort_t* sE1   = (ushort_t*)(wsf + 1048576);  // split ping [1.05,2.1M)
  ushort_t* sF0   = (ushort_t*)(wsf + 2097152);  // split pong [2.1,3.15M)
  ushort_t* sF1   = (ushort_t*)(wsf + 3145728);  // split pong [3.15,4.19M)
  float*    pbest = wsf + 0;                     // vq-era
  int*      pbid  = (int*)(wsf + 131072);        // vq-era
  ushort_t* t1out = (ushort_t*)(wsf + 2097152);  // dec-era [2.1M, 6.29M)
  ushort_t* decn  = (ushort_t*)(wsf + 6291456);  // dec-era [6.29M, 7.34M)
  ushort_t* wp_c2   = (ushort_t*)(wsf + 12582912);
  ushort_t* wp_r0w3 = (ushort_t*)(wsf + 13631488);
  ushort_t* wp_r1w3 = (ushort_t*)(wsf + 14221312);
  ushort_t* wp_r0w1 = (ushort_t*)(wsf + 14811136);
  ushort_t* wp_r1w1 = (ushort_t*)(wsf + 14876672);
  float*    wt_c1   = wsf + 14942208;
  float*    wt_toz  = wsf + 14954496;
  float*    wt_fromz= wsf + 14970880;
  ushort_t* t1wb    = (ushort_t*)(wsf + 14987264);
  ushort_t* w2pk    = (ushort_t*)(wsf + 15511552);
  float*    cnorm   = wsf + 15544320;

  float* out_img = (float*)d_out;        // 393216
  float* z_e_out = out_img + 393216;     // 524288
  float* e_k_out = z_e_out + 524288;     // 524288
  float* ids_out = e_k_out + 524288;     // 8192 (stored as float)

  // ---- weight prep (2 dispatches) ----
  k_prep_all<<<1714, 256, 0, stream>>>(
      c1_w, wt_c1, to_z_w, wt_toz, from_z_w, wt_fromz, cb, cnorm, t2_w, w2pk,
      c2_w, wp_c2, r0_w3, wp_r0w3, r1_w3, wp_r1w3, r0_w1, wp_r0w1, r1_w1, wp_r1w1);
  k_prep_t1w<<<256, 256, 0, stream>>>(t1_w, t1wb);

  // ---- encoder ----
  k_conv1_split<<<dim3(64, 4, 8), 256, 0, stream>>>(x, xs1p0, xs1p1, wt_c1, c1_b);
  // conv2: plain-store partials cp0/cp1, epilogue: sum+relu -> h32 + splits
  k_enc_mfma_split<0><<<dim3(64, 4, 2), 256, 0, stream>>>(xs1p0, xs1p1, wp_c2, cp0);
  k_enc_epi<true><<<dim3(32, 16), 256, 0, stream>>>(cp0, h32, sE0, sE1, c2_b);
  // fzT table (cp1 now dead); bit-identical to old from_z math
  k_prep_fzT<<<512, 256, 0, stream>>>(cb, from_z_w, from_z_b, fzT);
  // r0 w3 (kz=1 halo, fused epilogue): sE -> sF
  k_enc_mfma_3x3f<<<dim3(64, 8), 256, 0, stream>>>(sE0, sE1, wp_r0w3, r0_b3, sF0, sF1);
  // r0 w1: h += conv; write h32 + split(relu(h)): sF -> sE
  k_enc_mfma<true ><<<dim3(64, 8), 256, 0, stream>>>(
      sF0, sF1, wp_r0w1, r0_b1, h32, sE0, sE1);
  // r1 w3: sE -> sF
  k_enc_mfma_3x3f<<<dim3(64, 8), 256, 0, stream>>>(sE0, sE1, wp_r1w3, r1_b3, sF0, sF1);
  // r1 w1: h += conv; write h32 only: reads sF
  k_enc_mfma<false><<<dim3(64, 8), 256, 0, stream>>>(
      sF0, sF1, wp_r1w1, r1_b1, h32, nullptr, nullptr);
  // to_z (fp32)
  k_conv1x1<<<dim3(4, 8, 8), 256, 0, stream>>>(h32, z_e_out, wt_toz, to_z_b, 256, 64, 1024);

  // ---- VQ (chunk-parallel; bit-identical argmin); reduce also gathers decn --
  k_vq_part<<<dim3(32, 16), 256, 0, stream>>>(z_e_out, cb, cnorm, pbest, pbid);
  k_vq_reduce<<<32, 256, 0, stream>>>(pbest, pbid, cb, fzT, ids_out, e_k_out, decn);

  // ---- decoder (bf16) ----
  k_mfma_t1<<<dim3(64, 2, 4), 256, 0, stream>>>(decn, t1wb, t1_b, t1out);
  k_mfma_t2<<<dim3(128, 4), 256, 0, stream>>>(t1out, w2pk, t2_b, out_img);
}